// Round 10
// baseline (459.478 us; speedup 1.0000x reference)
//
#include <hip/hip_runtime.h>
#include <stdint.h>

// ---------- types / helpers ----------
typedef unsigned short u16;
typedef unsigned int   u32;
typedef __attribute__((ext_vector_type(4))) float f32x4;
typedef __attribute__((ext_vector_type(4))) u32   u32x4;
typedef __attribute__((ext_vector_type(8))) __bf16 bf16x8;

#define MFMA16(a,b,c) __builtin_amdgcn_mfma_f32_16x16x32_bf16((a),(b),(c),0,0,0)

#define QSCALE 0.08838834764831845f   // 128^-0.5
#define RMAX   24576                  // sum roundup(min(n,2048),256) <= 16384+32*255

__device__ __forceinline__ float bf2f(u16 x){ u32 u=((u32)x)<<16; float f; __builtin_memcpy(&f,&u,4); return f; }
__device__ __forceinline__ u16 f2bf(float f){ u32 u; __builtin_memcpy(&u,&f,4); u = u + 0x7FFFu + ((u>>16)&1u); return (u16)(u>>16); }
__device__ __forceinline__ u32 pack2(float a, float b){ return (u32)f2bf(a) | ((u32)f2bf(b)<<16); }

// async global->LDS, 16B per lane
__device__ __forceinline__ void gl_lds(const u16* g, u16* l){
  __builtin_amdgcn_global_load_lds(
      (const __attribute__((address_space(1))) void*)g,
      (__attribute__((address_space(3))) void*)l, 16, 0, 0);
}

// transposed-tile addr with octet swizzle (attn): row stride 72 u16
#define TSW(row, oct) ((row)*72 + ((((oct) ^ (((row)>>3)&7)))<<3))

// meta layout (ints): [0,32) n  [32,64) nact  [64,96) npad  [96,129) base
// [129,161) nchunks  [161] R_total  [192,352) 256-tile -> group map

// ---------- device bodies for fused pre-pass ----------
__device__ __forceinline__ void cvt_body(const float* __restrict__ s, u16* __restrict__ d,
                                         long n8, int lb, int nb){
  long idx = (long)lb*256 + threadIdx.x;
  long stride = (long)nb*256;
  for (long i=idx; i<n8; i+=stride){
    const float* p = s + i*8;
    f32x4 a = *(const f32x4*)p;
    f32x4 b = *(const f32x4*)(p+4);
    u32x4 o;
    o[0]=pack2(a[0],a[1]); o[1]=pack2(a[2],a[3]); o[2]=pack2(b[0],b[1]); o[3]=pack2(b[2],b[3]);
    *(u32x4*)(d + i*8) = o;
  }
}

__device__ __forceinline__ void route_body(const float* __restrict__ x, const float* __restrict__ gw,
  int* __restrict__ sel, float* __restrict__ rw, u16* __restrict__ xb, int lb)
{
  int w = threadIdx.x>>6, lane = threadIdx.x&63;
  int tok = lb*4 + w;
  const float* xr = x + (size_t)tok*1024 + lane*16;
  f32x4 xv[4];
  #pragma unroll
  for (int q=0;q<4;q++) xv[q] = *(const f32x4*)(xr + q*4);
  {
    u16* xrow = xb + (size_t)tok*1024 + lane*16;
    u32x4 o0, o1;
    o0[0]=pack2(xv[0][0],xv[0][1]); o0[1]=pack2(xv[0][2],xv[0][3]);
    o0[2]=pack2(xv[1][0],xv[1][1]); o0[3]=pack2(xv[1][2],xv[1][3]);
    o1[0]=pack2(xv[2][0],xv[2][1]); o1[1]=pack2(xv[2][2],xv[2][3]);
    o1[2]=pack2(xv[3][0],xv[3][1]); o1[3]=pack2(xv[3][2],xv[3][3]);
    *(u32x4*)xrow     = o0;
    *(u32x4*)(xrow+8) = o1;
  }
  float part[8];
  #pragma unroll
  for (int e=0;e<8;e++){
    const float* g = gw + e*1024 + lane*16;
    float s = 0.f;
    #pragma unroll
    for (int q=0;q<4;q++){
      f32x4 gv = *(const f32x4*)(g + q*4);
      s += xv[q][0]*gv[0] + xv[q][1]*gv[1] + xv[q][2]*gv[2] + xv[q][3]*gv[3];
    }
    part[e]=s;
  }
  #pragma unroll
  for (int e=0;e<8;e++){
    float v = part[e];
    #pragma unroll
    for (int off=32; off>0; off>>=1) v += __shfl_xor(v, off, 64);
    part[e]=v;
  }
  if (lane==0){
    int i0=0; float m0=part[0];
    #pragma unroll
    for (int e=1;e<8;e++) if (part[e]>m0){ m0=part[e]; i0=e; }
    int i1=0; float m1=-3.4e38f;
    #pragma unroll
    for (int e=0;e<8;e++) if (e!=i0 && part[e]>m1){ m1=part[e]; i1=e; }
    sel[tok] = i0 | (i1<<8);
    float e1 = expf(m1-m0);
    float inv = 1.f/(1.f+e1);
    rw[tok*2+0] = inv;
    rw[tok*2+1] = e1*inv;
  }
}

__device__ __forceinline__ void prep_body(
  const float* __restrict__ q_w, const float* __restrict__ k_w,
  const float* __restrict__ fmq1, const float* __restrict__ fmq2,
  const float* __restrict__ fmk1, const float* __restrict__ fmk2,
  u16* __restrict__ wA, u16* __restrict__ wB, int l, u16* shmem)
{
  int gi = l>>3;
  int c0 = (l&7)*128;
  const float* fm; const float* ws; u16* wd;
  if (gi < 8)      { int h=gi;    fm=fmq1; ws=q_w + (size_t)h*131072; wd=wA + (size_t)h*262144; }
  else if (gi < 16){ int h=gi-8;  fm=fmq2; ws=q_w + (size_t)h*131072; wd=wA + (size_t)h*262144 + 131072; }
  else if (gi < 80){ int t=gi-16, e=t>>3, h=t&7; fm=fmk1; ws=k_w + (size_t)(e*8+h)*131072; wd=wB + (size_t)e*2097152 + (size_t)h*262144; }
  else             { int t=gi-80, e=t>>3, h=t&7; fm=fmk2; ws=k_w + (size_t)(e*8+h)*131072; wd=wB + (size_t)e*2097152 + (size_t)h*262144 + 131072; }
  u16* Af = shmem;
  u16* Bf = shmem + 128*136;
  int tid = threadIdx.x;
  for (int i=tid; i<4096; i+=256){
    int row = i>>5, col = (i&31)*4;
    f32x4 v = *(const f32x4*)&fm[row*128 + col];
    u16* dp = &Af[row*136 + col];
    *(u32*)dp     = pack2(v[0],v[1]);
    *(u32*)(dp+2) = pack2(v[2],v[3]);
  }
  for (int i=tid; i<4096; i+=256){
    int dd = i>>5, cq = (i&31)*4;
    f32x4 v = *(const f32x4*)&ws[(size_t)dd*1024 + c0 + cq];
    #pragma unroll
    for (int j=0;j<4;j++){
      int c = cq+j;
      Bf[c*136 + (dd ^ (((c>>2)&3)<<3))] = f2bf(v[j]);
    }
  }
  __syncthreads();
  int lane=tid&63, w=tid>>6, wr=w>>1, wc=w&1, lc=lane&15, lr=lane>>4;
  const f32x4 Z4 = {0.f,0.f,0.f,0.f};
  f32x4 acc[4][4];
  #pragma unroll
  for (int i=0;i<4;i++){
    #pragma unroll
    for (int j=0;j<4;j++) acc[i][j]=Z4;
  }
  #pragma unroll
  for (int kk=0; kk<4; ++kk){
    bf16x8 a[4], b[4];
    #pragma unroll
    for (int mi=0;mi<4;mi++)
      a[mi] = *(const bf16x8*)&Af[(wr*64+mi*16+lc)*136 + kk*32 + lr*8];
    #pragma unroll
    for (int ni=0;ni<4;ni++){
      int c = wc*64+ni*16+lc;
      b[ni] = *(const bf16x8*)&Bf[c*136 + ((kk*32 + lr*8) ^ (((c>>2)&3)<<3))];
    }
    #pragma unroll
    for (int mi=0;mi<4;mi++){
      #pragma unroll
      for (int ni=0;ni<4;ni++)
        acc[mi][ni] = MFMA16(a[mi], b[ni], acc[mi][ni]);
    }
  }
  int r0=lr*4;
  #pragma unroll
  for (int mi=0;mi<4;mi++){
    #pragma unroll
    for (int ni=0;ni<4;ni++){
      int col = c0 + wc*64 + ni*16 + lc;
      #pragma unroll
      for (int r=0;r<4;r++){
        int row = wr*64 + mi*16 + r0 + r;
        wd[(size_t)row*1024 + col] = f2bf(acc[mi][ni][r]);
      }
    }
  }
}

// ---------- fused pre-pass: route+xb (0..2047) + prep (2048..3199) + cvt v_w (3200..3455) ----------
__global__ __launch_bounds__(256) void k_pre(
  const float* __restrict__ x, const float* __restrict__ gw,
  int* __restrict__ sel, float* __restrict__ rw,
  const float* __restrict__ q_w, const float* __restrict__ k_w,
  const float* __restrict__ fmq1, const float* __restrict__ fmq2,
  const float* __restrict__ fmk1, const float* __restrict__ fmk2,
  u16* __restrict__ wA, u16* __restrict__ wB, u16* __restrict__ xb,
  const float* __restrict__ v_w, u16* __restrict__ wVb)
{
  __shared__ __align__(16) u16 shmem[2*128*136];
  int bid = blockIdx.x;
  if (bid < 2048)      route_body(x, gw, sel, rw, xb, bid);
  else if (bid < 3200) prep_body(q_w, k_w, fmq1, fmq2, fmk1, fmk2, wA, wB, bid-2048, shmem);
  else                 cvt_body(v_w, wVb, 1048576L, bid-3200, 256);
}

// ---------- small cvt: o_w -> wOb ----------
__global__ __launch_bounds__(256) void k_cvtO(const float* __restrict__ o_w, u16* __restrict__ wOb){
  cvt_body(o_w, wOb, 131072L, blockIdx.x, 32);
}

// ---------- per-(b,e) counting sort ----------
__global__ __launch_bounds__(256) void k_count(const int* __restrict__ sel,
  int* __restrict__ slot_of, int* __restrict__ src_of, int* __restrict__ meta)
{
  int g = blockIdx.x, b = g>>3, e = g&7;
  int tid = threadIdx.x;
  __shared__ int cn[256];
  unsigned char ex[16];
  int cnt=0;
  #pragma unroll
  for (int i=0;i<16;i++){
    int t = tid*16+i;
    int sv = sel[b*2048 + (t>>1)];
    int ee = (t&1) ? ((sv>>8)&255) : (sv&255);
    ex[i]=(unsigned char)ee;
    cnt += (ee==e);
  }
  cn[tid]=cnt;
  __syncthreads();
  for (int off=1; off<256; off<<=1){
    int v = (tid>=off) ? cn[tid-off] : 0;
    __syncthreads();
    cn[tid] += v;
    __syncthreads();
  }
  int total = cn[255];
  int run = cn[tid]-cnt;
  int shift = total>2048 ? total-2048 : 0;
  #pragma unroll
  for (int i=0;i<16;i++){
    int t = tid*16+i;
    if (ex[i]==e){
      int j = run - shift;
      run++;
      slot_of[b*4096 + t] = (j>=0)? j : -1;
      if (j>=0) src_of[g*2048 + j] = t;
    }
  }
  if (tid==0) meta[g]=total;
}

// ---------- group bases (256-aligned) + 256-tile->group map ----------
__global__ void k_bases(int* meta){
  if (threadIdx.x || blockIdx.x) return;
  int basev=0, t=0;
  meta[96]=0;
  for (int g=0; g<32; ++g){
    int n = meta[g];
    int nact = n<2048 ? n : 2048;
    int npad = (nact+255)&~255;
    meta[32+g]=nact;
    meta[64+g]=npad;
    meta[129+g]=(nact+63)>>6;
    for (int i=0;i<(npad>>8);++i) meta[192+t++]=g;
    basev += npad;
    meta[97+g]=basev;
  }
  meta[161]=basev;
}

// ---------- gather bf16 rows -> compact + row->token map ----------
__global__ __launch_bounds__(256) void k_gather(const u16* __restrict__ xb,
  const int* __restrict__ src_of, const int* __restrict__ meta, u16* __restrict__ xg,
  int* __restrict__ tokmap)
{
  int g = blockIdx.y, jb = blockIdx.x;
  int npad = meta[64+g];
  if (jb*64 >= npad) return;
  int nact = meta[32+g], base = meta[96+g];
  int tid = threadIdx.x;
  int j = jb*64 + (tid>>2);
  int quart = tid&3;
  int src = (j<nact) ? src_of[g*2048+j] : -1;
  int token = (src>=0) ? ((g>>3)*2048 + (src>>1)) : 0;
  if (quart==0) tokmap[base+j] = token;
  u16* orow = xg + ((size_t)(base+j))*1024 + quart*256;
  if (src>=0){
    const u16* xr = xb + (size_t)token*1024 + quart*256;
    #pragma unroll
    for (int i=0;i<256;i+=8) *(u32x4*)(orow+i) = *(const u32x4*)(xr+i);
  } else {
    u32x4 z = {0,0,0,0};
    #pragma unroll
    for (int i=0;i<256;i+=8) *(u32x4*)(orow+i)=z;
  }
}

// ======== fused q+k+v 256x256 8-wave GEMM, BK=32, 4-buffer ring, counted vmcnt ========
// blocks [0,256): q dual (A=xb, W=wA, M=8192, *QSCALE)
// blocks [256,1024): k dual (A=xg, W=wB per-expert)
// blocks [1024,1408): v single (A=xg, W=wVb per-expert, N=1024)
// LDS: 4 bufs x (A 256x32 + B 256x32) = 128 KB; stage 2 K-tiles ahead; vmcnt(4) per K-tile.
__global__ __launch_bounds__(512,2) void k_gemmQKV(const u16* __restrict__ xb, const u16* __restrict__ xg,
  const u16* __restrict__ wA, const u16* __restrict__ wB, const u16* __restrict__ wVb,
  u16* __restrict__ qh, u16* __restrict__ kh, u16* __restrict__ vv, const int* __restrict__ meta)
{
  int bid = blockIdx.x;
  int role, tm, tn;
  const u16 *A, *Wp; u16* outB;
  if (bid < 256){
    role=0; int l=bid, xcd=l&7, jj=l>>3;       // jj<32
    int jd=jj>>3; tm=xcd*4+jd; tn=jj&7;
    A=xb; Wp=wA + (size_t)tn*262144; outB=qh;
  } else if (bid < 1024){
    role=1; int l=bid-256, xcd=l&7, jj=l>>3;   // jj<96
    int jd=jj>>3; tm=xcd*12+jd; tn=jj&7;
    if (tm*256 >= meta[161]) return;
    A=xg; Wp=wB + (size_t)(meta[192+tm]&7)*2097152 + (size_t)tn*262144; outB=kh;
  } else {
    role=2; int l=bid-1024, xcd=l&7, jj=l>>3;  // jj<48
    int jd=jj>>2; tm=xcd*12+jd; tn=jj&3;
    if (tm*256 >= meta[161]) return;
    A=xg; Wp=wVb + (size_t)(meta[192+tm]&7)*1048576 + (size_t)tn*262144; outB=vv;
  }

  __shared__ __align__(16) u16 smem[65536];   // 128 KB

  int tid=threadIdx.x, lane=tid&63;
  int w=tid>>6, wr=w>>2, wc=w&3, lc=lane&15, lr=lane>>4;
  int szl=(lc^(lc>>2))&3;
  const f32x4 Z4 = {0.f,0.f,0.f,0.f};
  f32x4 acc[8][4];
  #pragma unroll
  for(int i=0;i<8;i++){
    #pragma unroll
    for(int j2=0;j2<4;j2++) acc[i][j2]=Z4;
  }
  const u16* Ag = A + (size_t)tm*262144;
  const u16* Bg = Wp;
  int grow = tid>>2;
  int gch  = (((tid&3)^((grow^(grow>>2))&3)))*8;
  int lch  = (tid&3)*8;

  // stage half h (0:A rows0-127, 1:A rows128-255, 2:B0-127, 3:B128-255) of K-tile t_
  #define STG(t_, h_) { \
    const u16* gs = ((h_)&2) ? Bg : Ag; \
    int rb = ((h_)&1)*128; \
    gl_lds(gs + (size_t)(rb+grow)*1024 + (size_t)(t_)*32 + gch, \
           smem + (((t_)&3)<<14) + (((h_)&2)?8192:0) + (rb+grow)*32 + lch); \
  }

  STG(0,0); STG(0,1); STG(0,2); STG(0,3);
  STG(1,0); STG(1,1); STG(1,2); STG(1,3);
  asm volatile("s_waitcnt vmcnt(4)" ::: "memory");
  __builtin_amdgcn_s_barrier();

  for (int t=0; t<32; ++t){
    int abase=(t&3)<<14, bbase=abase+8192;
    bf16x8 a[8];
    #pragma unroll
    for (int q=0;q<2;++q){
      if (q==0){
        #pragma unroll
        for (int mi=0;mi<8;mi++){
          int arow = wr*128+mi*16+lc;
          a[mi] = *(const bf16x8*)&smem[abase + arow*32 + ((lr^szl)<<3)];
        }
      }
      bf16x8 b[2];
      #pragma unroll
      for (int nj=0;nj<2;nj++){
        int brow = wc*64+(q*2+nj)*16+lc;
        b[nj] = *(const bf16x8*)&smem[bbase + brow*32 + ((lr^szl)<<3)];
      }
      if (t<30){ STG(t+2, q*2); STG(t+2, q*2+1); }
      __builtin_amdgcn_s_barrier();
      __builtin_amdgcn_s_setprio(1);
      #pragma unroll
      for (int mi=0;mi<8;mi++){
        #pragma unroll
        for (int nj=0;nj<2;nj++)
          acc[mi][q*2+nj] = MFMA16(a[mi], b[nj], acc[mi][q*2+nj]);
      }
      __builtin_amdgcn_s_setprio(0);
      if (q==1){
        if (t<30)      asm volatile("s_waitcnt vmcnt(4)" ::: "memory");
        else if (t==30) asm volatile("s_waitcnt vmcnt(0)" ::: "memory");
      }
      __builtin_amdgcn_s_barrier();
    }
  }
  #undef STG

  __syncthreads();
  if (role < 2){
    // Hadamard: waves wc>=2 hold factor-2 (cat rows 128..255); stash f32 (256x128), multiply in wc<2
    if (wc >= 2){
      #pragma unroll
      for (int mi=0;mi<8;mi++){
        #pragma unroll
        for (int ni=0;ni<4;ni++){
          int col = (wc-2)*64 + ni*16 + lc;
          #pragma unroll
          for (int r=0;r<4;r++)
            ((float*)smem)[(wr*128+mi*16+lr*4+r)*128 + col] = acc[mi][ni][r];
        }
      }
    }
    __syncthreads();
    if (wc < 2){
      float scl = (role==0) ? QSCALE : 1.0f;
      #pragma unroll
      for (int mi=0;mi<8;mi++){
        #pragma unroll
        for (int ni=0;ni<4;ni++){
          int col = wc*64 + ni*16 + lc;
          #pragma unroll
          for (int r=0;r<4;r++){
            int row = wr*128+mi*16+lr*4+r;
            float v = acc[mi][ni][r] * ((float*)smem)[row*128 + col] * scl;
            outB[(size_t)(tm*256+row)*1024 + tn*128 + col] = f2bf(v);
          }
        }
      }
    }
  } else {
    #pragma unroll
    for (int mi=0;mi<8;mi++){
      #pragma unroll
      for (int ni=0;ni<4;ni++){
        int col = tn*256 + wc*64 + ni*16 + lc;
        #pragma unroll
        for (int r=0;r<4;r++){
          int row = tm*256 + wr*128 + mi*16 + lr*4 + r;
          outB[(size_t)row*1024 + col] = f2bf(acc[mi][ni][r]);
        }
      }
    }
  }
}

// ======== 128x256 8-wave single GEMM, T4+T2 pipeline — final out proj ========
__global__ __launch_bounds__(512) void k_gemmO(const u16* __restrict__ A, const u16* __restrict__ W,
  float* __restrict__ outF)
{
  int tnN = gridDim.x;
  int bid = blockIdx.y*tnN + blockIdx.x;
  int chunk = gridDim.y >> 3;
  int xcd = bid & 7, j = bid >> 3;
  int jd = j / tnN;
  int tm = xcd*chunk + jd;
  int tn = j - jd*tnN;

  __shared__ __align__(16) u16 smem[73728];

  int tid=threadIdx.x, lane=tid&63;
  int w=tid>>6, wr=w>>2, wc=w&3, lc=lane&15, lr=lane>>4;
  int swz = lc&7;
  const f32x4 Z4 = {0.f,0.f,0.f,0.f};
  f32x4 acc[4][4];
  #pragma unroll
  for(int i=0;i<4;i++){
    #pragma unroll
    for(int j2=0;j2<4;j2++) acc[i][j2]=Z4;
  }
  size_t lanoff = (size_t)(tid>>3)*1024 + (size_t)(((tid&7)^((tid>>3)&7))*8);
  const u16* Ag = A + (size_t)tm*131072 + lanoff;
  const u16* Bg = W + (size_t)tn*262144 + lanoff;
  int lo = tid*8;

  #define STAGEO(ao, bo, kt) { \
    const u16* ga = Ag + (kt)*64; const u16* gb = Bg + (kt)*64; \
    gl_lds(ga,                 &smem[(ao) + lo]); \
    gl_lds(ga + (size_t)65536, &smem[(ao) + 4096 + lo]); \
    gl_lds(gb,                  &smem[(bo) + lo]); \
    gl_lds(gb + (size_t)65536,  &smem[(bo) + 4096 + lo]); \
    gl_lds(gb + (size_t)131072, &smem[(bo) + 8192 + lo]); \
    gl_lds(gb + (size_t)196608, &smem[(bo) + 12288 + lo]); }

  STAGEO(0, 24576, 0);
  STAGEO(8192, 40960, 1);
  int cur = 0;
  for (int kt=0; kt<16; ++kt){
    if (kt<15) asm volatile("s_waitcnt vmcnt(6)" ::: "memory");
    else       asm volatile("s_waitcnt vmcnt(0)" ::: "memory");
    __builtin_amdgcn_s_barrier();
    if (kt<14){
      int nid = kt+2; nid -= (nid/3)*3;
      STAGEO(nid*8192, 24576+nid*16384, kt+2);
    }
    int ao = cur*8192, bo = 24576 + cur*16384;
    __builtin_amdgcn_s_setprio(1);
    #pragma unroll
    for (int kk=0; kk<2; ++kk){
      bf16x8 a[4], b[4];
      #pragma unroll
      for (int mi=0;mi<4;mi++){
        int row = wr*64+mi*16+lc;
        a[mi] = *(const bf16x8*)&smem[ao + row*64 + (((kk*4+lr)^swz)<<3)];
      }
      #pragma unroll
      for (int ni=0;ni<4;ni++){
        int row = wc*64+ni*16+lc;
        b[ni] = *(const bf16x8*)&smem[bo + row*64 + (((kk*4+lr)^swz)<<3)];
      }
      #pragma unroll
      for (int mi=0;mi<4;mi++){
        #pragma unroll
        for (int ni=0;ni<4;ni++)
          acc[mi][ni] = MFMA16(a[mi], b[ni], acc[mi][ni]);
      }
    }
    __builtin_amdgcn_s_setprio(0);
    cur = (cur==2)?0:cur+1;
  }
  #pragma unroll
  for (int mi=0;mi<4;mi++){
    #pragma unroll
    for (int ni=0;ni<4;ni++){
      int col = tn*256 + wc*64 + ni*16 + lc;
      #pragma unroll
      for (int r=0;r<4;r++){
        int row = tm*128 + wr*64 + mi*16 + lr*4 + r;
        outF[(size_t)row*1024 + col] = acc[mi][ni][r];
      }
    }
  }
  #undef STAGEO
}

// ---------- chunked causal linear attention, one block per (group, head) ----------
__global__ __launch_bounds__(256,1) void k_attn(const u16* __restrict__ qv, const u16* __restrict__ kv,
  const u16* __restrict__ vv, u16* __restrict__ o, const int* __restrict__ meta,
  const int* __restrict__ tokmap)
{
  int g = blockIdx.x>>3, h = blockIdx.x&7;
  int nch = meta[129+g];
  if (nch==0) return;
  int base = meta[96+g];
  __shared__ __align__(16) u16 Qs[64*136];
  __shared__ __align__(16) u16 Ks[64*136];
  __shared__ __align__(16) u16 KTs[128*72];
  __shared__ __align__(16) u16 VTs[128*72];
  __shared__ __align__(16) u16 Ts[2*128*136];
  __shared__ __align__(16) u16 Ps[64*72];
  int tid=threadIdx.x, w=tid>>6, lane=tid&63;
  int wr=w>>1, wc=w&1;
  int lr=lane>>4, lc=lane&15;
  {
    u32x4 z={0,0,0,0};
    for (int i=tid; i<128*136/8; i+=256) *(u32x4*)&Ts[i*8]=z;
  }
  const f32x4 Z4 = {0.f,0.f,0.f,0.f};
  f32x4 accT[4][4];
  #pragma unroll
  for (int i=0;i<4;i++){
    #pragma unroll
    for (int j=0;j<4;j++) accT[i][j]=Z4;
  }
  __syncthreads();
  const u16* kb = kv + (size_t)base*1024 + h*128;
  const u16* vb = vv + (size_t)base*1024 + h*128;
  u16* ob = o + (size_t)base*1024 + h*128;
  int tso = 0;

  for (int c=0; c<nch; ++c){
    #pragma unroll
    for (int it=0; it<4; ++it){
      int id = tid + it*256;
      int row = id>>4, kc = id&15;
      int tok = tokmap[base + c*64 + row];
      *(u32x4*)&Qs[row*136 + kc*8] = *(const u32x4*)(qv + (size_t)tok*1024 + h*128 + kc*8);
      *(u32x4*)&Ks[row*136 + kc*8] = *(const u32x4*)(kb + (size_t)(c*64+row)*1024 + kc*8);
    }
    #pragma unroll
    for (int it=0; it<4; ++it){
      int id = tid + it*256;
      int j = id>>4, dg = id&15;
      int col = (((j>>3) ^ (dg&7))<<3) + (j&7);
      u32x4 kx = *(const u32x4*)(kb + (size_t)(c*64+j)*1024 + dg*8);
      u32x4 vx = *(const u32x4*)(vb + (size_t)(c*64+j)*1024 + dg*8);
      #pragma unroll
      for (int t=0;t<4;t++){
        KTs[(dg*8+t*2  )*72 + col] = (u16)(kx[t]&0xffff);
        KTs[(dg*8+t*2+1)*72 + col] = (u16)(kx[t]>>16);
        VTs[(dg*8+t*2  )*72 + col] = (u16)(vx[t]&0xffff);
        VTs[(dg*8+t*2+1)*72 + col] = (u16)(vx[t]>>16);
      }
    }
    __syncthreads();
    bf16x8 qf[2][4];
    #pragma unroll
    for (int ti=0; ti<2; ++ti){
      #pragma unroll
      for (int ks=0; ks<4; ++ks)
        qf[ti][ks] = *(const bf16x8*)&Qs[(wr*32+ti*16+lc)*136 + ks*32 + lr*8];
    }
    f32x4 accO[2][4];
    #pragma unroll
    for (int i=0;i<2;i++){
      #pragma unroll
      for (int j=0;j<4;j++) accO[i][j]=Z4;
    }
    #pragma unroll
    for (int ks=0; ks<4; ++ks){
      bf16x8 bt[4];
      #pragma unroll
      for (int te=0; te<4; ++te)
        bt[te] = *(const bf16x8*)&Ts[tso + (wc*64+te*16+lc)*136 + ks*32 + lr*8];
      #pragma unroll
      for (int ti=0; ti<2; ++ti){
        #pragma unroll
        for (int te=0; te<4; ++te)
          accO[ti][te] = MFMA16(qf[ti][ks], bt[te], accO[ti][te]);
      }
    }
    f32x4 accP[2][2];
    #pragma unroll
    for (int i=0;i<2;i++){
      #pragma unroll
      for (int j=0;j<2;j++) accP[i][j]=Z4;
    }
    #pragma unroll
    for (int ks=0; ks<4; ++ks){
      bf16x8 bk[2];
      #pragma unroll
      for (int tj=0; tj<2; ++tj)
        bk[tj] = *(const bf16x8*)&Ks[(wc*32+tj*16+lc)*136 + ks*32 + lr*8];
      #pragma unroll
      for (int ti=0; ti<2; ++ti){
        #pragma unroll
        for (int tj=0; tj<2; ++tj)
          accP[ti][tj] = MFMA16(qf[ti][ks], bk[tj], accP[ti][tj]);
      }
    }
    #pragma unroll
    for (int ti=0; ti<2; ++ti){
      #pragma unroll
      for (int tj=0; tj<2; ++tj){
        #pragma unroll
        for (int r=0;r<4;r++){
          int i = wr*32+ti*16+lr*4+r;
          int j = wc*32+tj*16+lc;
          Ps[i*72 + j] = f2bf( (j<=i) ? accP[ti][tj][r] : 0.f );
        }
      }
    }
    __syncthreads();
    #pragma unroll
    for (int ks=0; ks<2; ++ks){
      bf16x8 ap[2], bv[4];
      #pragma unroll
      for (int ti=0; ti<2; ++ti)
        ap[ti] = *(const bf16x8*)&Ps[(wr*32+ti*16+lc)*72 + ks*32 + lr*8];
      #pragma unroll
      for (int te=0; te<4; ++te)
        bv[te] = *(const bf16x8*)&VTs[TSW(wc*64+te*16+lc, ks*4+lr)];
      #pragma unroll
      for (int ti=0; ti<2; ++ti){
        #pragma unroll
        for (int te=0; te<4; ++te)
          accO[ti][te] = MFMA16(ap[ti], bv[te], accO[ti][te]);
      }
    }
    #pragma unroll
    for (int ks=0; ks<2; ++ks){
      bf16x8 av[4], bk2[4];
      #pragma unroll
      for (int te=0; te<4; ++te)
        av[te] = *(const bf16x8*)&VTs[TSW(wr*64+te*16+lc, ks*4+lr)];
      #pragma unroll
      for (int td=0; td<4; ++td)
        bk2[td] = *(const bf16x8*)&KTs[TSW(wc*64+td*16+lc, ks*4+lr)];
      #pragma unroll
      for (int te=0; te<4; ++te){
        #pragma unroll
        for (int td=0; td<4; ++td)
          accT[te][td] = MFMA16(av[te], bk2[td], accT[te][td]);
      }
    }
    int tsn = tso ^ (128*136);
    #pragma unroll
    for (int te=0; te<4; ++te){
      #pragma unroll
      for (int td=0; td<4; ++td){
        int dk = wc*64+td*16+lc;
        #pragma unroll
        for (int r=0;r<4;r++){
          int erow = wr*64+te*16+lr*4+r;
          Ts[tsn + erow*136 + dk] = f2bf(accT[te][td][r]);
        }
      }
    }
    #pragma unroll
    for (int ti=0; ti<2; ++ti){
      #pragma unroll
      for (int te=0; te<4; ++te){
        int ecol = wc*64+te*16+lc;
        #pragma unroll
        for (int r=0;r<4;r++){
          int i = wr*32+ti*16+lr*4+r;
          ob[(size_t)(c*64+i)*1024 + ecol] = f2bf(accO[ti][te][r]);
        }
      }
    }
    __syncthreads();
    tso = tsn;
  }
}

// ---------- combine + per-head RMSNorm ----------
__global__ __launch_bounds__(256) void k_comb(const u16* __restrict__ o, const int* __restrict__ sel,
  const float* __restrict__ rw, const int* __restrict__ slot_of, const int* __restrict__ meta,
  const float* __restrict__ nw, u16* __restrict__ fin)
{
  int w=threadIdx.x>>6, lane=threadIdx.x&63;
  int tok = blockIdx.x*4 + w;
  int b = tok>>11;
  int sv = sel[tok];
  float acc[16];
  #pragma unroll
  for (int i=0;i<16;i++) acc[i]=0.f;
  #pragma unroll
  for (int kk=0; kk<2; ++kk){
    int e = kk ? ((sv>>8)&255) : (sv&255);
    int j = slot_of[tok*2 + kk];
    if (j < 0) continue;
    float wgt = rw[tok*2+kk];
    int row = meta[96 + b*8 + e] + j;
    const u16* orow = o + (size_t)row*1024 + lane*16;
    #pragma unroll
    for (int q=0;q<2;q++){
      u32x4 v = *(const u32x4*)(orow + q*8);
      #pragma unroll
      for (int t=0;t<4;t++){
        acc[q*8+t*2]   += wgt * bf2f((u16)(v[t]&0xffff));
        acc[q*8+t*2+1] += wgt * bf2f((u16)(v[t]>>16));
      }
    }
  }
  float ssq=0.f;
  #pragma unroll
  for (int i=0;i<16;i++) ssq += acc[i]*acc[i];
  ssq += __shfl_xor(ssq,1,64);
  ssq += __shfl_xor(ssq,2,64);
  ssq += __shfl_xor(ssq,4,64);
  float sc = rsqrtf(ssq*(1.f/128.f) + 1e-5f);
  int cbase = (lane&7)*16;
  u32x4 o0, o1;
  #pragma unroll
  for (int t=0;t<4;t++)
    o0[t] = pack2(acc[2*t]*sc*nw[cbase+2*t], acc[2*t+1]*sc*nw[cbase+2*t+1]);
  #pragma unroll
  for (int t=0;t<4;t++)
    o1[t] = pack2(acc[8+2*t]*sc*nw[cbase+8+2*t], acc[8+2*t+1]*sc*nw[cbase+8+2*t+1]);
  u16* fp = fin + (size_t)tok*1024 + lane*16;
  *(u32x4*)fp     = o0;
  *(u32x4*)(fp+8) = o1;
}

// ---------- host launcher ----------
extern "C" void kernel_launch(void* const* d_in, const int* in_sizes, int n_in,
                              void* d_out, int out_size, void* d_ws, size_t ws_size,
                              hipStream_t stream)
{
  (void)in_sizes; (void)n_in;
  const float* x     = (const float*)d_in[0];
  const float* gate  = (const float*)d_in[1];
  const float* q_w   = (const float*)d_in[2];
  const float* k_w   = (const float*)d_in[3];
  const float* v_w   = (const float*)d_in[4];
  const float* fmq1  = (const float*)d_in[5];
  const float* fmq2  = (const float*)d_in[6];
  const float* fmk1  = (const float*)d_in[7];
  const float* fmk2  = (const float*)d_in[8];
  const float* norm_w= (const float*)d_in[9];
  const float* o_w   = (const float*)d_in[10];
  float* out = (float*)d_out;

  uint8_t* ws = (uint8_t*)d_ws;
  size_t off = 0;
  auto alloc = [&](size_t bytes)->void*{ void* p = ws + off; off += (bytes + 255) & ~(size_t)255; return p; };
  int*   meta = (int*)alloc(4096);
  int*   sel  = (int*)alloc(8192*4);
  float* rwb  = (float*)alloc(8192*2*4);
  int*   slot = (int*)alloc(16384*4);
  int*   srcf = (int*)alloc((size_t)32*2048*4);
  int*   tokm = (int*)alloc((size_t)RMAX*4);
  u16* wA  = (u16*)alloc((size_t)2097152*2);           // q cat weights (2048x1024)
  u16* wVb = (u16*)alloc((size_t)8388608*2);           // v weights bf16 per expert
  u16* xb  = (u16*)alloc((size_t)8192*1024*2);         // bf16(x), token space
  u16* xg  = (u16*)alloc((size_t)RMAX*1024*2);
  u16* qh  = (u16*)alloc((size_t)8192*1024*2);         // q-hat, token space
  u16* kh  = (u16*)alloc((size_t)RMAX*1024*2);
  u16* vv  = (u16*)alloc((size_t)RMAX*1024*2);
  if (off > ws_size){
    hipMemsetAsync(d_out, 0x7F, (size_t)out_size*4, stream);
    return;
  }
  u16* wB  = (u16*)d_out;   // 33.5 MB k cat weights in output buffer (exact fit; dead before k_gemmO)
  u16* ob  = xg;            // reuse after GEMMs consumed xg
  u16* fin = qh;            // reuse after attn consumed qh
  u16* wOb = wA;            // reuse after k_gemmQKV consumed wA

  k_pre<<<3456,256,0,stream>>>(x, gate, sel, rwb, q_w, k_w, fmq1, fmq2, fmk1, fmk2, wA, wB, xb, v_w, wVb);
  k_count<<<32,256,0,stream>>>(sel, slot, srcf, meta);
  k_bases<<<1,64,0,stream>>>(meta);
  k_gather<<<dim3(32,32),256,0,stream>>>(xb, srcf, meta, xg, tokm);
  k_gemmQKV<<<1408,512,0,stream>>>(xb, xg, wA, wB, wVb, qh, kh, vv, meta);
  k_cvtO<<<32,256,0,stream>>>(o_w, wOb);
  k_attn<<<256,256,0,stream>>>(qh, kh, vv, ob, meta, tokm);
  k_comb<<<2048,256,0,stream>>>(ob, sel, rwb, slot, meta, norm_w, fin);
  k_gemmO<<<dim3(4,64),512,0,stream>>>(fin, wOb, out);
}

// Round 11
// 411.527 us; speedup vs baseline: 1.1165x; 1.1165x over previous
//
#include <hip/hip_runtime.h>
#include <stdint.h>

// ---------- types / helpers ----------
typedef unsigned short u16;
typedef unsigned int   u32;
typedef __attribute__((ext_vector_type(4))) float f32x4;
typedef __attribute__((ext_vector_type(4))) u32   u32x4;
typedef __attribute__((ext_vector_type(8))) __bf16 bf16x8;

#define MFMA16(a,b,c) __builtin_amdgcn_mfma_f32_16x16x32_bf16((a),(b),(c),0,0,0)

#define QSCALE 0.08838834764831845f   // 128^-0.5
#define RMAX   20480                  // sum roundup(min(n,2048),128) <= 16384+32*127

__device__ __forceinline__ float bf2f(u16 x){ u32 u=((u32)x)<<16; float f; __builtin_memcpy(&f,&u,4); return f; }
__device__ __forceinline__ u16 f2bf(float f){ u32 u; __builtin_memcpy(&u,&f,4); u = u + 0x7FFFu + ((u>>16)&1u); return (u16)(u>>16); }
__device__ __forceinline__ u32 pack2(float a, float b){ return (u32)f2bf(a) | ((u32)f2bf(b)<<16); }

// async global->LDS, 16B per lane
__device__ __forceinline__ void gl_lds(const u16* g, u16* l){
  __builtin_amdgcn_global_load_lds(
      (const __attribute__((address_space(1))) void*)g,
      (__attribute__((address_space(3))) void*)l, 16, 0, 0);
}

// transposed-tile addr with octet swizzle: row stride 72 u16; octet = (off8)>>3
#define TSW(row, oct) ((row)*72 + ((((oct) ^ (((row)>>3)&7)))<<3))

// meta layout (ints): [0,32) n  [32,64) nact  [64,96) npad  [96,129) base
// [129,161) nchunks  [161] R_total  [192,352) 128-tile -> group map

// ---------- device bodies for fused pre-pass ----------
__device__ __forceinline__ void cvt_body(const float* __restrict__ s, u16* __restrict__ d,
                                         long n8, int lb, int nb){
  long idx = (long)lb*256 + threadIdx.x;
  long stride = (long)nb*256;
  for (long i=idx; i<n8; i+=stride){
    const float* p = s + i*8;
    f32x4 a = *(const f32x4*)p;
    f32x4 b = *(const f32x4*)(p+4);
    u32x4 o;
    o[0]=pack2(a[0],a[1]); o[1]=pack2(a[2],a[3]); o[2]=pack2(b[0],b[1]); o[3]=pack2(b[2],b[3]);
    *(u32x4*)(d + i*8) = o;
  }
}

// route + write bf16(x): wave w holds token row in xv registers
__device__ __forceinline__ void route_body(const float* __restrict__ x, const float* __restrict__ gw,
  int* __restrict__ sel, float* __restrict__ rw, u16* __restrict__ xb, int lb)
{
  int w = threadIdx.x>>6, lane = threadIdx.x&63;
  int tok = lb*4 + w;
  const float* xr = x + (size_t)tok*1024 + lane*16;
  f32x4 xv[4];
  #pragma unroll
  for (int q=0;q<4;q++) xv[q] = *(const f32x4*)(xr + q*4);
  {
    u16* xrow = xb + (size_t)tok*1024 + lane*16;
    u32x4 o0, o1;
    o0[0]=pack2(xv[0][0],xv[0][1]); o0[1]=pack2(xv[0][2],xv[0][3]);
    o0[2]=pack2(xv[1][0],xv[1][1]); o0[3]=pack2(xv[1][2],xv[1][3]);
    o1[0]=pack2(xv[2][0],xv[2][1]); o1[1]=pack2(xv[2][2],xv[2][3]);
    o1[2]=pack2(xv[3][0],xv[3][1]); o1[3]=pack2(xv[3][2],xv[3][3]);
    *(u32x4*)xrow     = o0;
    *(u32x4*)(xrow+8) = o1;
  }
  float part[8];
  #pragma unroll
  for (int e=0;e<8;e++){
    const float* g = gw + e*1024 + lane*16;
    float s = 0.f;
    #pragma unroll
    for (int q=0;q<4;q++){
      f32x4 gv = *(const f32x4*)(g + q*4);
      s += xv[q][0]*gv[0] + xv[q][1]*gv[1] + xv[q][2]*gv[2] + xv[q][3]*gv[3];
    }
    part[e]=s;
  }
  #pragma unroll
  for (int e=0;e<8;e++){
    float v = part[e];
    #pragma unroll
    for (int off=32; off>0; off>>=1) v += __shfl_xor(v, off, 64);
    part[e]=v;
  }
  if (lane==0){
    int i0=0; float m0=part[0];
    #pragma unroll
    for (int e=1;e<8;e++) if (part[e]>m0){ m0=part[e]; i0=e; }
    int i1=0; float m1=-3.4e38f;
    #pragma unroll
    for (int e=0;e<8;e++) if (e!=i0 && part[e]>m1){ m1=part[e]; i1=e; }
    sel[tok] = i0 | (i1<<8);
    float e1 = expf(m1-m0);
    float inv = 1.f/(1.f+e1);
    rw[tok*2+0] = inv;
    rw[tok*2+1] = e1*inv;
  }
}

__device__ __forceinline__ void prep_body(
  const float* __restrict__ q_w, const float* __restrict__ k_w,
  const float* __restrict__ fmq1, const float* __restrict__ fmq2,
  const float* __restrict__ fmk1, const float* __restrict__ fmk2,
  u16* __restrict__ wA, u16* __restrict__ wB, int l, u16* shmem)
{
  int gi = l>>3;
  int c0 = (l&7)*128;
  const float* fm; const float* ws; u16* wd;
  if (gi < 8)      { int h=gi;    fm=fmq1; ws=q_w + (size_t)h*131072; wd=wA + (size_t)h*262144; }
  else if (gi < 16){ int h=gi-8;  fm=fmq2; ws=q_w + (size_t)h*131072; wd=wA + (size_t)h*262144 + 131072; }
  else if (gi < 80){ int t=gi-16, e=t>>3, h=t&7; fm=fmk1; ws=k_w + (size_t)(e*8+h)*131072; wd=wB + (size_t)e*2097152 + (size_t)h*262144; }
  else             { int t=gi-80, e=t>>3, h=t&7; fm=fmk2; ws=k_w + (size_t)(e*8+h)*131072; wd=wB + (size_t)e*2097152 + (size_t)h*262144 + 131072; }
  u16* Af = shmem;
  u16* Bf = shmem + 128*136;
  int tid = threadIdx.x;
  for (int i=tid; i<4096; i+=256){
    int row = i>>5, col = (i&31)*4;
    f32x4 v = *(const f32x4*)&fm[row*128 + col];
    u16* dp = &Af[row*136 + col];
    *(u32*)dp     = pack2(v[0],v[1]);
    *(u32*)(dp+2) = pack2(v[2],v[3]);
  }
  for (int i=tid; i<4096; i+=256){
    int dd = i>>5, cq = (i&31)*4;
    f32x4 v = *(const f32x4*)&ws[(size_t)dd*1024 + c0 + cq];
    #pragma unroll
    for (int j=0;j<4;j++){
      int c = cq+j;
      Bf[c*136 + (dd ^ (((c>>2)&3)<<3))] = f2bf(v[j]);
    }
  }
  __syncthreads();
  int lane=tid&63, w=tid>>6, wr=w>>1, wc=w&1, lc=lane&15, lr=lane>>4;
  const f32x4 Z4 = {0.f,0.f,0.f,0.f};
  f32x4 acc[4][4];
  #pragma unroll
  for (int i=0;i<4;i++){
    #pragma unroll
    for (int j=0;j<4;j++) acc[i][j]=Z4;
  }
  #pragma unroll
  for (int kk=0; kk<4; ++kk){
    bf16x8 a[4], b[4];
    #pragma unroll
    for (int mi=0;mi<4;mi++)
      a[mi] = *(const bf16x8*)&Af[(wr*64+mi*16+lc)*136 + kk*32 + lr*8];
    #pragma unroll
    for (int ni=0;ni<4;ni++){
      int c = wc*64+ni*16+lc;
      b[ni] = *(const bf16x8*)&Bf[c*136 + ((kk*32 + lr*8) ^ (((c>>2)&3)<<3))];
    }
    #pragma unroll
    for (int mi=0;mi<4;mi++){
      #pragma unroll
      for (int ni=0;ni<4;ni++)
        acc[mi][ni] = MFMA16(a[mi], b[ni], acc[mi][ni]);
    }
  }
  int r0=lr*4;
  #pragma unroll
  for (int mi=0;mi<4;mi++){
    #pragma unroll
    for (int ni=0;ni<4;ni++){
      int col = c0 + wc*64 + ni*16 + lc;
      #pragma unroll
      for (int r=0;r<4;r++){
        int row = wr*64 + mi*16 + r0 + r;
        wd[(size_t)row*1024 + col] = f2bf(acc[mi][ni][r]);
      }
    }
  }
}

// ---------- fused pre-pass: route+xb (0..2047) + prep (2048..3199) + cvt v_w (3200..3455) + cvt o_w (3456..3487) ----------
__global__ __launch_bounds__(256) void k_pre(
  const float* __restrict__ x, const float* __restrict__ gw,
  int* __restrict__ sel, float* __restrict__ rw,
  const float* __restrict__ q_w, const float* __restrict__ k_w,
  const float* __restrict__ fmq1, const float* __restrict__ fmq2,
  const float* __restrict__ fmk1, const float* __restrict__ fmk2,
  u16* __restrict__ wA, u16* __restrict__ wB, u16* __restrict__ xb,
  const float* __restrict__ v_w, u16* __restrict__ wVb,
  const float* __restrict__ o_w, u16* __restrict__ wOb, int* __restrict__ done)
{
  __shared__ __align__(16) u16 shmem[2*128*136];
  int bid = blockIdx.x;
  if (bid==0 && threadIdx.x==0) *done = 0;   // stream-ordered reset for k_count's last-block flag
  if (bid < 2048)      route_body(x, gw, sel, rw, xb, bid);
  else if (bid < 3200) prep_body(q_w, k_w, fmq1, fmq2, fmk1, fmk2, wA, wB, bid-2048, shmem);
  else if (bid < 3456) cvt_body(v_w, wVb, 1048576L, bid-3200, 256);
  else                 cvt_body(o_w, wOb, 131072L, bid-3456, 32);
}

// ---------- per-(b,e) counting sort + fused bases (last block) ----------
__global__ __launch_bounds__(256) void k_count(const int* __restrict__ sel,
  int* __restrict__ slot_of, int* __restrict__ src_of, int* __restrict__ meta,
  int* __restrict__ done)
{
  int g = blockIdx.x, b = g>>3, e = g&7;
  int tid = threadIdx.x;
  __shared__ int cn[256];
  unsigned char ex[16];
  int cnt=0;
  #pragma unroll
  for (int i=0;i<16;i++){
    int t = tid*16+i;
    int sv = sel[b*2048 + (t>>1)];
    int ee = (t&1) ? ((sv>>8)&255) : (sv&255);
    ex[i]=(unsigned char)ee;
    cnt += (ee==e);
  }
  cn[tid]=cnt;
  __syncthreads();
  for (int off=1; off<256; off<<=1){
    int v = (tid>=off) ? cn[tid-off] : 0;
    __syncthreads();
    cn[tid] += v;
    __syncthreads();
  }
  int total = cn[255];
  int run = cn[tid]-cnt;
  int shift = total>2048 ? total-2048 : 0;
  #pragma unroll
  for (int i=0;i<16;i++){
    int t = tid*16+i;
    if (ex[i]==e){
      int j = run - shift;
      run++;
      slot_of[b*4096 + t] = (j>=0)? j : -1;
      if (j>=0) src_of[g*2048 + j] = t;
    }
  }
  if (tid==0){
    meta[g]=total;
    __threadfence();
    if (atomicAdd(done,1)==31){
      // last block: compute bases (device-coherent reads via atomicAdd(p,0))
      int basev=0, t=0;
      meta[96]=0;
      for (int gg=0; gg<32; ++gg){
        int n = atomicAdd(&meta[gg],0);
        int nact = n<2048 ? n : 2048;
        int npad = (nact+127)&~127;
        meta[32+gg]=nact;
        meta[64+gg]=npad;
        meta[129+gg]=(nact+63)>>6;
        for (int i=0;i<(npad>>7);++i) meta[192+t++]=gg;
        basev += npad;
        meta[97+gg]=basev;
      }
      meta[161]=basev;
    }
  }
}

// ---------- gather bf16 rows -> compact + row->token map ----------
__global__ __launch_bounds__(256) void k_gather(const u16* __restrict__ xb,
  const int* __restrict__ src_of, const int* __restrict__ meta, u16* __restrict__ xg,
  int* __restrict__ tokmap)
{
  int g = blockIdx.y, jb = blockIdx.x;
  int npad = meta[64+g];
  if (jb*64 >= npad) return;
  int nact = meta[32+g], base = meta[96+g];
  int tid = threadIdx.x;
  int j = jb*64 + (tid>>2);
  int quart = tid&3;
  int src = (j<nact) ? src_of[g*2048+j] : -1;
  int token = (src>=0) ? ((g>>3)*2048 + (src>>1)) : 0;
  if (quart==0) tokmap[base+j] = token;
  u16* orow = xg + ((size_t)(base+j))*1024 + quart*256;
  if (src>=0){
    const u16* xr = xb + (size_t)token*1024 + quart*256;
    #pragma unroll
    for (int i=0;i<256;i+=8) *(u32x4*)(orow+i) = *(const u32x4*)(xr+i);
  } else {
    u32x4 z = {0,0,0,0};
    #pragma unroll
    for (int i=0;i<256;i+=8) *(u32x4*)(orow+i)=z;
  }
}

// ======== fused q+k+v 128x256 8-wave GEMM, depth-2 counted-vmcnt (T4) + swizzle (T2) ========
// blocks [0,512): q dual (A=xb, W=wA, M=8192, *QSCALE)
// blocks [512,1792): k dual (A=xg, W=wB per-expert)
// blocks [1792,2432): v single (A=xg, W=wVb per-expert, N=1024)
__global__ __launch_bounds__(512) void k_gemmQKV(const u16* __restrict__ xb, const u16* __restrict__ xg,
  const u16* __restrict__ wA, const u16* __restrict__ wB, const u16* __restrict__ wVb,
  u16* __restrict__ qh, u16* __restrict__ kh, u16* __restrict__ vv, const int* __restrict__ meta)
{
  int bid = blockIdx.x;
  int role, tm, tn;
  const u16 *A, *Wp; u16* outB;
  if (bid < 512){
    role=0; int l=bid, xcd=l&7, jj=l>>3, jd=jj>>3;
    tm=xcd*8+jd; tn=jj&7;
    A=xb; Wp=wA + (size_t)tn*262144; outB=qh;
  } else if (bid < 1792){
    role=1; int l=bid-512, xcd=l&7, jj=l>>3, jd=jj>>3;
    tm=xcd*20+jd; tn=jj&7;
    if (tm*128 >= meta[161]) return;
    A=xg; Wp=wB + (size_t)(meta[192+tm]&7)*2097152 + (size_t)tn*262144; outB=kh;
  } else {
    role=2; int l=bid-1792, xcd=l&7, jj=l>>3, jd=jj>>2;
    tm=xcd*20+jd; tn=jj&3;
    if (tm*128 >= meta[161]) return;
    A=xg; Wp=wVb + (size_t)(meta[192+tm]&7)*1048576 + (size_t)tn*262144; outB=vv;
  }

  __shared__ __align__(16) u16 smem[73728];   // 144 KB

  int tid=threadIdx.x, lane=tid&63;
  int w=tid>>6, wr=w>>2, wc=w&3, lc=lane&15, lr=lane>>4;
  int swz = lc&7;
  const f32x4 Z4 = {0.f,0.f,0.f,0.f};
  f32x4 acc[4][4];
  #pragma unroll
  for(int i=0;i<4;i++){
    #pragma unroll
    for(int j2=0;j2<4;j2++) acc[i][j2]=Z4;
  }
  size_t lanoff = (size_t)(tid>>3)*1024 + (size_t)(((tid&7)^((tid>>3)&7))*8);
  const u16* Ag = A  + (size_t)tm*131072 + lanoff;
  const u16* Bg = Wp + lanoff;
  int lo = tid*8;

  #define STAGEF(ao, bo, kt) { \
    const u16* ga = Ag + (kt)*64; const u16* gb = Bg + (kt)*64; \
    gl_lds(ga,                 &smem[(ao) + lo]); \
    gl_lds(ga + (size_t)65536, &smem[(ao) + 4096 + lo]); \
    gl_lds(gb,                  &smem[(bo) + lo]); \
    gl_lds(gb + (size_t)65536,  &smem[(bo) + 4096 + lo]); \
    gl_lds(gb + (size_t)131072, &smem[(bo) + 8192 + lo]); \
    gl_lds(gb + (size_t)196608, &smem[(bo) + 12288 + lo]); }

  STAGEF(0, 24576, 0);
  STAGEF(8192, 40960, 1);
  int cur = 0;
  for (int kt=0; kt<16; ++kt){
    if (kt<15) asm volatile("s_waitcnt vmcnt(6)" ::: "memory");
    else       asm volatile("s_waitcnt vmcnt(0)" ::: "memory");
    __builtin_amdgcn_s_barrier();
    if (kt<14){
      int nid = kt+2; nid -= (nid/3)*3;
      STAGEF(nid*8192, 24576+nid*16384, kt+2);
    }
    int ao = cur*8192, bo = 24576 + cur*16384;
    __builtin_amdgcn_s_setprio(1);
    #pragma unroll
    for (int kk=0; kk<2; ++kk){
      bf16x8 a[4], b[4];
      #pragma unroll
      for (int mi=0;mi<4;mi++){
        int row = wr*64+mi*16+lc;
        a[mi] = *(const bf16x8*)&smem[ao + row*64 + (((kk*4+lr)^swz)<<3)];
      }
      #pragma unroll
      for (int ni=0;ni<4;ni++){
        int row = wc*64+ni*16+lc;
        b[ni] = *(const bf16x8*)&smem[bo + row*64 + (((kk*4+lr)^swz)<<3)];
      }
      #pragma unroll
      for (int mi=0;mi<4;mi++){
        #pragma unroll
        for (int ni=0;ni<4;ni++)
          acc[mi][ni] = MFMA16(a[mi], b[ni], acc[mi][ni]);
      }
    }
    __builtin_amdgcn_s_setprio(0);
    cur = (cur==2)?0:cur+1;
  }
  __syncthreads();
  if (role < 2){
    // dual Hadamard: waves wc>=2 hold factor-2 (cat rows 128..255); stash f32, multiply in wc<2
    if (wc >= 2){
      #pragma unroll
      for (int mi=0;mi<4;mi++){
        #pragma unroll
        for (int ni=0;ni<4;ni++){
          int col = (wc-2)*64 + ni*16 + lc;
          #pragma unroll
          for (int r=0;r<4;r++)
            ((float*)smem)[(wr*64+mi*16+lr*4+r)*129 + col] = acc[mi][ni][r];
        }
      }
    }
    __syncthreads();
    if (wc < 2){
      float scl = (role==0) ? QSCALE : 1.0f;
      #pragma unroll
      for (int mi=0;mi<4;mi++){
        #pragma unroll
        for (int ni=0;ni<4;ni++){
          int col = wc*64 + ni*16 + lc;
          #pragma unroll
          for (int r=0;r<4;r++){
            int row = wr*64+mi*16+lr*4+r;
            float v = acc[mi][ni][r] * ((float*)smem)[row*129 + col] * scl;
            outB[(size_t)(tm*128+row)*1024 + tn*128 + col] = f2bf(v);
          }
        }
      }
    }
  } else {
    // v single: write full 256 cols
    #pragma unroll
    for (int mi=0;mi<4;mi++){
      #pragma unroll
      for (int ni=0;ni<4;ni++){
        int col = tn*256 + wc*64 + ni*16 + lc;
        #pragma unroll
        for (int r=0;r<4;r++){
          int row = tm*128 + wr*64 + mi*16 + lr*4 + r;
          outB[(size_t)row*1024 + col] = f2bf(acc[mi][ni][r]);
        }
      }
    }
  }
  #undef STAGEF
}

// ======== 128x256 8-wave single GEMM, T4+T2 pipeline (bf16 W) — final out proj ========
__global__ __launch_bounds__(512) void k_gemmO(const u16* __restrict__ A, const u16* __restrict__ W,
  float* __restrict__ outF)
{
  int tnN = gridDim.x;
  int bid = blockIdx.y*tnN + blockIdx.x;
  int chunk = gridDim.y >> 3;
  int xcd = bid & 7, j = bid >> 3;
  int jd = j / tnN;
  int tm = xcd*chunk + jd;
  int tn = j - jd*tnN;

  __shared__ __align__(16) u16 smem[73728];

  int tid=threadIdx.x, lane=tid&63;
  int w=tid>>6, wr=w>>2, wc=w&3, lc=lane&15, lr=lane>>4;
  int swz = lc&7;
  const f32x4 Z4 = {0.f,0.f,0.f,0.f};
  f32x4 acc[4][4];
  #pragma unroll
  for(int i=0;i<4;i++){
    #pragma unroll
    for(int j2=0;j2<4;j2++) acc[i][j2]=Z4;
  }
  size_t lanoff = (size_t)(tid>>3)*1024 + (size_t)(((tid&7)^((tid>>3)&7))*8);
  const u16* Ag = A + (size_t)tm*131072 + lanoff;
  const u16* Bg = W + (size_t)tn*262144 + lanoff;
  int lo = tid*8;

  #define STAGEO(ao, bo, kt) { \
    const u16* ga = Ag + (kt)*64; const u16* gb = Bg + (kt)*64; \
    gl_lds(ga,                 &smem[(ao) + lo]); \
    gl_lds(ga + (size_t)65536, &smem[(ao) + 4096 + lo]); \
    gl_lds(gb,                  &smem[(bo) + lo]); \
    gl_lds(gb + (size_t)65536,  &smem[(bo) + 4096 + lo]); \
    gl_lds(gb + (size_t)131072, &smem[(bo) + 8192 + lo]); \
    gl_lds(gb + (size_t)196608, &smem[(bo) + 12288 + lo]); }

  STAGEO(0, 24576, 0);
  STAGEO(8192, 40960, 1);
  int cur = 0;
  for (int kt=0; kt<16; ++kt){
    if (kt<15) asm volatile("s_waitcnt vmcnt(6)" ::: "memory");
    else       asm volatile("s_waitcnt vmcnt(0)" ::: "memory");
    __builtin_amdgcn_s_barrier();
    if (kt<14){
      int nid = kt+2; nid -= (nid/3)*3;
      STAGEO(nid*8192, 24576+nid*16384, kt+2);
    }
    int ao = cur*8192, bo = 24576 + cur*16384;
    __builtin_amdgcn_s_setprio(1);
    #pragma unroll
    for (int kk=0; kk<2; ++kk){
      bf16x8 a[4], b[4];
      #pragma unroll
      for (int mi=0;mi<4;mi++){
        int row = wr*64+mi*16+lc;
        a[mi] = *(const bf16x8*)&smem[ao + row*64 + (((kk*4+lr)^swz)<<3)];
      }
      #pragma unroll
      for (int ni=0;ni<4;ni++){
        int row = wc*64+ni*16+lc;
        b[ni] = *(const bf16x8*)&smem[bo + row*64 + (((kk*4+lr)^swz)<<3)];
      }
      #pragma unroll
      for (int mi=0;mi<4;mi++){
        #pragma unroll
        for (int ni=0;ni<4;ni++)
          acc[mi][ni] = MFMA16(a[mi], b[ni], acc[mi][ni]);
      }
    }
    __builtin_amdgcn_s_setprio(0);
    cur = (cur==2)?0:cur+1;
  }
  #pragma unroll
  for (int mi=0;mi<4;mi++){
    #pragma unroll
    for (int ni=0;ni<4;ni++){
      int col = tn*256 + wc*64 + ni*16 + lc;
      #pragma unroll
      for (int r=0;r<4;r++){
        int row = tm*128 + wr*64 + mi*16 + lr*4 + r;
        outF[(size_t)row*1024 + col] = acc[mi][ni][r];
      }
    }
  }
  #undef STAGEO
}

// ---------- chunked causal linear attention, one block per (group, head) ----------
// Ts ping-pong: 3 barriers/chunk
__global__ __launch_bounds__(256,1) void k_attn(const u16* __restrict__ qv, const u16* __restrict__ kv,
  const u16* __restrict__ vv, u16* __restrict__ o, const int* __restrict__ meta,
  const int* __restrict__ tokmap)
{
  int g = blockIdx.x>>3, h = blockIdx.x&7;
  int nch = meta[129+g];
  if (nch==0) return;
  int base = meta[96+g];
  __shared__ __align__(16) u16 Qs[64*136];
  __shared__ __align__(16) u16 Ks[64*136];
  __shared__ __align__(16) u16 KTs[128*72];
  __shared__ __align__(16) u16 VTs[128*72];
  __shared__ __align__(16) u16 Ts[2*128*136];
  __shared__ __align__(16) u16 Ps[64*72];
  int tid=threadIdx.x, w=tid>>6, lane=tid&63;
  int wr=w>>1, wc=w&1;
  int lr=lane>>4, lc=lane&15;
  {
    u32x4 z={0,0,0,0};
    for (int i=tid; i<128*136/8; i+=256) *(u32x4*)&Ts[i*8]=z;
  }
  const f32x4 Z4 = {0.f,0.f,0.f,0.f};
  f32x4 accT[4][4];
  #pragma unroll
  for (int i=0;i<4;i++){
    #pragma unroll
    for (int j=0;j<4;j++) accT[i][j]=Z4;
  }
  __syncthreads();
  const u16* kb = kv + (size_t)base*1024 + h*128;
  const u16* vb = vv + (size_t)base*1024 + h*128;
  u16* ob = o + (size_t)base*1024 + h*128;
  int tso = 0;

  for (int c=0; c<nch; ++c){
    #pragma unroll
    for (int it=0; it<4; ++it){
      int id = tid + it*256;
      int row = id>>4, kc = id&15;
      int tok = tokmap[base + c*64 + row];
      *(u32x4*)&Qs[row*136 + kc*8] = *(const u32x4*)(qv + (size_t)tok*1024 + h*128 + kc*8);
      *(u32x4*)&Ks[row*136 + kc*8] = *(const u32x4*)(kb + (size_t)(c*64+row)*1024 + kc*8);
    }
    #pragma unroll
    for (int it=0; it<4; ++it){
      int id = tid + it*256;
      int j = id>>4, dg = id&15;
      int col = (((j>>3) ^ (dg&7))<<3) + (j&7);
      u32x4 kx = *(const u32x4*)(kb + (size_t)(c*64+j)*1024 + dg*8);
      u32x4 vx = *(const u32x4*)(vb + (size_t)(c*64+j)*1024 + dg*8);
      #pragma unroll
      for (int t=0;t<4;t++){
        KTs[(dg*8+t*2  )*72 + col] = (u16)(kx[t]&0xffff);
        KTs[(dg*8+t*2+1)*72 + col] = (u16)(kx[t]>>16);
        VTs[(dg*8+t*2  )*72 + col] = (u16)(vx[t]&0xffff);
        VTs[(dg*8+t*2+1)*72 + col] = (u16)(vx[t]>>16);
      }
    }
    __syncthreads();
    bf16x8 qf[2][4];
    #pragma unroll
    for (int ti=0; ti<2; ++ti){
      #pragma unroll
      for (int ks=0; ks<4; ++ks)
        qf[ti][ks] = *(const bf16x8*)&Qs[(wr*32+ti*16+lc)*136 + ks*32 + lr*8];
    }
    f32x4 accO[2][4];
    #pragma unroll
    for (int i=0;i<2;i++){
      #pragma unroll
      for (int j=0;j<4;j++) accO[i][j]=Z4;
    }
    #pragma unroll
    for (int ks=0; ks<4; ++ks){
      bf16x8 bt[4];
      #pragma unroll
      for (int te=0; te<4; ++te)
        bt[te] = *(const bf16x8*)&Ts[tso + (wc*64+te*16+lc)*136 + ks*32 + lr*8];
      #pragma unroll
      for (int ti=0; ti<2; ++ti){
        #pragma unroll
        for (int te=0; te<4; ++te)
          accO[ti][te] = MFMA16(qf[ti][ks], bt[te], accO[ti][te]);
      }
    }
    f32x4 accP[2][2];
    #pragma unroll
    for (int i=0;i<2;i++){
      #pragma unroll
      for (int j=0;j<2;j++) accP[i][j]=Z4;
    }
    #pragma unroll
    for (int ks=0; ks<4; ++ks){
      bf16x8 bk[2];
      #pragma unroll
      for (int tj=0; tj<2; ++tj)
        bk[tj] = *(const bf16x8*)&Ks[(wc*32+tj*16+lc)*136 + ks*32 + lr*8];
      #pragma unroll
      for (int ti=0; ti<2; ++ti){
        #pragma unroll
        for (int tj=0; tj<2; ++tj)
          accP[ti][tj] = MFMA16(qf[ti][ks], bk[tj], accP[ti][tj]);
      }
    }
    #pragma unroll
    for (int ti=0; ti<2; ++ti){
      #pragma unroll
      for (int tj=0; tj<2; ++tj){
        #pragma unroll
        for (int r=0;r<4;r++){
          int i = wr*32+ti*16+lr*4+r;
          int j = wc*32+tj*16+lc;
          Ps[i*72 + j] = f2bf( (j<=i) ? accP[ti][tj][r] : 0.f );
        }
      }
    }
    __syncthreads();
    #pragma unroll
    for (int ks=0; ks<2; ++ks){
      bf16x8 ap[2], bv[4];
      #pragma unroll
      for (int ti=0; ti<2; ++ti)
        ap[ti] = *(const bf16x8*)&Ps[(wr*32+ti*16+lc)*72 + ks*32 + lr*8];
      #pragma unroll
      for (int te=0; te<4; ++te)
        bv[te] = *(const bf16x8*)&VTs[TSW(wc*64+te*16+lc, ks*4+lr)];
      #pragma unroll
      for (int ti=0; ti<2; ++ti){
        #pragma unroll
        for (int te=0; te<4; ++te)
          accO[ti][te] = MFMA16(ap[ti], bv[te], accO[ti][te]);
      }
    }
    #pragma unroll
    for (int ks=0; ks<2; ++ks){
      bf16x8 av[4], bk2[4];
      #pragma unroll
      for (int te=0; te<4; ++te)
        av[te] = *(const bf16x8*)&VTs[TSW(wr*64+te*16+lc, ks*4+lr)];
      #pragma unroll
      for (int td=0; td<4; ++td)
        bk2[td] = *(const bf16x8*)&KTs[TSW(wc*64+td*16+lc, ks*4+lr)];
      #pragma unroll
      for (int te=0; te<4; ++te){
        #pragma unroll
        for (int td=0; td<4; ++td)
          accT[te][td] = MFMA16(av[te], bk2[td], accT[te][td]);
      }
    }
    int tsn = tso ^ (128*136);
    #pragma unroll
    for (int te=0; te<4; ++te){
      #pragma unroll
      for (int td=0; td<4; ++td){
        int dk = wc*64+td*16+lc;
        #pragma unroll
        for (int r=0;r<4;r++){
          int erow = wr*64+te*16+lr*4+r;
          Ts[tsn + erow*136 + dk] = f2bf(accT[te][td][r]);
        }
      }
    }
    #pragma unroll
    for (int ti=0; ti<2; ++ti){
      #pragma unroll
      for (int te=0; te<4; ++te){
        int ecol = wc*64+te*16+lc;
        #pragma unroll
        for (int r=0;r<4;r++){
          int i = wr*32+ti*16+lr*4+r;
          ob[(size_t)(c*64+i)*1024 + ecol] = f2bf(accO[ti][te][r]);
        }
      }
    }
    __syncthreads();
    tso = tsn;
  }
}

// ---------- combine + per-head RMSNorm ----------
__global__ __launch_bounds__(256) void k_comb(const u16* __restrict__ o, const int* __restrict__ sel,
  const float* __restrict__ rw, const int* __restrict__ slot_of, const int* __restrict__ meta,
  const float* __restrict__ nw, u16* __restrict__ fin)
{
  int w=threadIdx.x>>6, lane=threadIdx.x&63;
  int tok = blockIdx.x*4 + w;
  int b = tok>>11;
  int sv = sel[tok];
  float acc[16];
  #pragma unroll
  for (int i=0;i<16;i++) acc[i]=0.f;
  #pragma unroll
  for (int kk=0; kk<2; ++kk){
    int e = kk ? ((sv>>8)&255) : (sv&255);
    int j = slot_of[tok*2 + kk];
    if (j < 0) continue;
    float wgt = rw[tok*2+kk];
    int row = meta[96 + b*8 + e] + j;
    const u16* orow = o + (size_t)row*1024 + lane*16;
    #pragma unroll
    for (int q=0;q<2;q++){
      u32x4 v = *(const u32x4*)(orow + q*8);
      #pragma unroll
      for (int t=0;t<4;t++){
        acc[q*8+t*2]   += wgt * bf2f((u16)(v[t]&0xffff));
        acc[q*8+t*2+1] += wgt * bf2f((u16)(v[t]>>16));
      }
    }
  }
  float ssq=0.f;
  #pragma unroll
  for (int i=0;i<16;i++) ssq += acc[i]*acc[i];
  ssq += __shfl_xor(ssq,1,64);
  ssq += __shfl_xor(ssq,2,64);
  ssq += __shfl_xor(ssq,4,64);
  float sc = rsqrtf(ssq*(1.f/128.f) + 1e-5f);
  int cbase = (lane&7)*16;
  u32x4 o0, o1;
  #pragma unroll
  for (int t=0;t<4;t++)
    o0[t] = pack2(acc[2*t]*sc*nw[cbase+2*t], acc[2*t+1]*sc*nw[cbase+2*t+1]);
  #pragma unroll
  for (int t=0;t<4;t++)
    o1[t] = pack2(acc[8+2*t]*sc*nw[cbase+8+2*t], acc[8+2*t+1]*sc*nw[cbase+8+2*t+1]);
  u16* fp = fin + (size_t)tok*1024 + lane*16;
  *(u32x4*)fp     = o0;
  *(u32x4*)(fp+8) = o1;
}

// ---------- host launcher ----------
extern "C" void kernel_launch(void* const* d_in, const int* in_sizes, int n_in,
                              void* d_out, int out_size, void* d_ws, size_t ws_size,
                              hipStream_t stream)
{
  (void)in_sizes; (void)n_in;
  const float* x     = (const float*)d_in[0];
  const float* gate  = (const float*)d_in[1];
  const float* q_w   = (const float*)d_in[2];
  const float* k_w   = (const float*)d_in[3];
  const float* v_w   = (const float*)d_in[4];
  const float* fmq1  = (const float*)d_in[5];
  const float* fmq2  = (const float*)d_in[6];
  const float* fmk1  = (const float*)d_in[7];
  const float* fmk2  = (const float*)d_in[8];
  const float* norm_w= (const float*)d_in[9];
  const float* o_w   = (const float*)d_in[10];
  float* out = (float*)d_out;

  uint8_t* ws = (uint8_t*)d_ws;
  size_t off = 0;
  auto alloc = [&](size_t bytes)->void*{ void* p = ws + off; off += (bytes + 255) & ~(size_t)255; return p; };
  int*   meta = (int*)alloc(4096);
  int*   sel  = (int*)alloc(8192*4);
  float* rwb  = (float*)alloc(8192*2*4);
  int*   slot = (int*)alloc(16384*4);
  int*   srcf = (int*)alloc((size_t)32*2048*4);
  int*   tokm = (int*)alloc((size_t)RMAX*4);
  int*   done = (int*)alloc(256);
  u16* wA  = (u16*)alloc((size_t)2097152*2);           // q cat weights (2048x1024)
  u16* wB  = (u16*)alloc((size_t)8*2097152*2);         // k cat weights per expert
  u16* wOb = (u16*)alloc((size_t)1048576*2);           // o_w bf16
  u16* xb  = (u16*)alloc((size_t)8192*1024*2);         // bf16(x), token space
  u16* xg  = (u16*)alloc((size_t)RMAX*1024*2);
  u16* qh  = (u16*)alloc((size_t)8192*1024*2);         // q-hat, token space
  u16* kh  = (u16*)alloc((size_t)RMAX*1024*2);
  u16* vv  = (u16*)alloc((size_t)RMAX*1024*2);
  if (off > ws_size){
    hipMemsetAsync(d_out, 0x7F, (size_t)out_size*4, stream);
    return;
  }
  u16* wVb = (u16*)d_out;   // 17 MB of the 33.5 MB output buffer as scratch (dead before k_gemmO)
  u16* ob  = xg;            // reuse after GEMMs consumed xg
  u16* fin = qh;            // reuse after attn consumed qh

  k_pre<<<3488,256,0,stream>>>(x, gate, sel, rwb, q_w, k_w, fmq1, fmq2, fmk1, fmk2, wA, wB, xb, v_w, wVb, o_w, wOb, done);
  k_count<<<32,256,0,stream>>>(sel, slot, srcf, meta, done);
  k_gather<<<dim3(32,32),256,0,stream>>>(xb, srcf, meta, xg, tokm);
  k_gemmQKV<<<2432,512,0,stream>>>(xb, xg, wA, wB, wVb, qh, kh, vv, meta);
  k_attn<<<256,256,0,stream>>>(qh, kh, vv, ob, meta, tokm);
  k_comb<<<2048,256,0,stream>>>(ob, sel, rwb, slot, meta, norm_w, fin);
  k_gemmO<<<dim3(4,64),512,0,stream>>>(fin, wOb, out);
}

// Round 12
// 405.948 us; speedup vs baseline: 1.1319x; 1.0137x over previous
//
#include <hip/hip_runtime.h>
#include <stdint.h>

// ---------- types / helpers ----------
typedef unsigned short u16;
typedef unsigned int   u32;
typedef __attribute__((ext_vector_type(4))) float f32x4;
typedef __attribute__((ext_vector_type(4))) u32   u32x4;
typedef __attribute__((ext_vector_type(8))) __bf16 bf16x8;

#define MFMA16(a,b,c) __builtin_amdgcn_mfma_f32_16x16x32_bf16((a),(b),(c),0,0,0)

#define QSCALE 0.08838834764831845f   // 128^-0.5
#define RMAX   24576                  // sum roundup(min(n,2048),256) <= 16384+32*255

__device__ __forceinline__ float bf2f(u16 x){ u32 u=((u32)x)<<16; float f; __builtin_memcpy(&f,&u,4); return f; }
__device__ __forceinline__ u16 f2bf(float f){ u32 u; __builtin_memcpy(&u,&f,4); u = u + 0x7FFFu + ((u>>16)&1u); return (u16)(u>>16); }
__device__ __forceinline__ u32 pack2(float a, float b){ return (u32)f2bf(a) | ((u32)f2bf(b)<<16); }

// async global->LDS, 16B per lane
__device__ __forceinline__ void gl_lds(const u16* g, u16* l){
  __builtin_amdgcn_global_load_lds(
      (const __attribute__((address_space(1))) void*)g,
      (__attribute__((address_space(3))) void*)l, 16, 0, 0);
}

// transposed-tile addr with octet swizzle (attn): row stride 72 u16
#define TSW(row, oct) ((row)*72 + ((((oct) ^ (((row)>>3)&7)))<<3))

// meta layout (ints): [0,32) n  [32,64) nact  [64,96) npad  [96,129) base
// [129,161) nchunks  [161] R_total  [192,352) 256-tile -> group map

// ---------- device bodies for fused pre-pass ----------
__device__ __forceinline__ void cvt_body(const float* __restrict__ s, u16* __restrict__ d,
                                         long n8, int lb, int nb){
  long idx = (long)lb*256 + threadIdx.x;
  long stride = (long)nb*256;
  for (long i=idx; i<n8; i+=stride){
    const float* p = s + i*8;
    f32x4 a = *(const f32x4*)p;
    f32x4 b = *(const f32x4*)(p+4);
    u32x4 o;
    o[0]=pack2(a[0],a[1]); o[1]=pack2(a[2],a[3]); o[2]=pack2(b[0],b[1]); o[3]=pack2(b[2],b[3]);
    *(u32x4*)(d + i*8) = o;
  }
}

__device__ __forceinline__ void route_body(const float* __restrict__ x, const float* __restrict__ gw,
  int* __restrict__ sel, float* __restrict__ rw, u16* __restrict__ xb, int lb)
{
  int w = threadIdx.x>>6, lane = threadIdx.x&63;
  int tok = lb*4 + w;
  const float* xr = x + (size_t)tok*1024 + lane*16;
  f32x4 xv[4];
  #pragma unroll
  for (int q=0;q<4;q++) xv[q] = *(const f32x4*)(xr + q*4);
  {
    u16* xrow = xb + (size_t)tok*1024 + lane*16;
    u32x4 o0, o1;
    o0[0]=pack2(xv[0][0],xv[0][1]); o0[1]=pack2(xv[0][2],xv[0][3]);
    o0[2]=pack2(xv[1][0],xv[1][1]); o0[3]=pack2(xv[1][2],xv[1][3]);
    o1[0]=pack2(xv[2][0],xv[2][1]); o1[1]=pack2(xv[2][2],xv[2][3]);
    o1[2]=pack2(xv[3][0],xv[3][1]); o1[3]=pack2(xv[3][2],xv[3][3]);
    *(u32x4*)xrow     = o0;
    *(u32x4*)(xrow+8) = o1;
  }
  float part[8];
  #pragma unroll
  for (int e=0;e<8;e++){
    const float* g = gw + e*1024 + lane*16;
    float s = 0.f;
    #pragma unroll
    for (int q=0;q<4;q++){
      f32x4 gv = *(const f32x4*)(g + q*4);
      s += xv[q][0]*gv[0] + xv[q][1]*gv[1] + xv[q][2]*gv[2] + xv[q][3]*gv[3];
    }
    part[e]=s;
  }
  #pragma unroll
  for (int e=0;e<8;e++){
    float v = part[e];
    #pragma unroll
    for (int off=32; off>0; off>>=1) v += __shfl_xor(v, off, 64);
    part[e]=v;
  }
  if (lane==0){
    int i0=0; float m0=part[0];
    #pragma unroll
    for (int e=1;e<8;e++) if (part[e]>m0){ m0=part[e]; i0=e; }
    int i1=0; float m1=-3.4e38f;
    #pragma unroll
    for (int e=0;e<8;e++) if (e!=i0 && part[e]>m1){ m1=part[e]; i1=e; }
    sel[tok] = i0 | (i1<<8);
    float e1 = expf(m1-m0);
    float inv = 1.f/(1.f+e1);
    rw[tok*2+0] = inv;
    rw[tok*2+1] = e1*inv;
  }
}

__device__ __forceinline__ void prep_body(
  const float* __restrict__ q_w, const float* __restrict__ k_w,
  const float* __restrict__ fmq1, const float* __restrict__ fmq2,
  const float* __restrict__ fmk1, const float* __restrict__ fmk2,
  u16* __restrict__ wA, u16* __restrict__ wB, int l, u16* shmem)
{
  int gi = l>>3;
  int c0 = (l&7)*128;
  const float* fm; const float* ws; u16* wd;
  if (gi < 8)      { int h=gi;    fm=fmq1; ws=q_w + (size_t)h*131072; wd=wA + (size_t)h*262144; }
  else if (gi < 16){ int h=gi-8;  fm=fmq2; ws=q_w + (size_t)h*131072; wd=wA + (size_t)h*262144 + 131072; }
  else if (gi < 80){ int t=gi-16, e=t>>3, h=t&7; fm=fmk1; ws=k_w + (size_t)(e*8+h)*131072; wd=wB + (size_t)e*2097152 + (size_t)h*262144; }
  else             { int t=gi-80, e=t>>3, h=t&7; fm=fmk2; ws=k_w + (size_t)(e*8+h)*131072; wd=wB + (size_t)e*2097152 + (size_t)h*262144 + 131072; }
  u16* Af = shmem;
  u16* Bf = shmem + 128*136;
  int tid = threadIdx.x;
  for (int i=tid; i<4096; i+=256){
    int row = i>>5, col = (i&31)*4;
    f32x4 v = *(const f32x4*)&fm[row*128 + col];
    u16* dp = &Af[row*136 + col];
    *(u32*)dp     = pack2(v[0],v[1]);
    *(u32*)(dp+2) = pack2(v[2],v[3]);
  }
  for (int i=tid; i<4096; i+=256){
    int dd = i>>5, cq = (i&31)*4;
    f32x4 v = *(const f32x4*)&ws[(size_t)dd*1024 + c0 + cq];
    #pragma unroll
    for (int j=0;j<4;j++){
      int c = cq+j;
      Bf[c*136 + (dd ^ (((c>>2)&3)<<3))] = f2bf(v[j]);
    }
  }
  __syncthreads();
  int lane=tid&63, w=tid>>6, wr=w>>1, wc=w&1, lc=lane&15, lr=lane>>4;
  const f32x4 Z4 = {0.f,0.f,0.f,0.f};
  f32x4 acc[4][4];
  #pragma unroll
  for (int i=0;i<4;i++){
    #pragma unroll
    for (int j=0;j<4;j++) acc[i][j]=Z4;
  }
  #pragma unroll
  for (int kk=0; kk<4; ++kk){
    bf16x8 a[4], b[4];
    #pragma unroll
    for (int mi=0;mi<4;mi++)
      a[mi] = *(const bf16x8*)&Af[(wr*64+mi*16+lc)*136 + kk*32 + lr*8];
    #pragma unroll
    for (int ni=0;ni<4;ni++){
      int c = wc*64+ni*16+lc;
      b[ni] = *(const bf16x8*)&Bf[c*136 + ((kk*32 + lr*8) ^ (((c>>2)&3)<<3))];
    }
    #pragma unroll
    for (int mi=0;mi<4;mi++){
      #pragma unroll
      for (int ni=0;ni<4;ni++)
        acc[mi][ni] = MFMA16(a[mi], b[ni], acc[mi][ni]);
    }
  }
  int r0=lr*4;
  #pragma unroll
  for (int mi=0;mi<4;mi++){
    #pragma unroll
    for (int ni=0;ni<4;ni++){
      int col = c0 + wc*64 + ni*16 + lc;
      #pragma unroll
      for (int r=0;r<4;r++){
        int row = wr*64 + mi*16 + r0 + r;
        wd[(size_t)row*1024 + col] = f2bf(acc[mi][ni][r]);
      }
    }
  }
}

// ---------- fused pre-pass: route+xb (0..2047) + prep (2048..3199) + cvt v_w (3200..3455) + cvt o_w (3456..3487) ----------
__global__ __launch_bounds__(256) void k_pre(
  const float* __restrict__ x, const float* __restrict__ gw,
  int* __restrict__ sel, float* __restrict__ rw,
  const float* __restrict__ q_w, const float* __restrict__ k_w,
  const float* __restrict__ fmq1, const float* __restrict__ fmq2,
  const float* __restrict__ fmk1, const float* __restrict__ fmk2,
  u16* __restrict__ wA, u16* __restrict__ wB, u16* __restrict__ xb,
  const float* __restrict__ v_w, u16* __restrict__ wVb,
  const float* __restrict__ o_w, u16* __restrict__ wOb, int* __restrict__ done)
{
  __shared__ __align__(16) u16 shmem[2*128*136];
  int bid = blockIdx.x;
  if (bid==0 && threadIdx.x==0) *done = 0;
  if (bid < 2048)      route_body(x, gw, sel, rw, xb, bid);
  else if (bid < 3200) prep_body(q_w, k_w, fmq1, fmq2, fmk1, fmk2, wA, wB, bid-2048, shmem);
  else if (bid < 3456) cvt_body(v_w, wVb, 1048576L, bid-3200, 256);
  else                 cvt_body(o_w, wOb, 131072L, bid-3456, 32);
}

// ---------- per-(b,e) counting sort + fused bases (256-pad, last block) ----------
__global__ __launch_bounds__(256) void k_count(const int* __restrict__ sel,
  int* __restrict__ slot_of, int* __restrict__ src_of, int* __restrict__ meta,
  int* __restrict__ done)
{
  int g = blockIdx.x, b = g>>3, e = g&7;
  int tid = threadIdx.x;
  __shared__ int cn[256];
  unsigned char ex[16];
  int cnt=0;
  #pragma unroll
  for (int i=0;i<16;i++){
    int t = tid*16+i;
    int sv = sel[b*2048 + (t>>1)];
    int ee = (t&1) ? ((sv>>8)&255) : (sv&255);
    ex[i]=(unsigned char)ee;
    cnt += (ee==e);
  }
  cn[tid]=cnt;
  __syncthreads();
  for (int off=1; off<256; off<<=1){
    int v = (tid>=off) ? cn[tid-off] : 0;
    __syncthreads();
    cn[tid] += v;
    __syncthreads();
  }
  int total = cn[255];
  int run = cn[tid]-cnt;
  int shift = total>2048 ? total-2048 : 0;
  #pragma unroll
  for (int i=0;i<16;i++){
    int t = tid*16+i;
    if (ex[i]==e){
      int j = run - shift;
      run++;
      slot_of[b*4096 + t] = (j>=0)? j : -1;
      if (j>=0) src_of[g*2048 + j] = t;
    }
  }
  if (tid==0){
    meta[g]=total;
    __threadfence();
    if (atomicAdd(done,1)==31){
      int basev=0, t=0;
      meta[96]=0;
      for (int gg=0; gg<32; ++gg){
        int n = atomicAdd(&meta[gg],0);
        int nact = n<2048 ? n : 2048;
        int npad = (nact+255)&~255;
        meta[32+gg]=nact;
        meta[64+gg]=npad;
        meta[129+gg]=(nact+63)>>6;
        for (int i=0;i<(npad>>8);++i) meta[192+t++]=gg;
        basev += npad;
        meta[97+gg]=basev;
      }
      meta[161]=basev;
    }
  }
}

// ---------- gather bf16 rows -> compact + row->token map ----------
__global__ __launch_bounds__(256) void k_gather(const u16* __restrict__ xb,
  const int* __restrict__ src_of, const int* __restrict__ meta, u16* __restrict__ xg,
  int* __restrict__ tokmap)
{
  int g = blockIdx.y, jb = blockIdx.x;
  int npad = meta[64+g];
  if (jb*64 >= npad) return;
  int nact = meta[32+g], base = meta[96+g];
  int tid = threadIdx.x;
  int j = jb*64 + (tid>>2);
  int quart = tid&3;
  int src = (j<nact) ? src_of[g*2048+j] : -1;
  int token = (src>=0) ? ((g>>3)*2048 + (src>>1)) : 0;
  if (quart==0) tokmap[base+j] = token;
  u16* orow = xg + ((size_t)(base+j))*1024 + quart*256;
  if (src>=0){
    const u16* xr = xb + (size_t)token*1024 + quart*256;
    #pragma unroll
    for (int i=0;i<256;i+=8) *(u32x4*)(orow+i) = *(const u32x4*)(xr+i);
  } else {
    u32x4 z = {0,0,0,0};
    #pragma unroll
    for (int i=0;i<256;i+=8) *(u32x4*)(orow+i)=z;
  }
}

// ======== fused q+k+v 256x256 8-wave GEMM, BK=64, 4-phase/K-tile, counted vmcnt(4) ========
// blocks [0,256): q dual (A=xb, W=wA, M=8192, *QSCALE)
// blocks [256,1024): k dual (A=xg, W=wB per-expert)
// blocks [1024,1408): v single (A=xg, W=wVb per-expert, N=1024)
// LDS 128 KB: buf d: A at d*32768, B at d*32768+16384. Per wave: 128x64 output (8x4 frags).
// Phase j (j=0..3): rows {2j,2j+1}; B frags (8) held from j0.
// Staging: j0: A(t+1)-lo -> other buf ; j1: A(t+1)-hi ; j2: B(t+2)-lo -> same buf ; j3: B(t+2)-hi.
__global__ __launch_bounds__(512,2) void k_gemmQKV(const u16* __restrict__ xb, const u16* __restrict__ xg,
  const u16* __restrict__ wA, const u16* __restrict__ wB, const u16* __restrict__ wVb,
  u16* __restrict__ qh, u16* __restrict__ kh, u16* __restrict__ vv, const int* __restrict__ meta)
{
  int bid = blockIdx.x;
  int role, tm, tn;
  const u16 *A, *Wp; u16* outB;
  if (bid < 256){
    role=0; int l=bid, xcd=l&7, jj=l>>3, jd=jj>>3;
    tm=xcd*4+jd; tn=jj&7;
    A=xb; Wp=wA + (size_t)tn*262144; outB=qh;
  } else if (bid < 1024){
    role=1; int l=bid-256, xcd=l&7, jj=l>>3, jd=jj>>3;
    tm=xcd*12+jd; tn=jj&7;
    if (tm*256 >= meta[161]) return;
    A=xg; Wp=wB + (size_t)(meta[192+tm]&7)*2097152 + (size_t)tn*262144; outB=kh;
  } else {
    role=2; int l=bid-1024, xcd=l&7, jj=l>>3, jd=jj>>2;
    tm=xcd*12+jd; tn=jj&3;
    if (tm*256 >= meta[161]) return;
    A=xg; Wp=wVb + (size_t)(meta[192+tm]&7)*1048576 + (size_t)tn*262144; outB=vv;
  }

  __shared__ __align__(16) u16 smem[65536];   // 128 KB

  int tid=threadIdx.x, lane=tid&63;
  int w=tid>>6, wr=w>>2, wc=w&3, lc=lane&15, lr=lane>>4;
  int swz = lc&7;
  int ck0 = ((lr)^swz)<<3;
  int ck1 = ((4+lr)^swz)<<3;
  int arow = (wr*128 + lc)*64;           // + mi*1024 + ck
  int brow = 16384 + (wc*64 + lc)*64;    // + ni*1024 + ck
  const f32x4 Z4 = {0.f,0.f,0.f,0.f};
  f32x4 acc[8][4];
  #pragma unroll
  for(int i=0;i<8;i++){
    #pragma unroll
    for(int j2=0;j2<4;j2++) acc[i][j2]=Z4;
  }
  int rowlane = tid>>3;
  int gch = ((tid&7)^(rowlane&7))*8;     // pre-swizzled source chunk
  const u16* Asrc = A  + (size_t)tm*262144 + (size_t)rowlane*1024 + gch;
  const u16* Bsrc = Wp + (size_t)rowlane*1024 + gch;

  // one half-tile (128 rows x 64 cols) = 2 gl_lds calls
  #define STG2(dst, src) { \
    gl_lds((src),         &smem[(dst) + tid*8]); \
    gl_lds((src) + 65536, &smem[(dst) + 4096 + tid*8]); }

  // prologue: B0, A0, B1  (order makes vmcnt(4) uniform)
  STG2(16384, Bsrc);                         // B0-lo
  STG2(24576, Bsrc + 131072);                // B0-hi
  STG2(0,     Asrc);                         // A0-lo
  STG2(8192,  Asrc + 131072);                // A0-hi
  STG2(49152, Bsrc + 64);                    // B1-lo
  STG2(57344, Bsrc + 131072 + 64);           // B1-hi

  for (int t=0; t<16; ++t){
    int d = (t&1)<<15;
    bf16x8 b0[4], b1[4];
    #pragma unroll
    for (int j=0; j<4; ++j){
      if (j==0){
        if (t<15) asm volatile("s_waitcnt vmcnt(4)" ::: "memory");
        else      asm volatile("s_waitcnt vmcnt(0)" ::: "memory");
      }
      __builtin_amdgcn_s_barrier();
      if (j==0){
        #pragma unroll
        for (int ni=0;ni<4;ni++){
          b0[ni] = *(const bf16x8*)&smem[d + brow + ni*1024 + ck0];
          b1[ni] = *(const bf16x8*)&smem[d + brow + ni*1024 + ck1];
        }
      }
      bf16x8 a00 = *(const bf16x8*)&smem[d + arow + (2*j  )*1024 + ck0];
      bf16x8 a01 = *(const bf16x8*)&smem[d + arow + (2*j+1)*1024 + ck0];
      bf16x8 a10 = *(const bf16x8*)&smem[d + arow + (2*j  )*1024 + ck1];
      bf16x8 a11 = *(const bf16x8*)&smem[d + arow + (2*j+1)*1024 + ck1];
      if (j==0 && t<15) STG2(((t+1)&1)<<15,            Asrc + (size_t)(t+1)*64);
      if (j==1 && t<15) STG2((((t+1)&1)<<15) + 8192,   Asrc + 131072 + (size_t)(t+1)*64);
      if (j==2 && t<14) STG2(d + 16384,                Bsrc + (size_t)(t+2)*64);
      if (j==3 && t<14) STG2(d + 24576,                Bsrc + 131072 + (size_t)(t+2)*64);
      __builtin_amdgcn_s_setprio(1);
      #pragma unroll
      for (int ni=0;ni<4;ni++){
        acc[2*j  ][ni] = MFMA16(a00, b0[ni], acc[2*j  ][ni]);
        acc[2*j+1][ni] = MFMA16(a01, b0[ni], acc[2*j+1][ni]);
      }
      #pragma unroll
      for (int ni=0;ni<4;ni++){
        acc[2*j  ][ni] = MFMA16(a10, b1[ni], acc[2*j  ][ni]);
        acc[2*j+1][ni] = MFMA16(a11, b1[ni], acc[2*j+1][ni]);
      }
      __builtin_amdgcn_s_setprio(0);
    }
  }
  #undef STG2

  __syncthreads();
  if (role < 2){
    // Hadamard: waves wc>=2 hold factor-2 (cat rows 128..255); stash f32 (256x128), multiply in wc<2
    if (wc >= 2){
      #pragma unroll
      for (int mi=0;mi<8;mi++){
        #pragma unroll
        for (int ni=0;ni<4;ni++){
          int col = (wc-2)*64 + ni*16 + lc;
          #pragma unroll
          for (int r=0;r<4;r++)
            ((float*)smem)[(wr*128+mi*16+lr*4+r)*128 + col] = acc[mi][ni][r];
        }
      }
    }
    __syncthreads();
    if (wc < 2){
      float scl = (role==0) ? QSCALE : 1.0f;
      #pragma unroll
      for (int mi=0;mi<8;mi++){
        #pragma unroll
        for (int ni=0;ni<4;ni++){
          int col = wc*64 + ni*16 + lc;
          #pragma unroll
          for (int r=0;r<4;r++){
            int row = wr*128+mi*16+lr*4+r;
            float v = acc[mi][ni][r] * ((float*)smem)[row*128 + col] * scl;
            outB[(size_t)(tm*256+row)*1024 + tn*128 + col] = f2bf(v);
          }
        }
      }
    }
  } else {
    #pragma unroll
    for (int mi=0;mi<8;mi++){
      #pragma unroll
      for (int ni=0;ni<4;ni++){
        int col = tn*256 + wc*64 + ni*16 + lc;
        #pragma unroll
        for (int r=0;r<4;r++){
          int row = tm*256 + wr*128 + mi*16 + lr*4 + r;
          outB[(size_t)row*1024 + col] = f2bf(acc[mi][ni][r]);
        }
      }
    }
  }
}

// ======== 128x256 8-wave single GEMM, T4+T2 pipeline — final out proj ========
__global__ __launch_bounds__(512) void k_gemmO(const u16* __restrict__ A, const u16* __restrict__ W,
  float* __restrict__ outF)
{
  int tnN = gridDim.x;
  int bid = blockIdx.y*tnN + blockIdx.x;
  int chunk = gridDim.y >> 3;
  int xcd = bid & 7, j = bid >> 3;
  int jd = j / tnN;
  int tm = xcd*chunk + jd;
  int tn = j - jd*tnN;

  __shared__ __align__(16) u16 smem[73728];

  int tid=threadIdx.x, lane=tid&63;
  int w=tid>>6, wr=w>>2, wc=w&3, lc=lane&15, lr=lane>>4;
  int swz = lc&7;
  const f32x4 Z4 = {0.f,0.f,0.f,0.f};
  f32x4 acc[4][4];
  #pragma unroll
  for(int i=0;i<4;i++){
    #pragma unroll
    for(int j2=0;j2<4;j2++) acc[i][j2]=Z4;
  }
  size_t lanoff = (size_t)(tid>>3)*1024 + (size_t)(((tid&7)^((tid>>3)&7))*8);
  const u16* Ag = A + (size_t)tm*131072 + lanoff;
  const u16* Bg = W + (size_t)tn*262144 + lanoff;
  int lo = tid*8;

  #define STAGEO(ao, bo, kt) { \
    const u16* ga = Ag + (kt)*64; const u16* gb = Bg + (kt)*64; \
    gl_lds(ga,                 &smem[(ao) + lo]); \
    gl_lds(ga + (size_t)65536, &smem[(ao) + 4096 + lo]); \
    gl_lds(gb,                  &smem[(bo) + lo]); \
    gl_lds(gb + (size_t)65536,  &smem[(bo) + 4096 + lo]); \
    gl_lds(gb + (size_t)131072, &smem[(bo) + 8192 + lo]); \
    gl_lds(gb + (size_t)196608, &smem[(bo) + 12288 + lo]); }

  STAGEO(0, 24576, 0);
  STAGEO(8192, 40960, 1);
  int cur = 0;
  for (int kt=0; kt<16; ++kt){
    if (kt<15) asm volatile("s_waitcnt vmcnt(6)" ::: "memory");
    else       asm volatile("s_waitcnt vmcnt(0)" ::: "memory");
    __builtin_amdgcn_s_barrier();
    if (kt<14){
      int nid = kt+2; nid -= (nid/3)*3;
      STAGEO(nid*8192, 24576+nid*16384, kt+2);
    }
    int ao = cur*8192, bo = 24576 + cur*16384;
    __builtin_amdgcn_s_setprio(1);
    #pragma unroll
    for (int kk=0; kk<2; ++kk){
      bf16x8 a[4], b[4];
      #pragma unroll
      for (int mi=0;mi<4;mi++){
        int row = wr*64+mi*16+lc;
        a[mi] = *(const bf16x8*)&smem[ao + row*64 + (((kk*4+lr)^swz)<<3)];
      }
      #pragma unroll
      for (int ni=0;ni<4;ni++){
        int row = wc*64+ni*16+lc;
        b[ni] = *(const bf16x8*)&smem[bo + row*64 + (((kk*4+lr)^swz)<<3)];
      }
      #pragma unroll
      for (int mi=0;mi<4;mi++){
        #pragma unroll
        for (int ni=0;ni<4;ni++)
          acc[mi][ni] = MFMA16(a[mi], b[ni], acc[mi][ni]);
      }
    }
    __builtin_amdgcn_s_setprio(0);
    cur = (cur==2)?0:cur+1;
  }
  #pragma unroll
  for (int mi=0;mi<4;mi++){
    #pragma unroll
    for (int ni=0;ni<4;ni++){
      int col = tn*256 + wc*64 + ni*16 + lc;
      #pragma unroll
      for (int r=0;r<4;r++){
        int row = tm*128 + wr*64 + mi*16 + lr*4 + r;
        outF[(size_t)row*1024 + col] = acc[mi][ni][r];
      }
    }
  }
  #undef STAGEO
}

// ---------- chunked causal linear attention, one block per (group, head) ----------
__global__ __launch_bounds__(256,1) void k_attn(const u16* __restrict__ qv, const u16* __restrict__ kv,
  const u16* __restrict__ vv, u16* __restrict__ o, const int* __restrict__ meta,
  const int* __restrict__ tokmap)
{
  int g = blockIdx.x>>3, h = blockIdx.x&7;
  int nch = meta[129+g];
  if (nch==0) return;
  int base = meta[96+g];
  __shared__ __align__(16) u16 Qs[64*136];
  __shared__ __align__(16) u16 Ks[64*136];
  __shared__ __align__(16) u16 KTs[128*72];
  __shared__ __align__(16) u16 VTs[128*72];
  __shared__ __align__(16) u16 Ts[2*128*136];
  __shared__ __align__(16) u16 Ps[64*72];
  int tid=threadIdx.x, w=tid>>6, lane=tid&63;
  int wr=w>>1, wc=w&1;
  int lr=lane>>4, lc=lane&15;
  {
    u32x4 z={0,0,0,0};
    for (int i=tid; i<128*136/8; i+=256) *(u32x4*)&Ts[i*8]=z;
  }
  const f32x4 Z4 = {0.f,0.f,0.f,0.f};
  f32x4 accT[4][4];
  #pragma unroll
  for (int i=0;i<4;i++){
    #pragma unroll
    for (int j=0;j<4;j++) accT[i][j]=Z4;
  }
  __syncthreads();
  const u16* kb = kv + (size_t)base*1024 + h*128;
  const u16* vb = vv + (size_t)base*1024 + h*128;
  u16* ob = o + (size_t)base*1024 + h*128;
  int tso = 0;

  for (int c=0; c<nch; ++c){
    #pragma unroll
    for (int it=0; it<4; ++it){
      int id = tid + it*256;
      int row = id>>4, kc = id&15;
      int tok = tokmap[base + c*64 + row];
      *(u32x4*)&Qs[row*136 + kc*8] = *(const u32x4*)(qv + (size_t)tok*1024 + h*128 + kc*8);
      *(u32x4*)&Ks[row*136 + kc*8] = *(const u32x4*)(kb + (size_t)(c*64+row)*1024 + kc*8);
    }
    #pragma unroll
    for (int it=0; it<4; ++it){
      int id = tid + it*256;
      int j = id>>4, dg = id&15;
      int col = (((j>>3) ^ (dg&7))<<3) + (j&7);
      u32x4 kx = *(const u32x4*)(kb + (size_t)(c*64+j)*1024 + dg*8);
      u32x4 vx = *(const u32x4*)(vb + (size_t)(c*64+j)*1024 + dg*8);
      #pragma unroll
      for (int t=0;t<4;t++){
        KTs[(dg*8+t*2  )*72 + col] = (u16)(kx[t]&0xffff);
        KTs[(dg*8+t*2+1)*72 + col] = (u16)(kx[t]>>16);
        VTs[(dg*8+t*2  )*72 + col] = (u16)(vx[t]&0xffff);
        VTs[(dg*8+t*2+1)*72 + col] = (u16)(vx[t]>>16);
      }
    }
    __syncthreads();
    bf16x8 qf[2][4];
    #pragma unroll
    for (int ti=0; ti<2; ++ti){
      #pragma unroll
      for (int ks=0; ks<4; ++ks)
        qf[ti][ks] = *(const bf16x8*)&Qs[(wr*32+ti*16+lc)*136 + ks*32 + lr*8];
    }
    f32x4 accO[2][4];
    #pragma unroll
    for (int i=0;i<2;i++){
      #pragma unroll
      for (int j=0;j<4;j++) accO[i][j]=Z4;
    }
    #pragma unroll
    for (int ks=0; ks<4; ++ks){
      bf16x8 bt[4];
      #pragma unroll
      for (int te=0; te<4; ++te)
        bt[te] = *(const bf16x8*)&Ts[tso + (wc*64+te*16+lc)*136 + ks*32 + lr*8];
      #pragma unroll
      for (int ti=0; ti<2; ++ti){
        #pragma unroll
        for (int te=0; te<4; ++te)
          accO[ti][te] = MFMA16(qf[ti][ks], bt[te], accO[ti][te]);
      }
    }
    f32x4 accP[2][2];
    #pragma unroll
    for (int i=0;i<2;i++){
      #pragma unroll
      for (int j=0;j<2;j++) accP[i][j]=Z4;
    }
    #pragma unroll
    for (int ks=0; ks<4; ++ks){
      bf16x8 bk[2];
      #pragma unroll
      for (int tj=0; tj<2; ++tj)
        bk[tj] = *(const bf16x8*)&Ks[(wc*32+tj*16+lc)*136 + ks*32 + lr*8];
      #pragma unroll
      for (int ti=0; ti<2; ++ti){
        #pragma unroll
        for (int tj=0; tj<2; ++tj)
          accP[ti][tj] = MFMA16(qf[ti][ks], bk[tj], accP[ti][tj]);
      }
    }
    #pragma unroll
    for (int ti=0; ti<2; ++ti){
      #pragma unroll
      for (int tj=0; tj<2; ++tj){
        #pragma unroll
        for (int r=0;r<4;r++){
          int i = wr*32+ti*16+lr*4+r;
          int j = wc*32+tj*16+lc;
          Ps[i*72 + j] = f2bf( (j<=i) ? accP[ti][tj][r] : 0.f );
        }
      }
    }
    __syncthreads();
    #pragma unroll
    for (int ks=0; ks<2; ++ks){
      bf16x8 ap[2], bv[4];
      #pragma unroll
      for (int ti=0; ti<2; ++ti)
        ap[ti] = *(const bf16x8*)&Ps[(wr*32+ti*16+lc)*72 + ks*32 + lr*8];
      #pragma unroll
      for (int te=0; te<4; ++te)
        bv[te] = *(const bf16x8*)&VTs[TSW(wc*64+te*16+lc, ks*4+lr)];
      #pragma unroll
      for (int ti=0; ti<2; ++ti){
        #pragma unroll
        for (int te=0; te<4; ++te)
          accO[ti][te] = MFMA16(ap[ti], bv[te], accO[ti][te]);
      }
    }
    #pragma unroll
    for (int ks=0; ks<2; ++ks){
      bf16x8 av[4], bk2[4];
      #pragma unroll
      for (int te=0; te<4; ++te)
        av[te] = *(const bf16x8*)&VTs[TSW(wr*64+te*16+lc, ks*4+lr)];
      #pragma unroll
      for (int td=0; td<4; ++td)
        bk2[td] = *(const bf16x8*)&KTs[TSW(wc*64+td*16+lc, ks*4+lr)];
      #pragma unroll
      for (int te=0; te<4; ++te){
        #pragma unroll
        for (int td=0; td<4; ++td)
          accT[te][td] = MFMA16(av[te], bk2[td], accT[te][td]);
      }
    }
    int tsn = tso ^ (128*136);
    #pragma unroll
    for (int te=0; te<4; ++te){
      #pragma unroll
      for (int td=0; td<4; ++td){
        int dk = wc*64+td*16+lc;
        #pragma unroll
        for (int r=0;r<4;r++){
          int erow = wr*64+te*16+lr*4+r;
          Ts[tsn + erow*136 + dk] = f2bf(accT[te][td][r]);
        }
      }
    }
    #pragma unroll
    for (int ti=0; ti<2; ++ti){
      #pragma unroll
      for (int te=0; te<4; ++te){
        int ecol = wc*64+te*16+lc;
        #pragma unroll
        for (int r=0;r<4;r++){
          int i = wr*32+ti*16+lr*4+r;
          ob[(size_t)(c*64+i)*1024 + ecol] = f2bf(accO[ti][te][r]);
        }
      }
    }
    __syncthreads();
    tso = tsn;
  }
}

// ---------- combine + per-head RMSNorm ----------
__global__ __launch_bounds__(256) void k_comb(const u16* __restrict__ o, const int* __restrict__ sel,
  const float* __restrict__ rw, const int* __restrict__ slot_of, const int* __restrict__ meta,
  const float* __restrict__ nw, u16* __restrict__ fin)
{
  int w=threadIdx.x>>6, lane=threadIdx.x&63;
  int tok = blockIdx.x*4 + w;
  int b = tok>>11;
  int sv = sel[tok];
  float acc[16];
  #pragma unroll
  for (int i=0;i<16;i++) acc[i]=0.f;
  #pragma unroll
  for (int kk=0; kk<2; ++kk){
    int e = kk ? ((sv>>8)&255) : (sv&255);
    int j = slot_of[tok*2 + kk];
    if (j < 0) continue;
    float wgt = rw[tok*2+kk];
    int row = meta[96 + b*8 + e] + j;
    const u16* orow = o + (size_t)row*1024 + lane*16;
    #pragma unroll
    for (int q=0;q<2;q++){
      u32x4 v = *(const u32x4*)(orow + q*8);
      #pragma unroll
      for (int t=0;t<4;t++){
        acc[q*8+t*2]   += wgt * bf2f((u16)(v[t]&0xffff));
        acc[q*8+t*2+1] += wgt * bf2f((u16)(v[t]>>16));
      }
    }
  }
  float ssq=0.f;
  #pragma unroll
  for (int i=0;i<16;i++) ssq += acc[i]*acc[i];
  ssq += __shfl_xor(ssq,1,64);
  ssq += __shfl_xor(ssq,2,64);
  ssq += __shfl_xor(ssq,4,64);
  float sc = rsqrtf(ssq*(1.f/128.f) + 1e-5f);
  int cbase = (lane&7)*16;
  u32x4 o0, o1;
  #pragma unroll
  for (int t=0;t<4;t++)
    o0[t] = pack2(acc[2*t]*sc*nw[cbase+2*t], acc[2*t+1]*sc*nw[cbase+2*t+1]);
  #pragma unroll
  for (int t=0;t<4;t++)
    o1[t] = pack2(acc[8+2*t]*sc*nw[cbase+8+2*t], acc[8+2*t+1]*sc*nw[cbase+8+2*t+1]);
  u16* fp = fin + (size_t)tok*1024 + lane*16;
  *(u32x4*)fp     = o0;
  *(u32x4*)(fp+8) = o1;
}

// ---------- host launcher ----------
extern "C" void kernel_launch(void* const* d_in, const int* in_sizes, int n_in,
                              void* d_out, int out_size, void* d_ws, size_t ws_size,
                              hipStream_t stream)
{
  (void)in_sizes; (void)n_in;
  const float* x     = (const float*)d_in[0];
  const float* gate  = (const float*)d_in[1];
  const float* q_w   = (const float*)d_in[2];
  const float* k_w   = (const float*)d_in[3];
  const float* v_w   = (const float*)d_in[4];
  const float* fmq1  = (const float*)d_in[5];
  const float* fmq2  = (const float*)d_in[6];
  const float* fmk1  = (const float*)d_in[7];
  const float* fmk2  = (const float*)d_in[8];
  const float* norm_w= (const float*)d_in[9];
  const float* o_w   = (const float*)d_in[10];
  float* out = (float*)d_out;

  uint8_t* ws = (uint8_t*)d_ws;
  size_t off = 0;
  auto alloc = [&](size_t bytes)->void*{ void* p = ws + off; off += (bytes + 255) & ~(size_t)255; return p; };
  int*   meta = (int*)alloc(4096);
  int*   sel  = (int*)alloc(8192*4);
  float* rwb  = (float*)alloc(8192*2*4);
  int*   slot = (int*)alloc(16384*4);
  int*   srcf = (int*)alloc((size_t)32*2048*4);
  int*   tokm = (int*)alloc((size_t)RMAX*4);
  int*   done = (int*)alloc(256);
  u16* wA  = (u16*)alloc((size_t)2097152*2);           // q cat weights (2048x1024)
  u16* wVb = (u16*)alloc((size_t)8388608*2);           // v weights bf16 per expert
  u16* wOb = (u16*)alloc((size_t)1048576*2);           // o_w bf16
  u16* xb  = (u16*)alloc((size_t)8192*1024*2);         // bf16(x), token space
  u16* xg  = (u16*)alloc((size_t)RMAX*1024*2);
  u16* qh  = (u16*)alloc((size_t)8192*1024*2);         // q-hat, token space
  u16* kh  = (u16*)alloc((size_t)RMAX*1024*2);
  u16* vv  = (u16*)alloc((size_t)RMAX*1024*2);
  if (off > ws_size){
    hipMemsetAsync(d_out, 0x7F, (size_t)out_size*4, stream);
    return;
  }
  u16* wB  = (u16*)d_out;   // 33.5 MB k cat weights in output buffer (dead before k_gemmO)
  u16* ob  = xg;            // reuse after GEMMs consumed xg
  u16* fin = qh;            // reuse after attn consumed qh

  k_pre<<<3488,256,0,stream>>>(x, gate, sel, rwb, q_w, k_w, fmq1, fmq2, fmk1, fmk2, wA, wB, xb, v_w, wVb, o_w, wOb, done);
  k_count<<<32,256,0,stream>>>(sel, slot, srcf, meta, done);
  k_gather<<<dim3(32,32),256,0,stream>>>(xb, srcf, meta, xg, tokm);
  k_gemmQKV<<<1408,512,0,stream>>>(xb, xg, wA, wB, wVb, qh, kh, vv, meta);
  k_attn<<<256,256,0,stream>>>(qh, kh, vv, ob, meta, tokm);
  k_comb<<<2048,256,0,stream>>>(ob, sel, rwb, slot, meta, norm_w, fin);
  k_gemmO<<<dim3(4,64),512,0,stream>>>(fin, wOb, out);
}

// Round 13
// 404.320 us; speedup vs baseline: 1.1364x; 1.0040x over previous
//
#include <hip/hip_runtime.h>
#include <stdint.h>

// ---------- types / helpers ----------
typedef unsigned short u16;
typedef unsigned int   u32;
typedef __attribute__((ext_vector_type(4))) float f32x4;
typedef __attribute__((ext_vector_type(4))) u32   u32x4;
typedef __attribute__((ext_vector_type(8))) __bf16 bf16x8;

#define MFMA16(a,b,c) __builtin_amdgcn_mfma_f32_16x16x32_bf16((a),(b),(c),0,0,0)

#define QSCALE 0.08838834764831845f   // 128^-0.5
#define RMAX   24576                  // sum roundup(min(n,2048),256) <= 16384+32*255

__device__ __forceinline__ float bf2f(u16 x){ u32 u=((u32)x)<<16; float f; __builtin_memcpy(&f,&u,4); return f; }
__device__ __forceinline__ u16 f2bf(float f){ u32 u; __builtin_memcpy(&u,&f,4); u = u + 0x7FFFu + ((u>>16)&1u); return (u16)(u>>16); }
__device__ __forceinline__ u32 pack2(float a, float b){ return (u32)f2bf(a) | ((u32)f2bf(b)<<16); }

// async global->LDS, 16B per lane
__device__ __forceinline__ void gl_lds(const u16* g, u16* l){
  __builtin_amdgcn_global_load_lds(
      (const __attribute__((address_space(1))) void*)g,
      (__attribute__((address_space(3))) void*)l, 16, 0, 0);
}

// transposed-tile addr with octet swizzle (attn): row stride 72 u16
#define TSW(row, oct) ((row)*72 + ((((oct) ^ (((row)>>3)&7)))<<3))

// meta layout (ints): [0,32) n  [32,64) nact  [64,96) npad  [96,129) base
// [129,161) nchunks  [161] R_total  [192,352) 256-tile -> group map

// ---------- device bodies for fused pre-pass ----------
__device__ __forceinline__ void cvt_body(const float* __restrict__ s, u16* __restrict__ d,
                                         long n8, int lb, int nb){
  long idx = (long)lb*256 + threadIdx.x;
  long stride = (long)nb*256;
  for (long i=idx; i<n8; i+=stride){
    const float* p = s + i*8;
    f32x4 a = *(const f32x4*)p;
    f32x4 b = *(const f32x4*)(p+4);
    u32x4 o;
    o[0]=pack2(a[0],a[1]); o[1]=pack2(a[2],a[3]); o[2]=pack2(b[0],b[1]); o[3]=pack2(b[2],b[3]);
    *(u32x4*)(d + i*8) = o;
  }
}

__device__ __forceinline__ void route_body(const float* __restrict__ x, const float* __restrict__ gw,
  int* __restrict__ sel, float* __restrict__ rw, u16* __restrict__ xb, int lb)
{
  int w = threadIdx.x>>6, lane = threadIdx.x&63;
  int tok = lb*4 + w;
  const float* xr = x + (size_t)tok*1024 + lane*16;
  f32x4 xv[4];
  #pragma unroll
  for (int q=0;q<4;q++) xv[q] = *(const f32x4*)(xr + q*4);
  {
    u16* xrow = xb + (size_t)tok*1024 + lane*16;
    u32x4 o0, o1;
    o0[0]=pack2(xv[0][0],xv[0][1]); o0[1]=pack2(xv[0][2],xv[0][3]);
    o0[2]=pack2(xv[1][0],xv[1][1]); o0[3]=pack2(xv[1][2],xv[1][3]);
    o1[0]=pack2(xv[2][0],xv[2][1]); o1[1]=pack2(xv[2][2],xv[2][3]);
    o1[2]=pack2(xv[3][0],xv[3][1]); o1[3]=pack2(xv[3][2],xv[3][3]);
    *(u32x4*)xrow     = o0;
    *(u32x4*)(xrow+8) = o1;
  }
  float part[8];
  #pragma unroll
  for (int e=0;e<8;e++){
    const float* g = gw + e*1024 + lane*16;
    float s = 0.f;
    #pragma unroll
    for (int q=0;q<4;q++){
      f32x4 gv = *(const f32x4*)(g + q*4);
      s += xv[q][0]*gv[0] + xv[q][1]*gv[1] + xv[q][2]*gv[2] + xv[q][3]*gv[3];
    }
    part[e]=s;
  }
  #pragma unroll
  for (int e=0;e<8;e++){
    float v = part[e];
    #pragma unroll
    for (int off=32; off>0; off>>=1) v += __shfl_xor(v, off, 64);
    part[e]=v;
  }
  if (lane==0){
    int i0=0; float m0=part[0];
    #pragma unroll
    for (int e=1;e<8;e++) if (part[e]>m0){ m0=part[e]; i0=e; }
    int i1=0; float m1=-3.4e38f;
    #pragma unroll
    for (int e=0;e<8;e++) if (e!=i0 && part[e]>m1){ m1=part[e]; i1=e; }
    sel[tok] = i0 | (i1<<8);
    float e1 = expf(m1-m0);
    float inv = 1.f/(1.f+e1);
    rw[tok*2+0] = inv;
    rw[tok*2+1] = e1*inv;
  }
}

__device__ __forceinline__ void prep_body(
  const float* __restrict__ q_w, const float* __restrict__ k_w,
  const float* __restrict__ fmq1, const float* __restrict__ fmq2,
  const float* __restrict__ fmk1, const float* __restrict__ fmk2,
  u16* __restrict__ wA, u16* __restrict__ wB, int l, u16* shmem)
{
  int gi = l>>3;
  int c0 = (l&7)*128;
  const float* fm; const float* ws; u16* wd;
  if (gi < 8)      { int h=gi;    fm=fmq1; ws=q_w + (size_t)h*131072; wd=wA + (size_t)h*262144; }
  else if (gi < 16){ int h=gi-8;  fm=fmq2; ws=q_w + (size_t)h*131072; wd=wA + (size_t)h*262144 + 131072; }
  else if (gi < 80){ int t=gi-16, e=t>>3, h=t&7; fm=fmk1; ws=k_w + (size_t)(e*8+h)*131072; wd=wB + (size_t)e*2097152 + (size_t)h*262144; }
  else             { int t=gi-80, e=t>>3, h=t&7; fm=fmk2; ws=k_w + (size_t)(e*8+h)*131072; wd=wB + (size_t)e*2097152 + (size_t)h*262144 + 131072; }
  u16* Af = shmem;
  u16* Bf = shmem + 128*136;
  int tid = threadIdx.x;
  for (int i=tid; i<4096; i+=256){
    int row = i>>5, col = (i&31)*4;
    f32x4 v = *(const f32x4*)&fm[row*128 + col];
    u16* dp = &Af[row*136 + col];
    *(u32*)dp     = pack2(v[0],v[1]);
    *(u32*)(dp+2) = pack2(v[2],v[3]);
  }
  for (int i=tid; i<4096; i+=256){
    int dd = i>>5, cq = (i&31)*4;
    f32x4 v = *(const f32x4*)&ws[(size_t)dd*1024 + c0 + cq];
    #pragma unroll
    for (int j=0;j<4;j++){
      int c = cq+j;
      Bf[c*136 + (dd ^ (((c>>2)&3)<<3))] = f2bf(v[j]);
    }
  }
  __syncthreads();
  int lane=tid&63, w=tid>>6, wr=w>>1, wc=w&1, lc=lane&15, lr=lane>>4;
  const f32x4 Z4 = {0.f,0.f,0.f,0.f};
  f32x4 acc[4][4];
  #pragma unroll
  for (int i=0;i<4;i++){
    #pragma unroll
    for (int j=0;j<4;j++) acc[i][j]=Z4;
  }
  #pragma unroll
  for (int kk=0; kk<4; ++kk){
    bf16x8 a[4], b[4];
    #pragma unroll
    for (int mi=0;mi<4;mi++)
      a[mi] = *(const bf16x8*)&Af[(wr*64+mi*16+lc)*136 + kk*32 + lr*8];
    #pragma unroll
    for (int ni=0;ni<4;ni++){
      int c = wc*64+ni*16+lc;
      b[ni] = *(const bf16x8*)&Bf[c*136 + ((kk*32 + lr*8) ^ (((c>>2)&3)<<3))];
    }
    #pragma unroll
    for (int mi=0;mi<4;mi++){
      #pragma unroll
      for (int ni=0;ni<4;ni++)
        acc[mi][ni] = MFMA16(a[mi], b[ni], acc[mi][ni]);
    }
  }
  int r0=lr*4;
  #pragma unroll
  for (int mi=0;mi<4;mi++){
    #pragma unroll
    for (int ni=0;ni<4;ni++){
      int col = c0 + wc*64 + ni*16 + lc;
      #pragma unroll
      for (int r=0;r<4;r++){
        int row = wr*64 + mi*16 + r0 + r;
        wd[(size_t)row*1024 + col] = f2bf(acc[mi][ni][r]);
      }
    }
  }
}

// ---------- fused pre-pass ----------
__global__ __launch_bounds__(256) void k_pre(
  const float* __restrict__ x, const float* __restrict__ gw,
  int* __restrict__ sel, float* __restrict__ rw,
  const float* __restrict__ q_w, const float* __restrict__ k_w,
  const float* __restrict__ fmq1, const float* __restrict__ fmq2,
  const float* __restrict__ fmk1, const float* __restrict__ fmk2,
  u16* __restrict__ wA, u16* __restrict__ wB, u16* __restrict__ xb,
  const float* __restrict__ v_w, u16* __restrict__ wVb,
  const float* __restrict__ o_w, u16* __restrict__ wOb, int* __restrict__ done)
{
  __shared__ __align__(16) u16 shmem[2*128*136];
  int bid = blockIdx.x;
  if (bid==0 && threadIdx.x==0) *done = 0;
  if (bid < 2048)      route_body(x, gw, sel, rw, xb, bid);
  else if (bid < 3200) prep_body(q_w, k_w, fmq1, fmq2, fmk1, fmk2, wA, wB, bid-2048, shmem);
  else if (bid < 3456) cvt_body(v_w, wVb, 1048576L, bid-3200, 256);
  else                 cvt_body(o_w, wOb, 131072L, bid-3456, 32);
}

// ---------- per-(b,e) counting sort + fused bases (256-pad, last block) ----------
__global__ __launch_bounds__(256) void k_count(const int* __restrict__ sel,
  int* __restrict__ slot_of, int* __restrict__ src_of, int* __restrict__ meta,
  int* __restrict__ done)
{
  int g = blockIdx.x, b = g>>3, e = g&7;
  int tid = threadIdx.x;
  __shared__ int cn[256];
  unsigned char ex[16];
  int cnt=0;
  #pragma unroll
  for (int i=0;i<16;i++){
    int t = tid*16+i;
    int sv = sel[b*2048 + (t>>1)];
    int ee = (t&1) ? ((sv>>8)&255) : (sv&255);
    ex[i]=(unsigned char)ee;
    cnt += (ee==e);
  }
  cn[tid]=cnt;
  __syncthreads();
  for (int off=1; off<256; off<<=1){
    int v = (tid>=off) ? cn[tid-off] : 0;
    __syncthreads();
    cn[tid] += v;
    __syncthreads();
  }
  int total = cn[255];
  int run = cn[tid]-cnt;
  int shift = total>2048 ? total-2048 : 0;
  #pragma unroll
  for (int i=0;i<16;i++){
    int t = tid*16+i;
    if (ex[i]==e){
      int j = run - shift;
      run++;
      slot_of[b*4096 + t] = (j>=0)? j : -1;
      if (j>=0) src_of[g*2048 + j] = t;
    }
  }
  if (tid==0){
    meta[g]=total;
    __threadfence();
    if (atomicAdd(done,1)==31){
      int basev=0, t=0;
      meta[96]=0;
      for (int gg=0; gg<32; ++gg){
        int n = atomicAdd(&meta[gg],0);
        int nact = n<2048 ? n : 2048;
        int npad = (nact+255)&~255;
        meta[32+gg]=nact;
        meta[64+gg]=npad;
        meta[129+gg]=(nact+63)>>6;
        for (int i=0;i<(npad>>8);++i) meta[192+t++]=gg;
        basev += npad;
        meta[97+gg]=basev;
      }
      meta[161]=basev;
    }
  }
}

// ---------- gather bf16 rows -> compact + row->token map ----------
__global__ __launch_bounds__(256) void k_gather(const u16* __restrict__ xb,
  const int* __restrict__ src_of, const int* __restrict__ meta, u16* __restrict__ xg,
  int* __restrict__ tokmap)
{
  int g = blockIdx.y, jb = blockIdx.x;
  int npad = meta[64+g];
  if (jb*64 >= npad) return;
  int nact = meta[32+g], base = meta[96+g];
  int tid = threadIdx.x;
  int j = jb*64 + (tid>>2);
  int quart = tid&3;
  int src = (j<nact) ? src_of[g*2048+j] : -1;
  int token = (src>=0) ? ((g>>3)*2048 + (src>>1)) : 0;
  if (quart==0) tokmap[base+j] = token;
  u16* orow = xg + ((size_t)(base+j))*1024 + quart*256;
  if (src>=0){
    const u16* xr = xb + (size_t)token*1024 + quart*256;
    #pragma unroll
    for (int i=0;i<256;i+=8) *(u32x4*)(orow+i) = *(const u32x4*)(xr+i);
  } else {
    u32x4 z = {0,0,0,0};
    #pragma unroll
    for (int i=0;i<256;i+=8) *(u32x4*)(orow+i)=z;
  }
}

// ======== fused q+k+v 256x256 8-wave GEMM, BK=64, 4-phase/K-tile, counted vmcnt(4) ========
// Phase-ahead A-frag ds_read prefetch: phase j reads phase j+1's frags before its MFMA.
__global__ __launch_bounds__(512,2) void k_gemmQKV(const u16* __restrict__ xb, const u16* __restrict__ xg,
  const u16* __restrict__ wA, const u16* __restrict__ wB, const u16* __restrict__ wVb,
  u16* __restrict__ qh, u16* __restrict__ kh, u16* __restrict__ vv, const int* __restrict__ meta)
{
  int bid = blockIdx.x;
  int role, tm, tn;
  const u16 *A, *Wp; u16* outB;
  if (bid < 256){
    role=0; int l=bid, xcd=l&7, jj=l>>3, jd=jj>>3;
    tm=xcd*4+jd; tn=jj&7;
    A=xb; Wp=wA + (size_t)tn*262144; outB=qh;
  } else if (bid < 1024){
    role=1; int l=bid-256, xcd=l&7, jj=l>>3, jd=jj>>3;
    tm=xcd*12+jd; tn=jj&7;
    if (tm*256 >= meta[161]) return;
    A=xg; Wp=wB + (size_t)(meta[192+tm]&7)*2097152 + (size_t)tn*262144; outB=kh;
  } else {
    role=2; int l=bid-1024, xcd=l&7, jj=l>>3, jd=jj>>2;
    tm=xcd*12+jd; tn=jj&3;
    if (tm*256 >= meta[161]) return;
    A=xg; Wp=wVb + (size_t)(meta[192+tm]&7)*1048576 + (size_t)tn*262144; outB=vv;
  }

  __shared__ __align__(16) u16 smem[65536];   // 128 KB

  int tid=threadIdx.x, lane=tid&63;
  int w=tid>>6, wr=w>>2, wc=w&3, lc=lane&15, lr=lane>>4;
  int swz = lc&7;
  int ck0 = ((lr)^swz)<<3;
  int ck1 = ((4+lr)^swz)<<3;
  int arow = (wr*128 + lc)*64;
  int brow = 16384 + (wc*64 + lc)*64;
  const f32x4 Z4 = {0.f,0.f,0.f,0.f};
  f32x4 acc[8][4];
  #pragma unroll
  for(int i=0;i<8;i++){
    #pragma unroll
    for(int j2=0;j2<4;j2++) acc[i][j2]=Z4;
  }
  int rowlane = tid>>3;
  int gch = ((tid&7)^(rowlane&7))*8;
  const u16* Asrc = A  + (size_t)tm*262144 + (size_t)rowlane*1024 + gch;
  const u16* Bsrc = Wp + (size_t)rowlane*1024 + gch;

  #define STG2(dst, src) { \
    gl_lds((src),         &smem[(dst) + tid*8]); \
    gl_lds((src) + 65536, &smem[(dst) + 4096 + tid*8]); }

  // read 4 A-frags of phase jrow from buffer d
  #define RDA(dst, jrow) { \
    dst[0] = *(const bf16x8*)&smem[d + arow + (2*(jrow)  )*1024 + ck0]; \
    dst[1] = *(const bf16x8*)&smem[d + arow + (2*(jrow)+1)*1024 + ck0]; \
    dst[2] = *(const bf16x8*)&smem[d + arow + (2*(jrow)  )*1024 + ck1]; \
    dst[3] = *(const bf16x8*)&smem[d + arow + (2*(jrow)+1)*1024 + ck1]; }

  // 16 MFMA of phase jrow using frags in src (same accumulation order as before)
  #define DOMFMA(src, jrow) { \
    __builtin_amdgcn_s_setprio(1); \
    _Pragma("unroll") \
    for (int ni=0;ni<4;ni++){ \
      acc[2*(jrow)  ][ni] = MFMA16(src[0], b0[ni], acc[2*(jrow)  ][ni]); \
      acc[2*(jrow)+1][ni] = MFMA16(src[1], b0[ni], acc[2*(jrow)+1][ni]); } \
    _Pragma("unroll") \
    for (int ni=0;ni<4;ni++){ \
      acc[2*(jrow)  ][ni] = MFMA16(src[2], b1[ni], acc[2*(jrow)  ][ni]); \
      acc[2*(jrow)+1][ni] = MFMA16(src[3], b1[ni], acc[2*(jrow)+1][ni]); } \
    __builtin_amdgcn_s_setprio(0); }

  // prologue: B0, A0, B1  (order makes vmcnt(4) uniform)
  STG2(16384, Bsrc);
  STG2(24576, Bsrc + 131072);
  STG2(0,     Asrc);
  STG2(8192,  Asrc + 131072);
  STG2(49152, Bsrc + 64);
  STG2(57344, Bsrc + 131072 + 64);

  for (int t=0; t<16; ++t){
    int d = (t&1)<<15;
    bf16x8 b0[4], b1[4], aE[4], aO[4];
    // ---- phase 0 ----
    if (t<15) asm volatile("s_waitcnt vmcnt(4)" ::: "memory");
    else      asm volatile("s_waitcnt vmcnt(0)" ::: "memory");
    __builtin_amdgcn_s_barrier();
    #pragma unroll
    for (int ni=0;ni<4;ni++){
      b0[ni] = *(const bf16x8*)&smem[d + brow + ni*1024 + ck0];
      b1[ni] = *(const bf16x8*)&smem[d + brow + ni*1024 + ck1];
    }
    RDA(aE, 0);
    if (t<15) STG2(((t+1)&1)<<15, Asrc + (size_t)(t+1)*64);
    RDA(aO, 1);                    // prefetch phase 1
    DOMFMA(aE, 0);
    // ---- phase 1 ----
    __builtin_amdgcn_s_barrier();
    if (t<15) STG2((((t+1)&1)<<15) + 8192, Asrc + 131072 + (size_t)(t+1)*64);
    RDA(aE, 2);                    // prefetch phase 2
    DOMFMA(aO, 1);
    // ---- phase 2 ----
    __builtin_amdgcn_s_barrier();
    if (t<14) STG2(d + 16384, Bsrc + (size_t)(t+2)*64);
    RDA(aO, 3);                    // prefetch phase 3
    DOMFMA(aE, 2);
    // ---- phase 3 ----
    __builtin_amdgcn_s_barrier();
    if (t<14) STG2(d + 24576, Bsrc + 131072 + (size_t)(t+2)*64);
    DOMFMA(aO, 3);
  }
  #undef STG2
  #undef RDA
  #undef DOMFMA

  __syncthreads();
  if (role < 2){
    if (wc >= 2){
      #pragma unroll
      for (int mi=0;mi<8;mi++){
        #pragma unroll
        for (int ni=0;ni<4;ni++){
          int col = (wc-2)*64 + ni*16 + lc;
          #pragma unroll
          for (int r=0;r<4;r++)
            ((float*)smem)[(wr*128+mi*16+lr*4+r)*128 + col] = acc[mi][ni][r];
        }
      }
    }
    __syncthreads();
    if (wc < 2){
      float scl = (role==0) ? QSCALE : 1.0f;
      #pragma unroll
      for (int mi=0;mi<8;mi++){
        #pragma unroll
        for (int ni=0;ni<4;ni++){
          int col = wc*64 + ni*16 + lc;
          #pragma unroll
          for (int r=0;r<4;r++){
            int row = wr*128+mi*16+lr*4+r;
            float v = acc[mi][ni][r] * ((float*)smem)[row*128 + col] * scl;
            outB[(size_t)(tm*256+row)*1024 + tn*128 + col] = f2bf(v);
          }
        }
      }
    }
  } else {
    #pragma unroll
    for (int mi=0;mi<8;mi++){
      #pragma unroll
      for (int ni=0;ni<4;ni++){
        int col = tn*256 + wc*64 + ni*16 + lc;
        #pragma unroll
        for (int r=0;r<4;r++){
          int row = tm*256 + wr*128 + mi*16 + lr*4 + r;
          outB[(size_t)row*1024 + col] = f2bf(acc[mi][ni][r]);
        }
      }
    }
  }
}

// ======== 128x256 8-wave single GEMM, T4+T2 pipeline — final out proj ========
__global__ __launch_bounds__(512) void k_gemmO(const u16* __restrict__ A, const u16* __restrict__ W,
  float* __restrict__ outF)
{
  int tnN = gridDim.x;
  int bid = blockIdx.y*tnN + blockIdx.x;
  int chunk = gridDim.y >> 3;
  int xcd = bid & 7, j = bid >> 3;
  int jd = j / tnN;
  int tm = xcd*chunk + jd;
  int tn = j - jd*tnN;

  __shared__ __align__(16) u16 smem[73728];

  int tid=threadIdx.x, lane=tid&63;
  int w=tid>>6, wr=w>>2, wc=w&3, lc=lane&15, lr=lane>>4;
  int swz = lc&7;
  const f32x4 Z4 = {0.f,0.f,0.f,0.f};
  f32x4 acc[4][4];
  #pragma unroll
  for(int i=0;i<4;i++){
    #pragma unroll
    for(int j2=0;j2<4;j2++) acc[i][j2]=Z4;
  }
  size_t lanoff = (size_t)(tid>>3)*1024 + (size_t)(((tid&7)^((tid>>3)&7))*8);
  const u16* Ag = A + (size_t)tm*131072 + lanoff;
  const u16* Bg = W + (size_t)tn*262144 + lanoff;
  int lo = tid*8;

  #define STAGEO(ao, bo, kt) { \
    const u16* ga = Ag + (kt)*64; const u16* gb = Bg + (kt)*64; \
    gl_lds(ga,                 &smem[(ao) + lo]); \
    gl_lds(ga + (size_t)65536, &smem[(ao) + 4096 + lo]); \
    gl_lds(gb,                  &smem[(bo) + lo]); \
    gl_lds(gb + (size_t)65536,  &smem[(bo) + 4096 + lo]); \
    gl_lds(gb + (size_t)131072, &smem[(bo) + 8192 + lo]); \
    gl_lds(gb + (size_t)196608, &smem[(bo) + 12288 + lo]); }

  STAGEO(0, 24576, 0);
  STAGEO(8192, 40960, 1);
  int cur = 0;
  for (int kt=0; kt<16; ++kt){
    if (kt<15) asm volatile("s_waitcnt vmcnt(6)" ::: "memory");
    else       asm volatile("s_waitcnt vmcnt(0)" ::: "memory");
    __builtin_amdgcn_s_barrier();
    if (kt<14){
      int nid = kt+2; nid -= (nid/3)*3;
      STAGEO(nid*8192, 24576+nid*16384, kt+2);
    }
    int ao = cur*8192, bo = 24576 + cur*16384;
    __builtin_amdgcn_s_setprio(1);
    #pragma unroll
    for (int kk=0; kk<2; ++kk){
      bf16x8 a[4], b[4];
      #pragma unroll
      for (int mi=0;mi<4;mi++){
        int row = wr*64+mi*16+lc;
        a[mi] = *(const bf16x8*)&smem[ao + row*64 + (((kk*4+lr)^swz)<<3)];
      }
      #pragma unroll
      for (int ni=0;ni<4;ni++){
        int row = wc*64+ni*16+lc;
        b[ni] = *(const bf16x8*)&smem[bo + row*64 + (((kk*4+lr)^swz)<<3)];
      }
      #pragma unroll
      for (int mi=0;mi<4;mi++){
        #pragma unroll
        for (int ni=0;ni<4;ni++)
          acc[mi][ni] = MFMA16(a[mi], b[ni], acc[mi][ni]);
      }
    }
    __builtin_amdgcn_s_setprio(0);
    cur = (cur==2)?0:cur+1;
  }
  #pragma unroll
  for (int mi=0;mi<4;mi++){
    #pragma unroll
    for (int ni=0;ni<4;ni++){
      int col = tn*256 + wc*64 + ni*16 + lc;
      #pragma unroll
      for (int r=0;r<4;r++){
        int row = tm*128 + wr*64 + mi*16 + lr*4 + r;
        outF[(size_t)row*1024 + col] = acc[mi][ni][r];
      }
    }
  }
  #undef STAGEO
}

// ---------- chunked causal linear attention, one block per (group, head) ----------
__global__ __launch_bounds__(256,1) void k_attn(const u16* __restrict__ qv, const u16* __restrict__ kv,
  const u16* __restrict__ vv, u16* __restrict__ o, const int* __restrict__ meta,
  const int* __restrict__ tokmap)
{
  int g = blockIdx.x>>3, h = blockIdx.x&7;
  int nch = meta[129+g];
  if (nch==0) return;
  int base = meta[96+g];
  __shared__ __align__(16) u16 Qs[64*136];
  __shared__ __align__(16) u16 Ks[64*136];
  __shared__ __align__(16) u16 KTs[128*72];
  __shared__ __align__(16) u16 VTs[128*72];
  __shared__ __align__(16) u16 Ts[2*128*136];
  __shared__ __align__(16) u16 Ps[64*72];
  int tid=threadIdx.x, w=tid>>6, lane=tid&63;
  int wr=w>>1, wc=w&1;
  int lr=lane>>4, lc=lane&15;
  {
    u32x4 z={0,0,0,0};
    for (int i=tid; i<128*136/8; i+=256) *(u32x4*)&Ts[i*8]=z;
  }
  const f32x4 Z4 = {0.f,0.f,0.f,0.f};
  f32x4 accT[4][4];
  #pragma unroll
  for (int i=0;i<4;i++){
    #pragma unroll
    for (int j=0;j<4;j++) accT[i][j]=Z4;
  }
  __syncthreads();
  const u16* kb = kv + (size_t)base*1024 + h*128;
  const u16* vb = vv + (size_t)base*1024 + h*128;
  u16* ob = o + (size_t)base*1024 + h*128;
  int tso = 0;

  for (int c=0; c<nch; ++c){
    #pragma unroll
    for (int it=0; it<4; ++it){
      int id = tid + it*256;
      int row = id>>4, kc = id&15;
      int tok = tokmap[base + c*64 + row];
      *(u32x4*)&Qs[row*136 + kc*8] = *(const u32x4*)(qv + (size_t)tok*1024 + h*128 + kc*8);
      *(u32x4*)&Ks[row*136 + kc*8] = *(const u32x4*)(kb + (size_t)(c*64+row)*1024 + kc*8);
    }
    #pragma unroll
    for (int it=0; it<4; ++it){
      int id = tid + it*256;
      int j = id>>4, dg = id&15;
      int col = (((j>>3) ^ (dg&7))<<3) + (j&7);
      u32x4 kx = *(const u32x4*)(kb + (size_t)(c*64+j)*1024 + dg*8);
      u32x4 vx = *(const u32x4*)(vb + (size_t)(c*64+j)*1024 + dg*8);
      #pragma unroll
      for (int t=0;t<4;t++){
        KTs[(dg*8+t*2  )*72 + col] = (u16)(kx[t]&0xffff);
        KTs[(dg*8+t*2+1)*72 + col] = (u16)(kx[t]>>16);
        VTs[(dg*8+t*2  )*72 + col] = (u16)(vx[t]&0xffff);
        VTs[(dg*8+t*2+1)*72 + col] = (u16)(vx[t]>>16);
      }
    }
    __syncthreads();
    bf16x8 qf[2][4];
    #pragma unroll
    for (int ti=0; ti<2; ++ti){
      #pragma unroll
      for (int ks=0; ks<4; ++ks)
        qf[ti][ks] = *(const bf16x8*)&Qs[(wr*32+ti*16+lc)*136 + ks*32 + lr*8];
    }
    f32x4 accO[2][4];
    #pragma unroll
    for (int i=0;i<2;i++){
      #pragma unroll
      for (int j=0;j<4;j++) accO[i][j]=Z4;
    }
    #pragma unroll
    for (int ks=0; ks<4; ++ks){
      bf16x8 bt[4];
      #pragma unroll
      for (int te=0; te<4; ++te)
        bt[te] = *(const bf16x8*)&Ts[tso + (wc*64+te*16+lc)*136 + ks*32 + lr*8];
      #pragma unroll
      for (int ti=0; ti<2; ++ti){
        #pragma unroll
        for (int te=0; te<4; ++te)
          accO[ti][te] = MFMA16(qf[ti][ks], bt[te], accO[ti][te]);
      }
    }
    f32x4 accP[2][2];
    #pragma unroll
    for (int i=0;i<2;i++){
      #pragma unroll
      for (int j=0;j<2;j++) accP[i][j]=Z4;
    }
    #pragma unroll
    for (int ks=0; ks<4; ++ks){
      bf16x8 bk[2];
      #pragma unroll
      for (int tj=0; tj<2; ++tj)
        bk[tj] = *(const bf16x8*)&Ks[(wc*32+tj*16+lc)*136 + ks*32 + lr*8];
      #pragma unroll
      for (int ti=0; ti<2; ++ti){
        #pragma unroll
        for (int tj=0; tj<2; ++tj)
          accP[ti][tj] = MFMA16(qf[ti][ks], bk[tj], accP[ti][tj]);
      }
    }
    #pragma unroll
    for (int ti=0; ti<2; ++ti){
      #pragma unroll
      for (int tj=0; tj<2; ++tj){
        #pragma unroll
        for (int r=0;r<4;r++){
          int i = wr*32+ti*16+lr*4+r;
          int j = wc*32+tj*16+lc;
          Ps[i*72 + j] = f2bf( (j<=i) ? accP[ti][tj][r] : 0.f );
        }
      }
    }
    __syncthreads();
    #pragma unroll
    for (int ks=0; ks<2; ++ks){
      bf16x8 ap[2], bv[4];
      #pragma unroll
      for (int ti=0; ti<2; ++ti)
        ap[ti] = *(const bf16x8*)&Ps[(wr*32+ti*16+lc)*72 + ks*32 + lr*8];
      #pragma unroll
      for (int te=0; te<4; ++te)
        bv[te] = *(const bf16x8*)&VTs[TSW(wc*64+te*16+lc, ks*4+lr)];
      #pragma unroll
      for (int ti=0; ti<2; ++ti){
        #pragma unroll
        for (int te=0; te<4; ++te)
          accO[ti][te] = MFMA16(ap[ti], bv[te], accO[ti][te]);
      }
    }
    #pragma unroll
    for (int ks=0; ks<2; ++ks){
      bf16x8 av[4], bk2[4];
      #pragma unroll
      for (int te=0; te<4; ++te)
        av[te] = *(const bf16x8*)&VTs[TSW(wr*64+te*16+lc, ks*4+lr)];
      #pragma unroll
      for (int td=0; td<4; ++td)
        bk2[td] = *(const bf16x8*)&KTs[TSW(wc*64+td*16+lc, ks*4+lr)];
      #pragma unroll
      for (int te=0; te<4; ++te){
        #pragma unroll
        for (int td=0; td<4; ++td)
          accT[te][td] = MFMA16(av[te], bk2[td], accT[te][td]);
      }
    }
    int tsn = tso ^ (128*136);
    #pragma unroll
    for (int te=0; te<4; ++te){
      #pragma unroll
      for (int td=0; td<4; ++td){
        int dk = wc*64+td*16+lc;
        #pragma unroll
        for (int r=0;r<4;r++){
          int erow = wr*64+te*16+lr*4+r;
          Ts[tsn + erow*136 + dk] = f2bf(accT[te][td][r]);
        }
      }
    }
    #pragma unroll
    for (int ti=0; ti<2; ++ti){
      #pragma unroll
      for (int te=0; te<4; ++te){
        int ecol = wc*64+te*16+lc;
        #pragma unroll
        for (int r=0;r<4;r++){
          int i = wr*32+ti*16+lr*4+r;
          ob[(size_t)(c*64+i)*1024 + ecol] = f2bf(accO[ti][te][r]);
        }
      }
    }
    __syncthreads();
    tso = tsn;
  }
}

// ---------- combine + per-head RMSNorm ----------
__global__ __launch_bounds__(256) void k_comb(const u16* __restrict__ o, const int* __restrict__ sel,
  const float* __restrict__ rw, const int* __restrict__ slot_of, const int* __restrict__ meta,
  const float* __restrict__ nw, u16* __restrict__ fin)
{
  int w=threadIdx.x>>6, lane=threadIdx.x&63;
  int tok = blockIdx.x*4 + w;
  int b = tok>>11;
  int sv = sel[tok];
  float acc[16];
  #pragma unroll
  for (int i=0;i<16;i++) acc[i]=0.f;
  #pragma unroll
  for (int kk=0; kk<2; ++kk){
    int e = kk ? ((sv>>8)&255) : (sv&255);
    int j = slot_of[tok*2 + kk];
    if (j < 0) continue;
    float wgt = rw[tok*2+kk];
    int row = meta[96 + b*8 + e] + j;
    const u16* orow = o + (size_t)row*1024 + lane*16;
    #pragma unroll
    for (int q=0;q<2;q++){
      u32x4 v = *(const u32x4*)(orow + q*8);
      #pragma unroll
      for (int t=0;t<4;t++){
        acc[q*8+t*2]   += wgt * bf2f((u16)(v[t]&0xffff));
        acc[q*8+t*2+1] += wgt * bf2f((u16)(v[t]>>16));
      }
    }
  }
  float ssq=0.f;
  #pragma unroll
  for (int i=0;i<16;i++) ssq += acc[i]*acc[i];
  ssq += __shfl_xor(ssq,1,64);
  ssq += __shfl_xor(ssq,2,64);
  ssq += __shfl_xor(ssq,4,64);
  float sc = rsqrtf(ssq*(1.f/128.f) + 1e-5f);
  int cbase = (lane&7)*16;
  u32x4 o0, o1;
  #pragma unroll
  for (int t=0;t<4;t++)
    o0[t] = pack2(acc[2*t]*sc*nw[cbase+2*t], acc[2*t+1]*sc*nw[cbase+2*t+1]);
  #pragma unroll
  for (int t=0;t<4;t++)
    o1[t] = pack2(acc[8+2*t]*sc*nw[cbase+8+2*t], acc[8+2*t+1]*sc*nw[cbase+8+2*t+1]);
  u16* fp = fin + (size_t)tok*1024 + lane*16;
  *(u32x4*)fp     = o0;
  *(u32x4*)(fp+8) = o1;
}

// ---------- host launcher ----------
extern "C" void kernel_launch(void* const* d_in, const int* in_sizes, int n_in,
                              void* d_out, int out_size, void* d_ws, size_t ws_size,
                              hipStream_t stream)
{
  (void)in_sizes; (void)n_in;
  const float* x     = (const float*)d_in[0];
  const float* gate  = (const float*)d_in[1];
  const float* q_w   = (const float*)d_in[2];
  const float* k_w   = (const float*)d_in[3];
  const float* v_w   = (const float*)d_in[4];
  const float* fmq1  = (const float*)d_in[5];
  const float* fmq2  = (const float*)d_in[6];
  const float* fmk1  = (const float*)d_in[7];
  const float* fmk2  = (const float*)d_in[8];
  const float* norm_w= (const float*)d_in[9];
  const float* o_w   = (const float*)d_in[10];
  float* out = (float*)d_out;

  uint8_t* ws = (uint8_t*)d_ws;
  size_t off = 0;
  auto alloc = [&](size_t bytes)->void*{ void* p = ws + off; off += (bytes + 255) & ~(size_t)255; return p; };
  int*   meta = (int*)alloc(4096);
  int*   sel  = (int*)alloc(8192*4);
  float* rwb  = (float*)alloc(8192*2*4);
  int*   slot = (int*)alloc(16384*4);
  int*   srcf = (int*)alloc((size_t)32*2048*4);
  int*   tokm = (int*)alloc((size_t)RMAX*4);
  int*   done = (int*)alloc(256);
  u16* wA  = (u16*)alloc((size_t)2097152*2);           // q cat weights (2048x1024)
  u16* wVb = (u16*)alloc((size_t)8388608*2);           // v weights bf16 per expert
  u16* wOb = (u16*)alloc((size_t)1048576*2);           // o_w bf16
  u16* xb  = (u16*)alloc((size_t)8192*1024*2);         // bf16(x), token space
  u16* xg  = (u16*)alloc((size_t)RMAX*1024*2);
  u16* qh  = (u16*)alloc((size_t)8192*1024*2);         // q-hat, token space
  u16* kh  = (u16*)alloc((size_t)RMAX*1024*2);
  u16* vv  = (u16*)alloc((size_t)RMAX*1024*2);
  if (off > ws_size){
    hipMemsetAsync(d_out, 0x7F, (size_t)out_size*4, stream);
    return;
  }
  u16* wB  = (u16*)d_out;   // 33.5 MB k cat weights in output buffer (dead before k_gemmO)
  u16* ob  = xg;            // reuse after GEMMs consumed xg
  u16* fin = qh;            // reuse after attn consumed qh

  k_pre<<<3488,256,0,stream>>>(x, gate, sel, rwb, q_w, k_w, fmq1, fmq2, fmk1, fmk2, wA, wB, xb, v_w, wVb, o_w, wOb, done);
  k_count<<<32,256,0,stream>>>(sel, slot, srcf, meta, done);
  k_gather<<<dim3(32,32),256,0,stream>>>(xb, srcf, meta, xg, tokm);
  k_gemmQKV<<<1408,512,0,stream>>>(xb, xg, wA, wB, wVb, qh, kh, vv, meta);
  k_attn<<<256,256,0,stream>>>(qh, kh, vv, ob, meta, tokm);
  k_comb<<<2048,256,0,stream>>>(ob, sel, rwb, slot, meta, norm_w, fin);
  k_gemmO<<<dim3(4,64),512,0,stream>>>(fin, wOb, out);
}

// Round 14
// 345.922 us; speedup vs baseline: 1.3283x; 1.1688x over previous
//
#include <hip/hip_runtime.h>
#include <stdint.h>

// ---------- types / helpers ----------
typedef unsigned short u16;
typedef unsigned int   u32;
typedef __attribute__((ext_vector_type(4))) float f32x4;
typedef __attribute__((ext_vector_type(4))) u32   u32x4;
typedef __attribute__((ext_vector_type(8))) __bf16 bf16x8;

#define MFMA16(a,b,c) __builtin_amdgcn_mfma_f32_16x16x32_bf16((a),(b),(c),0,0,0)

#define QSCALE 0.08838834764831845f   // 128^-0.5
#define RMAX   24576                  // sum roundup(min(n,2048),256) <= 16384+32*255

__device__ __forceinline__ float bf2f(u16 x){ u32 u=((u32)x)<<16; float f; __builtin_memcpy(&f,&u,4); return f; }
__device__ __forceinline__ u16 f2bf(float f){ u32 u; __builtin_memcpy(&u,&f,4); u = u + 0x7FFFu + ((u>>16)&1u); return (u16)(u>>16); }
__device__ __forceinline__ u32 pack2(float a, float b){ return (u32)f2bf(a) | ((u32)f2bf(b)<<16); }

// async global->LDS, 16B per lane
__device__ __forceinline__ void gl_lds(const u16* g, u16* l){
  __builtin_amdgcn_global_load_lds(
      (const __attribute__((address_space(1))) void*)g,
      (__attribute__((address_space(3))) void*)l, 16, 0, 0);
}

// transposed-tile addr with octet swizzle (attn): row stride 72 u16
#define TSW(row, oct) ((row)*72 + ((((oct) ^ (((row)>>3)&7)))<<3))

// meta layout (ints): [0,32) n  [32,64) nact  [64,96) npad  [96,129) base
// [129,161) nchunks  [161] R_total  [192,352) 256-tile -> group map

// ---------- device bodies for fused pre-pass ----------
__device__ __forceinline__ void cvt_body(const float* __restrict__ s, u16* __restrict__ d,
                                         long n8, int lb, int nb){
  long idx = (long)lb*256 + threadIdx.x;
  long stride = (long)nb*256;
  for (long i=idx; i<n8; i+=stride){
    const float* p = s + i*8;
    f32x4 a = *(const f32x4*)p;
    f32x4 b = *(const f32x4*)(p+4);
    u32x4 o;
    o[0]=pack2(a[0],a[1]); o[1]=pack2(a[2],a[3]); o[2]=pack2(b[0],b[1]); o[3]=pack2(b[2],b[3]);
    *(u32x4*)(d + i*8) = o;
  }
}

__device__ __forceinline__ void route_body(const float* __restrict__ x, const float* __restrict__ gw,
  int* __restrict__ sel, float* __restrict__ rw, u16* __restrict__ xb, int lb)
{
  int w = threadIdx.x>>6, lane = threadIdx.x&63;
  int tok = lb*4 + w;
  const float* xr = x + (size_t)tok*1024 + lane*16;
  f32x4 xv[4];
  #pragma unroll
  for (int q=0;q<4;q++) xv[q] = *(const f32x4*)(xr + q*4);
  {
    u16* xrow = xb + (size_t)tok*1024 + lane*16;
    u32x4 o0, o1;
    o0[0]=pack2(xv[0][0],xv[0][1]); o0[1]=pack2(xv[0][2],xv[0][3]);
    o0[2]=pack2(xv[1][0],xv[1][1]); o0[3]=pack2(xv[1][2],xv[1][3]);
    o1[0]=pack2(xv[2][0],xv[2][1]); o1[1]=pack2(xv[2][2],xv[2][3]);
    o1[2]=pack2(xv[3][0],xv[3][1]); o1[3]=pack2(xv[3][2],xv[3][3]);
    *(u32x4*)xrow     = o0;
    *(u32x4*)(xrow+8) = o1;
  }
  float part[8];
  #pragma unroll
  for (int e=0;e<8;e++){
    const float* g = gw + e*1024 + lane*16;
    float s = 0.f;
    #pragma unroll
    for (int q=0;q<4;q++){
      f32x4 gv = *(const f32x4*)(g + q*4);
      s += xv[q][0]*gv[0] + xv[q][1]*gv[1] + xv[q][2]*gv[2] + xv[q][3]*gv[3];
    }
    part[e]=s;
  }
  #pragma unroll
  for (int e=0;e<8;e++){
    float v = part[e];
    #pragma unroll
    for (int off=32; off>0; off>>=1) v += __shfl_xor(v, off, 64);
    part[e]=v;
  }
  if (lane==0){
    int i0=0; float m0=part[0];
    #pragma unroll
    for (int e=1;e<8;e++) if (part[e]>m0){ m0=part[e]; i0=e; }
    int i1=0; float m1=-3.4e38f;
    #pragma unroll
    for (int e=0;e<8;e++) if (e!=i0 && part[e]>m1){ m1=part[e]; i1=e; }
    sel[tok] = i0 | (i1<<8);
    float e1 = expf(m1-m0);
    float inv = 1.f/(1.f+e1);
    rw[tok*2+0] = inv;
    rw[tok*2+1] = e1*inv;
  }
}

// fm-pair fused weight prep: one block computes fm1- and fm2-combined tiles from ONE staged w slice
__device__ __forceinline__ void prep_body(
  const float* __restrict__ q_w, const float* __restrict__ k_w,
  const float* __restrict__ fmq1, const float* __restrict__ fmq2,
  const float* __restrict__ fmk1, const float* __restrict__ fmk2,
  u16* __restrict__ wA, u16* __restrict__ wB, int l, u16* shmem)
{
  const float *fm1, *fm2, *ws; u16 *wd1;
  int c0;
  if (l < 64){
    int h = l>>3; c0 = (l&7)*128;
    fm1=fmq1; fm2=fmq2; ws=q_w + (size_t)h*131072;
    wd1=wA + (size_t)h*262144;
  } else {
    int l2=l-64, eh=l2>>3; c0=(l2&7)*128;
    int e=eh>>3, h=eh&7;
    fm1=fmk1; fm2=fmk2; ws=k_w + (size_t)eh*131072;
    wd1=wB + (size_t)e*2097152 + (size_t)h*262144;
  }
  u16* wd2 = wd1 + 131072;
  u16* Af = shmem;
  u16* Bf = shmem + 128*136;
  int tid = threadIdx.x;
  // stage B = w[d][c0:c0+128] transposed + swizzled (once)
  for (int i=tid; i<4096; i+=256){
    int dd = i>>5, cq = (i&31)*4;
    f32x4 v = *(const f32x4*)&ws[(size_t)dd*1024 + c0 + cq];
    #pragma unroll
    for (int j=0;j<4;j++){
      int c = cq+j;
      Bf[c*136 + (dd ^ (((c>>2)&3)<<3))] = f2bf(v[j]);
    }
  }
  int lane=tid&63, w=tid>>6, wr=w>>1, wc=w&1, lc=lane&15, lr=lane>>4;
  const f32x4 Z4 = {0.f,0.f,0.f,0.f};
  #pragma unroll
  for (int pass=0; pass<2; ++pass){
    const float* fm = pass ? fm2 : fm1;
    u16* wd = pass ? wd2 : wd1;
    for (int i=tid; i<4096; i+=256){
      int row = i>>5, col = (i&31)*4;
      f32x4 v = *(const f32x4*)&fm[row*128 + col];
      u16* dp = &Af[row*136 + col];
      *(u32*)dp     = pack2(v[0],v[1]);
      *(u32*)(dp+2) = pack2(v[2],v[3]);
    }
    __syncthreads();
    f32x4 acc[4][4];
    #pragma unroll
    for (int i=0;i<4;i++){
      #pragma unroll
      for (int j=0;j<4;j++) acc[i][j]=Z4;
    }
    #pragma unroll
    for (int kk=0; kk<4; ++kk){
      bf16x8 a[4], b[4];
      #pragma unroll
      for (int mi=0;mi<4;mi++)
        a[mi] = *(const bf16x8*)&Af[(wr*64+mi*16+lc)*136 + kk*32 + lr*8];
      #pragma unroll
      for (int ni=0;ni<4;ni++){
        int c = wc*64+ni*16+lc;
        b[ni] = *(const bf16x8*)&Bf[c*136 + ((kk*32 + lr*8) ^ (((c>>2)&3)<<3))];
      }
      #pragma unroll
      for (int mi=0;mi<4;mi++){
        #pragma unroll
        for (int ni=0;ni<4;ni++)
          acc[mi][ni] = MFMA16(a[mi], b[ni], acc[mi][ni]);
      }
    }
    int r0=lr*4;
    #pragma unroll
    for (int mi=0;mi<4;mi++){
      #pragma unroll
      for (int ni=0;ni<4;ni++){
        int col = c0 + wc*64 + ni*16 + lc;
        #pragma unroll
        for (int r=0;r<4;r++){
          int row = wr*64 + mi*16 + r0 + r;
          wd[(size_t)row*1024 + col] = f2bf(acc[mi][ni][r]);
        }
      }
    }
    __syncthreads();   // all reads of Af done before restage
  }
}

// ---------- fused pre-pass: route+xb (0..2047) + prep (2048..2623) + cvt v_w (2624..2879)
//            + cvt o_w (2880..2911) + zero-row (2912) ----------
__global__ __launch_bounds__(256) void k_pre(
  const float* __restrict__ x, const float* __restrict__ gw,
  int* __restrict__ sel, float* __restrict__ rw,
  const float* __restrict__ q_w, const float* __restrict__ k_w,
  const float* __restrict__ fmq1, const float* __restrict__ fmq2,
  const float* __restrict__ fmk1, const float* __restrict__ fmk2,
  u16* __restrict__ wA, u16* __restrict__ wB, u16* __restrict__ xb,
  const float* __restrict__ v_w, u16* __restrict__ wVb,
  const float* __restrict__ o_w, u16* __restrict__ wOb, int* __restrict__ done)
{
  __shared__ __align__(16) u16 shmem[2*128*136];
  int bid = blockIdx.x;
  if (bid==0 && threadIdx.x==0) *done = 0;
  if (bid < 2048)      route_body(x, gw, sel, rw, xb, bid);
  else if (bid < 2624) prep_body(q_w, k_w, fmq1, fmq2, fmk1, fmk2, wA, wB, bid-2048, shmem);
  else if (bid < 2880) cvt_body(v_w, wVb, 1048576L, bid-2624, 256);
  else if (bid < 2912) cvt_body(o_w, wOb, 131072L, bid-2880, 32);
  else {
    // zero row 8192 of xb (pad-row source for k/v GEMM)
    if (threadIdx.x < 128){
      u32x4 z = {0,0,0,0};
      *(u32x4*)&xb[(size_t)8192*1024 + threadIdx.x*8] = z;
    }
  }
}

// ---------- per-(b,e) counting sort + tokmap2 + fused bases (256-pad, last block) ----------
__global__ __launch_bounds__(256) void k_count(const int* __restrict__ sel,
  int* __restrict__ slot_of, int* __restrict__ tokmap2, int* __restrict__ meta,
  int* __restrict__ done)
{
  int g = blockIdx.x, b = g>>3, e = g&7;
  int tid = threadIdx.x;
  __shared__ int cn[256];
  unsigned char ex[16];
  int cnt=0;
  #pragma unroll
  for (int i=0;i<16;i++){
    int t = tid*16+i;
    int sv = sel[b*2048 + (t>>1)];
    int ee = (t&1) ? ((sv>>8)&255) : (sv&255);
    ex[i]=(unsigned char)ee;
    cnt += (ee==e);
  }
  cn[tid]=cnt;
  __syncthreads();
  for (int off=1; off<256; off<<=1){
    int v = (tid>=off) ? cn[tid-off] : 0;
    __syncthreads();
    cn[tid] += v;
    __syncthreads();
  }
  int total = cn[255];
  int run = cn[tid]-cnt;
  int shift = total>2048 ? total-2048 : 0;
  #pragma unroll
  for (int i=0;i<16;i++){
    int t = tid*16+i;
    if (ex[i]==e){
      int j = run - shift;
      run++;
      slot_of[b*4096 + t] = (j>=0)? j : -1;
      if (j>=0) tokmap2[g*2048 + j] = b*2048 + (t>>1);
    }
  }
  if (tid==0){
    meta[g]=total;
    __threadfence();
    if (atomicAdd(done,1)==31){
      int basev=0, t=0;
      meta[96]=0;
      for (int gg=0; gg<32; ++gg){
        int n = atomicAdd(&meta[gg],0);
        int nact = n<2048 ? n : 2048;
        int npad = (nact+255)&~255;
        meta[32+gg]=nact;
        meta[64+gg]=npad;
        meta[129+gg]=(nact+63)>>6;
        for (int i=0;i<(npad>>8);++i) meta[192+t++]=gg;
        basev += npad;
        meta[97+gg]=basev;
      }
      meta[161]=basev;
    }
  }
}

// ======== fused q+k+v 256x256 8-wave GEMM, BK=64, 4-phase/K-tile, counted vmcnt(4) ========
// A sourced directly from xb via tokmap2 (no gathered copy); pad rows -> zero row 8192.
__global__ __launch_bounds__(512,2) void k_gemmQKV(const u16* __restrict__ xb,
  const u16* __restrict__ wA, const u16* __restrict__ wB, const u16* __restrict__ wVb,
  u16* __restrict__ qh, u16* __restrict__ kh, u16* __restrict__ vv,
  const int* __restrict__ meta, const int* __restrict__ tokmap2)
{
  int bid = blockIdx.x;
  int role, tm, tn;
  const u16 *Wp; u16* outB;
  if (bid < 256){
    role=0; int l=bid, xcd=l&7, jj=l>>3, jd=jj>>3;
    tm=xcd*4+jd; tn=jj&7;
    Wp=wA + (size_t)tn*262144; outB=qh;
  } else if (bid < 1024){
    role=1; int l=bid-256, xcd=l&7, jj=l>>3, jd=jj>>3;
    tm=xcd*12+jd; tn=jj&7;
    if (tm*256 >= meta[161]) return;
    Wp=wB + (size_t)(meta[192+tm]&7)*2097152 + (size_t)tn*262144; outB=kh;
  } else {
    role=2; int l=bid-1024, xcd=l&7, jj=l>>3, jd=jj>>2;
    tm=xcd*12+jd; tn=jj&3;
    if (tm*256 >= meta[161]) return;
    Wp=wVb + (size_t)(meta[192+tm]&7)*1048576 + (size_t)tn*262144; outB=vv;
  }

  __shared__ __align__(16) u16 smem[65536];   // 128 KB

  int tid=threadIdx.x, lane=tid&63;
  int w=tid>>6, wr=w>>2, wc=w&3, lc=lane&15, lr=lane>>4;
  int swz = lc&7;
  int ck0 = ((lr)^swz)<<3;
  int ck1 = ((4+lr)^swz)<<3;
  int arow = (wr*128 + lc)*64;
  int brow = 16384 + (wc*64 + lc)*64;
  const f32x4 Z4 = {0.f,0.f,0.f,0.f};
  f32x4 acc[8][4];
  #pragma unroll
  for(int i=0;i<8;i++){
    #pragma unroll
    for(int j2=0;j2<4;j2++) acc[i][j2]=Z4;
  }
  int rowlane = tid>>3;
  int gch = ((tid&7)^(rowlane&7))*8;
  // token per A row-slot (rowlane + 64*i)
  int tk0, tk1, tk2, tk3;
  {
    int r0 = tm*256 + rowlane;
    if (role==0){
      tk0=r0; tk1=r0+64; tk2=r0+128; tk3=r0+192;
    } else {
      int g = meta[192+tm], base = meta[96+g], nact = meta[32+g];
      int gb = g*2048;
      int j0 = r0 - base;
      tk0 = (j0     < nact) ? tokmap2[gb + j0]     : 8192;
      tk1 = (j0+64  < nact) ? tokmap2[gb + j0+64]  : 8192;
      tk2 = (j0+128 < nact) ? tokmap2[gb + j0+128] : 8192;
      tk3 = (j0+192 < nact) ? tokmap2[gb + j0+192] : 8192;
    }
  }
  const u16* Ap0 = xb + (size_t)tk0*1024 + gch;
  const u16* Ap1 = xb + (size_t)tk1*1024 + gch;
  const u16* Ap2 = xb + (size_t)tk2*1024 + gch;
  const u16* Ap3 = xb + (size_t)tk3*1024 + gch;
  const u16* Bsrc = Wp + (size_t)rowlane*1024 + gch;

  // stage A half (two row-slots) at column t*64
  #define STGA(dst, p0, p1, coff) { \
    gl_lds((p0) + (coff), &smem[(dst) + tid*8]); \
    gl_lds((p1) + (coff), &smem[(dst) + 4096 + tid*8]); }
  #define STGB(dst, src) { \
    gl_lds((src),         &smem[(dst) + tid*8]); \
    gl_lds((src) + 65536, &smem[(dst) + 4096 + tid*8]); }

  #define RDA(dst, jrow) { \
    dst[0] = *(const bf16x8*)&smem[d + arow + (2*(jrow)  )*1024 + ck0]; \
    dst[1] = *(const bf16x8*)&smem[d + arow + (2*(jrow)+1)*1024 + ck0]; \
    dst[2] = *(const bf16x8*)&smem[d + arow + (2*(jrow)  )*1024 + ck1]; \
    dst[3] = *(const bf16x8*)&smem[d + arow + (2*(jrow)+1)*1024 + ck1]; }

  #define DOMFMA(src, jrow) { \
    __builtin_amdgcn_s_setprio(1); \
    _Pragma("unroll") \
    for (int ni=0;ni<4;ni++){ \
      acc[2*(jrow)  ][ni] = MFMA16(src[0], b0[ni], acc[2*(jrow)  ][ni]); \
      acc[2*(jrow)+1][ni] = MFMA16(src[1], b0[ni], acc[2*(jrow)+1][ni]); } \
    _Pragma("unroll") \
    for (int ni=0;ni<4;ni++){ \
      acc[2*(jrow)  ][ni] = MFMA16(src[2], b1[ni], acc[2*(jrow)  ][ni]); \
      acc[2*(jrow)+1][ni] = MFMA16(src[3], b1[ni], acc[2*(jrow)+1][ni]); } \
    __builtin_amdgcn_s_setprio(0); }

  // prologue: B0, A0, B1
  STGB(16384, Bsrc);
  STGB(24576, Bsrc + 131072);
  STGA(0,     Ap0, Ap1, 0);
  STGA(8192,  Ap2, Ap3, 0);
  STGB(49152, Bsrc + 64);
  STGB(57344, Bsrc + 131072 + 64);

  for (int t=0; t<16; ++t){
    int d = (t&1)<<15;
    bf16x8 b0[4], b1[4], aE[4], aO[4];
    // ---- phase 0 ----
    if (t<15) asm volatile("s_waitcnt vmcnt(4)" ::: "memory");
    else      asm volatile("s_waitcnt vmcnt(0)" ::: "memory");
    __builtin_amdgcn_s_barrier();
    #pragma unroll
    for (int ni=0;ni<4;ni++){
      b0[ni] = *(const bf16x8*)&smem[d + brow + ni*1024 + ck0];
      b1[ni] = *(const bf16x8*)&smem[d + brow + ni*1024 + ck1];
    }
    RDA(aE, 0);
    if (t<15) STGA(((t+1)&1)<<15, Ap0, Ap1, (size_t)(t+1)*64);
    RDA(aO, 1);
    DOMFMA(aE, 0);
    // ---- phase 1 ----
    __builtin_amdgcn_s_barrier();
    if (t<15) STGA((((t+1)&1)<<15) + 8192, Ap2, Ap3, (size_t)(t+1)*64);
    RDA(aE, 2);
    DOMFMA(aO, 1);
    // ---- phase 2 ----
    __builtin_amdgcn_s_barrier();
    if (t<14) STGB(d + 16384, Bsrc + (size_t)(t+2)*64);
    RDA(aO, 3);
    DOMFMA(aE, 2);
    // ---- phase 3 ----
    __builtin_amdgcn_s_barrier();
    if (t<14) STGB(d + 24576, Bsrc + 131072 + (size_t)(t+2)*64);
    DOMFMA(aO, 3);
  }
  #undef STGA
  #undef STGB
  #undef RDA
  #undef DOMFMA

  __syncthreads();
  if (role < 2){
    if (wc >= 2){
      #pragma unroll
      for (int mi=0;mi<8;mi++){
        #pragma unroll
        for (int ni=0;ni<4;ni++){
          int col = (wc-2)*64 + ni*16 + lc;
          #pragma unroll
          for (int r=0;r<4;r++)
            ((float*)smem)[(wr*128+mi*16+lr*4+r)*128 + col] = acc[mi][ni][r];
        }
      }
    }
    __syncthreads();
    if (wc < 2){
      float scl = (role==0) ? QSCALE : 1.0f;
      #pragma unroll
      for (int mi=0;mi<8;mi++){
        #pragma unroll
        for (int ni=0;ni<4;ni++){
          int col = wc*64 + ni*16 + lc;
          #pragma unroll
          for (int r=0;r<4;r++){
            int row = wr*128+mi*16+lr*4+r;
            float v = acc[mi][ni][r] * ((float*)smem)[row*128 + col] * scl;
            outB[(size_t)(tm*256+row)*1024 + tn*128 + col] = f2bf(v);
          }
        }
      }
    }
  } else {
    #pragma unroll
    for (int mi=0;mi<8;mi++){
      #pragma unroll
      for (int ni=0;ni<4;ni++){
        int col = tn*256 + wc*64 + ni*16 + lc;
        #pragma unroll
        for (int r=0;r<4;r++){
          int row = tm*256 + wr*128 + mi*16 + lr*4 + r;
          outB[(size_t)row*1024 + col] = f2bf(acc[mi][ni][r]);
        }
      }
    }
  }
}

// ======== 128x256 8-wave single GEMM, T4+T2 pipeline — final out proj ========
__global__ __launch_bounds__(512) void k_gemmO(const u16* __restrict__ A, const u16* __restrict__ W,
  float* __restrict__ outF)
{
  int tnN = gridDim.x;
  int bid = blockIdx.y*tnN + blockIdx.x;
  int chunk = gridDim.y >> 3;
  int xcd = bid & 7, j = bid >> 3;
  int jd = j / tnN;
  int tm = xcd*chunk + jd;
  int tn = j - jd*tnN;

  __shared__ __align__(16) u16 smem[73728];

  int tid=threadIdx.x, lane=tid&63;
  int w=tid>>6, wr=w>>2, wc=w&3, lc=lane&15, lr=lane>>4;
  int swz = lc&7;
  const f32x4 Z4 = {0.f,0.f,0.f,0.f};
  f32x4 acc[4][4];
  #pragma unroll
  for(int i=0;i<4;i++){
    #pragma unroll
    for(int j2=0;j2<4;j2++) acc[i][j2]=Z4;
  }
  size_t lanoff = (size_t)(tid>>3)*1024 + (size_t)(((tid&7)^((tid>>3)&7))*8);
  const u16* Ag = A + (size_t)tm*131072 + lanoff;
  const u16* Bg = W + (size_t)tn*262144 + lanoff;
  int lo = tid*8;

  #define STAGEO(ao, bo, kt) { \
    const u16* ga = Ag + (kt)*64; const u16* gb = Bg + (kt)*64; \
    gl_lds(ga,                 &smem[(ao) + lo]); \
    gl_lds(ga + (size_t)65536, &smem[(ao) + 4096 + lo]); \
    gl_lds(gb,                  &smem[(bo) + lo]); \
    gl_lds(gb + (size_t)65536,  &smem[(bo) + 4096 + lo]); \
    gl_lds(gb + (size_t)131072, &smem[(bo) + 8192 + lo]); \
    gl_lds(gb + (size_t)196608, &smem[(bo) + 12288 + lo]); }

  STAGEO(0, 24576, 0);
  STAGEO(8192, 40960, 1);
  int cur = 0;
  for (int kt=0; kt<16; ++kt){
    if (kt<15) asm volatile("s_waitcnt vmcnt(6)" ::: "memory");
    else       asm volatile("s_waitcnt vmcnt(0)" ::: "memory");
    __builtin_amdgcn_s_barrier();
    if (kt<14){
      int nid = kt+2; nid -= (nid/3)*3;
      STAGEO(nid*8192, 24576+nid*16384, kt+2);
    }
    int ao = cur*8192, bo = 24576 + cur*16384;
    __builtin_amdgcn_s_setprio(1);
    #pragma unroll
    for (int kk=0; kk<2; ++kk){
      bf16x8 a[4], b[4];
      #pragma unroll
      for (int mi=0;mi<4;mi++){
        int row = wr*64+mi*16+lc;
        a[mi] = *(const bf16x8*)&smem[ao + row*64 + (((kk*4+lr)^swz)<<3)];
      }
      #pragma unroll
      for (int ni=0;ni<4;ni++){
        int row = wc*64+ni*16+lc;
        b[ni] = *(const bf16x8*)&smem[bo + row*64 + (((kk*4+lr)^swz)<<3)];
      }
      #pragma unroll
      for (int mi=0;mi<4;mi++){
        #pragma unroll
        for (int ni=0;ni<4;ni++)
          acc[mi][ni] = MFMA16(a[mi], b[ni], acc[mi][ni]);
      }
    }
    __builtin_amdgcn_s_setprio(0);
    cur = (cur==2)?0:cur+1;
  }
  #pragma unroll
  for (int mi=0;mi<4;mi++){
    #pragma unroll
    for (int ni=0;ni<4;ni++){
      int col = tn*256 + wc*64 + ni*16 + lc;
      #pragma unroll
      for (int r=0;r<4;r++){
        int row = tm*128 + wr*64 + mi*16 + lr*4 + r;
        outF[(size_t)row*1024 + col] = acc[mi][ni][r];
      }
    }
  }
  #undef STAGEO
}

// ---------- chunked causal linear attention, one block per (group, head) ----------
// merged staging: each K/V row loaded once; Q via tokmap2
__global__ __launch_bounds__(256,1) void k_attn(const u16* __restrict__ qv, const u16* __restrict__ kv,
  const u16* __restrict__ vv, u16* __restrict__ o, const int* __restrict__ meta,
  const int* __restrict__ tokmap2)
{
  int g = blockIdx.x>>3, h = blockIdx.x&7;
  int nch = meta[129+g];
  if (nch==0) return;
  int base = meta[96+g], nact = meta[32+g];
  __shared__ __align__(16) u16 Qs[64*136];
  __shared__ __align__(16) u16 Ks[64*136];
  __shared__ __align__(16) u16 KTs[128*72];
  __shared__ __align__(16) u16 VTs[128*72];
  __shared__ __align__(16) u16 Ts[2*128*136];
  __shared__ __align__(16) u16 Ps[64*72];
  int tid=threadIdx.x, w=tid>>6, lane=tid&63;
  int wr=w>>1, wc=w&1;
  int lr=lane>>4, lc=lane&15;
  {
    u32x4 z={0,0,0,0};
    for (int i=tid; i<128*136/8; i+=256) *(u32x4*)&Ts[i*8]=z;
  }
  const f32x4 Z4 = {0.f,0.f,0.f,0.f};
  f32x4 accT[4][4];
  #pragma unroll
  for (int i=0;i<4;i++){
    #pragma unroll
    for (int j=0;j<4;j++) accT[i][j]=Z4;
  }
  __syncthreads();
  const u16* kb = kv + (size_t)base*1024 + h*128;
  const u16* vb = vv + (size_t)base*1024 + h*128;
  u16* ob = o + (size_t)base*1024 + h*128;
  int tso = 0;

  for (int c=0; c<nch; ++c){
    #pragma unroll
    for (int it=0; it<4; ++it){
      int id = tid + it*256;
      int row = id>>4, kc = id&15;
      int jj = c*64 + row;
      int tok = tokmap2[g*2048 + (jj<nact ? jj : 0)];
      u32x4 qx = *(const u32x4*)(qv + (size_t)tok*1024 + h*128 + kc*8);
      u32x4 kx = *(const u32x4*)(kb + (size_t)jj*1024 + kc*8);
      u32x4 vx = *(const u32x4*)(vb + (size_t)jj*1024 + kc*8);
      *(u32x4*)&Qs[row*136 + kc*8] = qx;
      *(u32x4*)&Ks[row*136 + kc*8] = kx;
      int col = (((row>>3) ^ (kc&7))<<3) + (row&7);
      #pragma unroll
      for (int t=0;t<4;t++){
        KTs[(kc*8+t*2  )*72 + col] = (u16)(kx[t]&0xffff);
        KTs[(kc*8+t*2+1)*72 + col] = (u16)(kx[t]>>16);
        VTs[(kc*8+t*2  )*72 + col] = (u16)(vx[t]&0xffff);
        VTs[(kc*8+t*2+1)*72 + col] = (u16)(vx[t]>>16);
      }
    }
    __syncthreads();
    bf16x8 qf[2][4];
    #pragma unroll
    for (int ti=0; ti<2; ++ti){
      #pragma unroll
      for (int ks=0; ks<4; ++ks)
        qf[ti][ks] = *(const bf16x8*)&Qs[(wr*32+ti*16+lc)*136 + ks*32 + lr*8];
    }
    f32x4 accO[2][4];
    #pragma unroll
    for (int i=0;i<2;i++){
      #pragma unroll
      for (int j=0;j<4;j++) accO[i][j]=Z4;
    }
    #pragma unroll
    for (int ks=0; ks<4; ++ks){
      bf16x8 bt[4];
      #pragma unroll
      for (int te=0; te<4; ++te)
        bt[te] = *(const bf16x8*)&Ts[tso + (wc*64+te*16+lc)*136 + ks*32 + lr*8];
      #pragma unroll
      for (int ti=0; ti<2; ++ti){
        #pragma unroll
        for (int te=0; te<4; ++te)
          accO[ti][te] = MFMA16(qf[ti][ks], bt[te], accO[ti][te]);
      }
    }
    f32x4 accP[2][2];
    #pragma unroll
    for (int i=0;i<2;i++){
      #pragma unroll
      for (int j=0;j<2;j++) accP[i][j]=Z4;
    }
    #pragma unroll
    for (int ks=0; ks<4; ++ks){
      bf16x8 bk[2];
      #pragma unroll
      for (int tj=0; tj<2; ++tj)
        bk[tj] = *(const bf16x8*)&Ks[(wc*32+tj*16+lc)*136 + ks*32 + lr*8];
      #pragma unroll
      for (int ti=0; ti<2; ++ti){
        #pragma unroll
        for (int tj=0; tj<2; ++tj)
          accP[ti][tj] = MFMA16(qf[ti][ks], bk[tj], accP[ti][tj]);
      }
    }
    #pragma unroll
    for (int ti=0; ti<2; ++ti){
      #pragma unroll
      for (int tj=0; tj<2; ++tj){
        #pragma unroll
        for (int r=0;r<4;r++){
          int i = wr*32+ti*16+lr*4+r;
          int j = wc*32+tj*16+lc;
          Ps[i*72 + j] = f2bf( (j<=i) ? accP[ti][tj][r] : 0.f );
        }
      }
    }
    __syncthreads();
    #pragma unroll
    for (int ks=0; ks<2; ++ks){
      bf16x8 ap[2], bv[4];
      #pragma unroll
      for (int ti=0; ti<2; ++ti)
        ap[ti] = *(const bf16x8*)&Ps[(wr*32+ti*16+lc)*72 + ks*32 + lr*8];
      #pragma unroll
      for (int te=0; te<4; ++te)
        bv[te] = *(const bf16x8*)&VTs[TSW(wc*64+te*16+lc, ks*4+lr)];
      #pragma unroll
      for (int ti=0; ti<2; ++ti){
        #pragma unroll
        for (int te=0; te<4; ++te)
          accO[ti][te] = MFMA16(ap[ti], bv[te], accO[ti][te]);
      }
    }
    #pragma unroll
    for (int ks=0; ks<2; ++ks){
      bf16x8 av[4], bk2[4];
      #pragma unroll
      for (int te=0; te<4; ++te)
        av[te] = *(const bf16x8*)&VTs[TSW(wr*64+te*16+lc, ks*4+lr)];
      #pragma unroll
      for (int td=0; td<4; ++td)
        bk2[td] = *(const bf16x8*)&KTs[TSW(wc*64+td*16+lc, ks*4+lr)];
      #pragma unroll
      for (int te=0; te<4; ++te){
        #pragma unroll
        for (int td=0; td<4; ++td)
          accT[te][td] = MFMA16(av[te], bk2[td], accT[te][td]);
      }
    }
    int tsn = tso ^ (128*136);
    #pragma unroll
    for (int te=0; te<4; ++te){
      #pragma unroll
      for (int td=0; td<4; ++td){
        int dk = wc*64+td*16+lc;
        #pragma unroll
        for (int r=0;r<4;r++){
          int erow = wr*64+te*16+lr*4+r;
          Ts[tsn + erow*136 + dk] = f2bf(accT[te][td][r]);
        }
      }
    }
    #pragma unroll
    for (int ti=0; ti<2; ++ti){
      #pragma unroll
      for (int te=0; te<4; ++te){
        int ecol = wc*64+te*16+lc;
        #pragma unroll
        for (int r=0;r<4;r++){
          int i = wr*32+ti*16+lr*4+r;
          ob[(size_t)(c*64+i)*1024 + ecol] = f2bf(accO[ti][te][r]);
        }
      }
    }
    __syncthreads();
    tso = tsn;
  }
}

// ---------- combine + per-head RMSNorm ----------
__global__ __launch_bounds__(256) void k_comb(const u16* __restrict__ o, const int* __restrict__ sel,
  const float* __restrict__ rw, const int* __restrict__ slot_of, const int* __restrict__ meta,
  const float* __restrict__ nw, u16* __restrict__ fin)
{
  int w=threadIdx.x>>6, lane=threadIdx.x&63;
  int tok = blockIdx.x*4 + w;
  int b = tok>>11;
  int sv = sel[tok];
  float acc[16];
  #pragma unroll
  for (int i=0;i<16;i++) acc[i]=0.f;
  #pragma unroll
  for (int kk=0; kk<2; ++kk){
    int e = kk ? ((sv>>8)&255) : (sv&255);
    int j = slot_of[tok*2 + kk];
    if (j < 0) continue;
    float wgt = rw[tok*2+kk];
    int row = meta[96 + b*8 + e] + j;
    const u16* orow = o + (size_t)row*1024 + lane*16;
    #pragma unroll
    for (int q=0;q<2;q++){
      u32x4 v = *(const u32x4*)(orow + q*8);
      #pragma unroll
      for (int t=0;t<4;t++){
        acc[q*8+t*2]   += wgt * bf2f((u16)(v[t]&0xffff));
        acc[q*8+t*2+1] += wgt * bf2f((u16)(v[t]>>16));
      }
    }
  }
  float ssq=0.f;
  #pragma unroll
  for (int i=0;i<16;i++) ssq += acc[i]*acc[i];
  ssq += __shfl_xor(ssq,1,64);
  ssq += __shfl_xor(ssq,2,64);
  ssq += __shfl_xor(ssq,4,64);
  float sc = rsqrtf(ssq*(1.f/128.f) + 1e-5f);
  int cbase = (lane&7)*16;
  u32x4 o0, o1;
  #pragma unroll
  for (int t=0;t<4;t++)
    o0[t] = pack2(acc[2*t]*sc*nw[cbase+2*t], acc[2*t+1]*sc*nw[cbase+2*t+1]);
  #pragma unroll
  for (int t=0;t<4;t++)
    o1[t] = pack2(acc[8+2*t]*sc*nw[cbase+8+2*t], acc[8+2*t+1]*sc*nw[cbase+8+2*t+1]);
  u16* fp = fin + (size_t)tok*1024 + lane*16;
  *(u32x4*)fp     = o0;
  *(u32x4*)(fp+8) = o1;
}

// ---------- host launcher ----------
extern "C" void kernel_launch(void* const* d_in, const int* in_sizes, int n_in,
                              void* d_out, int out_size, void* d_ws, size_t ws_size,
                              hipStream_t stream)
{
  (void)in_sizes; (void)n_in;
  const float* x     = (const float*)d_in[0];
  const float* gate  = (const float*)d_in[1];
  const float* q_w   = (const float*)d_in[2];
  const float* k_w   = (const float*)d_in[3];
  const float* v_w   = (const float*)d_in[4];
  const float* fmq1  = (const float*)d_in[5];
  const float* fmq2  = (const float*)d_in[6];
  const float* fmk1  = (const float*)d_in[7];
  const float* fmk2  = (const float*)d_in[8];
  const float* norm_w= (const float*)d_in[9];
  const float* o_w   = (const float*)d_in[10];
  float* out = (float*)d_out;

  uint8_t* ws = (uint8_t*)d_ws;
  size_t off = 0;
  auto alloc = [&](size_t bytes)->void*{ void* p = ws + off; off += (bytes + 255) & ~(size_t)255; return p; };
  int*   meta = (int*)alloc(4096);
  int*   sel  = (int*)alloc(8192*4);
  float* rwb  = (float*)alloc(8192*2*4);
  int*   slot = (int*)alloc(16384*4);
  int*   tokm2= (int*)alloc((size_t)65536*4);
  int*   done = (int*)alloc(256);
  u16* wA  = (u16*)alloc((size_t)2097152*2);           // q cat weights (2048x1024)
  u16* wVb = (u16*)alloc((size_t)8388608*2);           // v weights bf16 per expert
  u16* wOb = (u16*)alloc((size_t)1048576*2);           // o_w bf16
  u16* xb  = (u16*)alloc((size_t)8193*1024*2);         // bf16(x) + zero row 8192
  u16* ob  = (u16*)alloc((size_t)RMAX*1024*2);         // attn output
  u16* qh  = (u16*)alloc((size_t)8192*1024*2);         // q-hat, token space
  u16* kh  = (u16*)alloc((size_t)RMAX*1024*2);
  u16* vv  = (u16*)alloc((size_t)RMAX*1024*2);
  if (off > ws_size){
    hipMemsetAsync(d_out, 0x7F, (size_t)out_size*4, stream);
    return;
  }
  u16* wB  = (u16*)d_out;   // 33.5 MB k cat weights in output buffer (dead before k_gemmO)
  u16* fin = qh;            // reuse after attn consumed qh

  k_pre<<<2913,256,0,stream>>>(x, gate, sel, rwb, q_w, k_w, fmq1, fmq2, fmk1, fmk2, wA, wB, xb, v_w, wVb, o_w, wOb, done);
  k_count<<<32,256,0,stream>>>(sel, slot, tokm2, meta, done);
  k_gemmQKV<<<1408,512,0,stream>>>(xb, wA, wB, wVb, qh, kh, vv, meta, tokm2);
  k_attn<<<256,256,0,stream>>>(qh, kh, vv, ob, meta, tokm2);
  k_comb<<<2048,256,0,stream>>>(ob, sel, rwb, slot, meta, norm_w, fin);
  k_gemmO<<<dim3(4,64),512,0,stream>>>(fin, wOb, out);
}

// Round 15
// 345.073 us; speedup vs baseline: 1.3315x; 1.0025x over previous
//
#include <hip/hip_runtime.h>
#include <stdint.h>

// ---------- types / helpers ----------
typedef unsigned short u16;
typedef unsigned int   u32;
typedef __attribute__((ext_vector_type(4))) float f32x4;
typedef __attribute__((ext_vector_type(4))) u32   u32x4;
typedef __attribute__((ext_vector_type(8))) __bf16 bf16x8;

#define MFMA16(a,b,c) __builtin_amdgcn_mfma_f32_16x16x32_bf16((a),(b),(c),0,0,0)

#define QSCALE 0.08838834764831845f   // 128^-0.5
#define RMAX   24576                  // sum roundup(min(n,2048),256) <= 16384+32*255

__device__ __forceinline__ float bf2f(u16 x){ u32 u=((u32)x)<<16; float f; __builtin_memcpy(&f,&u,4); return f; }
__device__ __forceinline__ u16 f2bf(float f){ u32 u; __builtin_memcpy(&u,&f,4); u = u + 0x7FFFu + ((u>>16)&1u); return (u16)(u>>16); }
__device__ __forceinline__ u32 pack2(float a, float b){ return (u32)f2bf(a) | ((u32)f2bf(b)<<16); }

// async global->LDS, 16B per lane
__device__ __forceinline__ void gl_lds(const u16* g, u16* l){
  __builtin_amdgcn_global_load_lds(
      (const __attribute__((address_space(1))) void*)g,
      (__attribute__((address_space(3))) void*)l, 16, 0, 0);
}

// transposed-tile addr with octet swizzle (attn): row stride 72 u16
#define TSW(row, oct) ((row)*72 + ((((oct) ^ (((row)>>3)&7)))<<3))

// meta layout (ints): [0,32) n  [32,64) nact  [64,96) npad  [96,129) base
// [129,161) nchunks  [161] R_total  [192,352) 256-tile -> group map

// ---------- device bodies for fused pre-pass ----------
__device__ __forceinline__ void cvt_body(const float* __restrict__ s, u16* __restrict__ d,
                                         long n8, int lb, int nb){
  long idx = (long)lb*256 + threadIdx.x;
  long stride = (long)nb*256;
  for (long i=idx; i<n8; i+=stride){
    const float* p = s + i*8;
    f32x4 a = *(const f32x4*)p;
    f32x4 b = *(const f32x4*)(p+4);
    u32x4 o;
    o[0]=pack2(a[0],a[1]); o[1]=pack2(a[2],a[3]); o[2]=pack2(b[0],b[1]); o[3]=pack2(b[2],b[3]);
    *(u32x4*)(d + i*8) = o;
  }
}

__device__ __forceinline__ void route_body(const float* __restrict__ x, const float* __restrict__ gw,
  int* __restrict__ sel, float* __restrict__ rw, u16* __restrict__ xb, int lb)
{
  int w = threadIdx.x>>6, lane = threadIdx.x&63;
  int tok = lb*4 + w;
  const float* xr = x + (size_t)tok*1024 + lane*16;
  f32x4 xv[4];
  #pragma unroll
  for (int q=0;q<4;q++) xv[q] = *(const f32x4*)(xr + q*4);
  {
    u16* xrow = xb + (size_t)tok*1024 + lane*16;
    u32x4 o0, o1;
    o0[0]=pack2(xv[0][0],xv[0][1]); o0[1]=pack2(xv[0][2],xv[0][3]);
    o0[2]=pack2(xv[1][0],xv[1][1]); o0[3]=pack2(xv[1][2],xv[1][3]);
    o1[0]=pack2(xv[2][0],xv[2][1]); o1[1]=pack2(xv[2][2],xv[2][3]);
    o1[2]=pack2(xv[3][0],xv[3][1]); o1[3]=pack2(xv[3][2],xv[3][3]);
    *(u32x4*)xrow     = o0;
    *(u32x4*)(xrow+8) = o1;
  }
  float part[8];
  #pragma unroll
  for (int e=0;e<8;e++){
    const float* g = gw + e*1024 + lane*16;
    float s = 0.f;
    #pragma unroll
    for (int q=0;q<4;q++){
      f32x4 gv = *(const f32x4*)(g + q*4);
      s += xv[q][0]*gv[0] + xv[q][1]*gv[1] + xv[q][2]*gv[2] + xv[q][3]*gv[3];
    }
    part[e]=s;
  }
  #pragma unroll
  for (int e=0;e<8;e++){
    float v = part[e];
    #pragma unroll
    for (int off=32; off>0; off>>=1) v += __shfl_xor(v, off, 64);
    part[e]=v;
  }
  if (lane==0){
    int i0=0; float m0=part[0];
    #pragma unroll
    for (int e=1;e<8;e++) if (part[e]>m0){ m0=part[e]; i0=e; }
    int i1=0; float m1=-3.4e38f;
    #pragma unroll
    for (int e=0;e<8;e++) if (e!=i0 && part[e]>m1){ m1=part[e]; i1=e; }
    sel[tok] = i0 | (i1<<8);
    float e1 = expf(m1-m0);
    float inv = 1.f/(1.f+e1);
    rw[tok*2+0] = inv;
    rw[tok*2+1] = e1*inv;
  }
}

// fm-pair fused weight prep
__device__ __forceinline__ void prep_body(
  const float* __restrict__ q_w, const float* __restrict__ k_w,
  const float* __restrict__ fmq1, const float* __restrict__ fmq2,
  const float* __restrict__ fmk1, const float* __restrict__ fmk2,
  u16* __restrict__ wA, u16* __restrict__ wB, int l, u16* shmem)
{
  const float *fm1, *fm2, *ws; u16 *wd1;
  int c0;
  if (l < 64){
    int h = l>>3; c0 = (l&7)*128;
    fm1=fmq1; fm2=fmq2; ws=q_w + (size_t)h*131072;
    wd1=wA + (size_t)h*262144;
  } else {
    int l2=l-64, eh=l2>>3; c0=(l2&7)*128;
    int e=eh>>3, h=eh&7;
    fm1=fmk1; fm2=fmk2; ws=k_w + (size_t)eh*131072;
    wd1=wB + (size_t)e*2097152 + (size_t)h*262144;
  }
  u16* wd2 = wd1 + 131072;
  u16* Af = shmem;
  u16* Bf = shmem + 128*136;
  int tid = threadIdx.x;
  for (int i=tid; i<4096; i+=256){
    int dd = i>>5, cq = (i&31)*4;
    f32x4 v = *(const f32x4*)&ws[(size_t)dd*1024 + c0 + cq];
    #pragma unroll
    for (int j=0;j<4;j++){
      int c = cq+j;
      Bf[c*136 + (dd ^ (((c>>2)&3)<<3))] = f2bf(v[j]);
    }
  }
  int lane=tid&63, w=tid>>6, wr=w>>1, wc=w&1, lc=lane&15, lr=lane>>4;
  const f32x4 Z4 = {0.f,0.f,0.f,0.f};
  #pragma unroll
  for (int pass=0; pass<2; ++pass){
    const float* fm = pass ? fm2 : fm1;
    u16* wd = pass ? wd2 : wd1;
    for (int i=tid; i<4096; i+=256){
      int row = i>>5, col = (i&31)*4;
      f32x4 v = *(const f32x4*)&fm[row*128 + col];
      u16* dp = &Af[row*136 + col];
      *(u32*)dp     = pack2(v[0],v[1]);
      *(u32*)(dp+2) = pack2(v[2],v[3]);
    }
    __syncthreads();
    f32x4 acc[4][4];
    #pragma unroll
    for (int i=0;i<4;i++){
      #pragma unroll
      for (int j=0;j<4;j++) acc[i][j]=Z4;
    }
    #pragma unroll
    for (int kk=0; kk<4; ++kk){
      bf16x8 a[4], b[4];
      #pragma unroll
      for (int mi=0;mi<4;mi++)
        a[mi] = *(const bf16x8*)&Af[(wr*64+mi*16+lc)*136 + kk*32 + lr*8];
      #pragma unroll
      for (int ni=0;ni<4;ni++){
        int c = wc*64+ni*16+lc;
        b[ni] = *(const bf16x8*)&Bf[c*136 + ((kk*32 + lr*8) ^ (((c>>2)&3)<<3))];
      }
      #pragma unroll
      for (int mi=0;mi<4;mi++){
        #pragma unroll
        for (int ni=0;ni<4;ni++)
          acc[mi][ni] = MFMA16(a[mi], b[ni], acc[mi][ni]);
      }
    }
    int r0=lr*4;
    #pragma unroll
    for (int mi=0;mi<4;mi++){
      #pragma unroll
      for (int ni=0;ni<4;ni++){
        int col = c0 + wc*64 + ni*16 + lc;
        #pragma unroll
        for (int r=0;r<4;r++){
          int row = wr*64 + mi*16 + r0 + r;
          wd[(size_t)row*1024 + col] = f2bf(acc[mi][ni][r]);
        }
      }
    }
    __syncthreads();
  }
}

// ---------- fused pre-pass ----------
__global__ __launch_bounds__(256) void k_pre(
  const float* __restrict__ x, const float* __restrict__ gw,
  int* __restrict__ sel, float* __restrict__ rw,
  const float* __restrict__ q_w, const float* __restrict__ k_w,
  const float* __restrict__ fmq1, const float* __restrict__ fmq2,
  const float* __restrict__ fmk1, const float* __restrict__ fmk2,
  u16* __restrict__ wA, u16* __restrict__ wB, u16* __restrict__ xb,
  const float* __restrict__ v_w, u16* __restrict__ wVb,
  const float* __restrict__ o_w, u16* __restrict__ wOb, int* __restrict__ done)
{
  __shared__ __align__(16) u16 shmem[2*128*136];
  int bid = blockIdx.x;
  if (bid==0 && threadIdx.x==0) *done = 0;
  if (bid < 2048)      route_body(x, gw, sel, rw, xb, bid);
  else if (bid < 2624) prep_body(q_w, k_w, fmq1, fmq2, fmk1, fmk2, wA, wB, bid-2048, shmem);
  else if (bid < 2880) cvt_body(v_w, wVb, 1048576L, bid-2624, 256);
  else if (bid < 2912) cvt_body(o_w, wOb, 131072L, bid-2880, 32);
  else {
    if (threadIdx.x < 128){
      u32x4 z = {0,0,0,0};
      *(u32x4*)&xb[(size_t)8192*1024 + threadIdx.x*8] = z;
    }
  }
}

// ---------- per-(b,e) counting sort + tokmap2 + fused bases ----------
__global__ __launch_bounds__(256) void k_count(const int* __restrict__ sel,
  int* __restrict__ slot_of, int* __restrict__ tokmap2, int* __restrict__ meta,
  int* __restrict__ done)
{
  int g = blockIdx.x, b = g>>3, e = g&7;
  int tid = threadIdx.x;
  __shared__ int cn[256];
  unsigned char ex[16];
  int cnt=0;
  #pragma unroll
  for (int i=0;i<16;i++){
    int t = tid*16+i;
    int sv = sel[b*2048 + (t>>1)];
    int ee = (t&1) ? ((sv>>8)&255) : (sv&255);
    ex[i]=(unsigned char)ee;
    cnt += (ee==e);
  }
  cn[tid]=cnt;
  __syncthreads();
  for (int off=1; off<256; off<<=1){
    int v = (tid>=off) ? cn[tid-off] : 0;
    __syncthreads();
    cn[tid] += v;
    __syncthreads();
  }
  int total = cn[255];
  int run = cn[tid]-cnt;
  int shift = total>2048 ? total-2048 : 0;
  #pragma unroll
  for (int i=0;i<16;i++){
    int t = tid*16+i;
    if (ex[i]==e){
      int j = run - shift;
      run++;
      slot_of[b*4096 + t] = (j>=0)? j : -1;
      if (j>=0) tokmap2[g*2048 + j] = b*2048 + (t>>1);
    }
  }
  if (tid==0){
    meta[g]=total;
    __threadfence();
    if (atomicAdd(done,1)==31){
      int basev=0, t=0;
      meta[96]=0;
      for (int gg=0; gg<32; ++gg){
        int n = atomicAdd(&meta[gg],0);
        int nact = n<2048 ? n : 2048;
        int npad = (nact+255)&~255;
        meta[32+gg]=nact;
        meta[64+gg]=npad;
        meta[129+gg]=(nact+63)>>6;
        for (int i=0;i<(npad>>8);++i) meta[192+t++]=gg;
        basev += npad;
        meta[97+gg]=basev;
      }
      meta[161]=basev;
    }
  }
}

// ======== fused q+k+v 256x256 8-wave GEMM, BK=64, 2 barriers/K-tile, counted vmcnt(4) ========
__global__ __launch_bounds__(512,2) void k_gemmQKV(const u16* __restrict__ xb,
  const u16* __restrict__ wA, const u16* __restrict__ wB, const u16* __restrict__ wVb,
  u16* __restrict__ qh, u16* __restrict__ kh, u16* __restrict__ vv,
  const int* __restrict__ meta, const int* __restrict__ tokmap2)
{
  int bid = blockIdx.x;
  int role, tm, tn;
  const u16 *Wp; u16* outB;
  if (bid < 256){
    role=0; int l=bid, xcd=l&7, jj=l>>3, jd=jj>>3;
    tm=xcd*4+jd; tn=jj&7;
    Wp=wA + (size_t)tn*262144; outB=qh;
  } else if (bid < 1024){
    role=1; int l=bid-256, xcd=l&7, jj=l>>3, jd=jj>>3;
    tm=xcd*12+jd; tn=jj&7;
    if (tm*256 >= meta[161]) return;
    Wp=wB + (size_t)(meta[192+tm]&7)*2097152 + (size_t)tn*262144; outB=kh;
  } else {
    role=2; int l=bid-1024, xcd=l&7, jj=l>>3, jd=jj>>2;
    tm=xcd*12+jd; tn=jj&3;
    if (tm*256 >= meta[161]) return;
    Wp=wVb + (size_t)(meta[192+tm]&7)*1048576 + (size_t)tn*262144; outB=vv;
  }

  __shared__ __align__(16) u16 smem[65536];   // 128 KB

  int tid=threadIdx.x, lane=tid&63;
  int w=tid>>6, wr=w>>2, wc=w&3, lc=lane&15, lr=lane>>4;
  int swz = lc&7;
  int ck0 = ((lr)^swz)<<3;
  int ck1 = ((4+lr)^swz)<<3;
  int arow = (wr*128 + lc)*64;
  int brow = 16384 + (wc*64 + lc)*64;
  const f32x4 Z4 = {0.f,0.f,0.f,0.f};
  f32x4 acc[8][4];
  #pragma unroll
  for(int i=0;i<8;i++){
    #pragma unroll
    for(int j2=0;j2<4;j2++) acc[i][j2]=Z4;
  }
  int rowlane = tid>>3;
  int gch = ((tid&7)^(rowlane&7))*8;
  int tk0, tk1, tk2, tk3;
  {
    int r0 = tm*256 + rowlane;
    if (role==0){
      tk0=r0; tk1=r0+64; tk2=r0+128; tk3=r0+192;
    } else {
      int g = meta[192+tm], base = meta[96+g], nact = meta[32+g];
      int gb = g*2048;
      int j0 = r0 - base;
      tk0 = (j0     < nact) ? tokmap2[gb + j0]     : 8192;
      tk1 = (j0+64  < nact) ? tokmap2[gb + j0+64]  : 8192;
      tk2 = (j0+128 < nact) ? tokmap2[gb + j0+128] : 8192;
      tk3 = (j0+192 < nact) ? tokmap2[gb + j0+192] : 8192;
    }
  }
  const u16* Ap0 = xb + (size_t)tk0*1024 + gch;
  const u16* Ap1 = xb + (size_t)tk1*1024 + gch;
  const u16* Ap2 = xb + (size_t)tk2*1024 + gch;
  const u16* Ap3 = xb + (size_t)tk3*1024 + gch;
  const u16* Bsrc = Wp + (size_t)rowlane*1024 + gch;

  #define STGA(dst, p0, p1, coff) { \
    gl_lds((p0) + (coff), &smem[(dst) + tid*8]); \
    gl_lds((p1) + (coff), &smem[(dst) + 4096 + tid*8]); }
  #define STGB(dst, src) { \
    gl_lds((src),         &smem[(dst) + tid*8]); \
    gl_lds((src) + 65536, &smem[(dst) + 4096 + tid*8]); }

  #define RDA(dst, jrow) { \
    dst[0] = *(const bf16x8*)&smem[d + arow + (2*(jrow)  )*1024 + ck0]; \
    dst[1] = *(const bf16x8*)&smem[d + arow + (2*(jrow)+1)*1024 + ck0]; \
    dst[2] = *(const bf16x8*)&smem[d + arow + (2*(jrow)  )*1024 + ck1]; \
    dst[3] = *(const bf16x8*)&smem[d + arow + (2*(jrow)+1)*1024 + ck1]; }

  #define DOMFMA(src, jrow) { \
    _Pragma("unroll") \
    for (int ni=0;ni<4;ni++){ \
      acc[2*(jrow)  ][ni] = MFMA16(src[0], b0[ni], acc[2*(jrow)  ][ni]); \
      acc[2*(jrow)+1][ni] = MFMA16(src[1], b0[ni], acc[2*(jrow)+1][ni]); } \
    _Pragma("unroll") \
    for (int ni=0;ni<4;ni++){ \
      acc[2*(jrow)  ][ni] = MFMA16(src[2], b1[ni], acc[2*(jrow)  ][ni]); \
      acc[2*(jrow)+1][ni] = MFMA16(src[3], b1[ni], acc[2*(jrow)+1][ni]); } }

  // prologue: B0, A0, B1  (issue order makes vmcnt(4) uniform)
  STGB(16384, Bsrc);
  STGB(24576, Bsrc + 131072);
  STGA(0,     Ap0, Ap1, 0);
  STGA(8192,  Ap2, Ap3, 0);
  STGB(49152, Bsrc + 64);
  STGB(57344, Bsrc + 131072 + 64);

  for (int t=0; t<16; ++t){
    int d = (t&1)<<15;
    bf16x8 b0[4], b1[4], aE[4], aO[4];
    // ---- half 1: phases 0+1 (rows 0..3), stage A(t+1) ----
    if (t<15) asm volatile("s_waitcnt vmcnt(4)" ::: "memory");
    else      asm volatile("s_waitcnt vmcnt(0)" ::: "memory");
    __builtin_amdgcn_s_barrier();
    #pragma unroll
    for (int ni=0;ni<4;ni++){
      b0[ni] = *(const bf16x8*)&smem[d + brow + ni*1024 + ck0];
      b1[ni] = *(const bf16x8*)&smem[d + brow + ni*1024 + ck1];
    }
    RDA(aE, 0);
    if (t<15){
      STGA(((t+1)&1)<<15,          Ap0, Ap1, (size_t)(t+1)*64);
      STGA((((t+1)&1)<<15) + 8192, Ap2, Ap3, (size_t)(t+1)*64);
    }
    RDA(aO, 1);
    __builtin_amdgcn_s_setprio(1);
    DOMFMA(aE, 0);
    DOMFMA(aO, 1);
    __builtin_amdgcn_s_setprio(0);
    // ---- half 2: phases 2+3 (rows 4..7), stage B(t+2) ----
    __builtin_amdgcn_s_barrier();
    RDA(aE, 2);
    if (t<14){
      STGB(d + 16384, Bsrc + (size_t)(t+2)*64);
      STGB(d + 24576, Bsrc + 131072 + (size_t)(t+2)*64);
    }
    RDA(aO, 3);
    __builtin_amdgcn_s_setprio(1);
    DOMFMA(aE, 2);
    DOMFMA(aO, 3);
    __builtin_amdgcn_s_setprio(0);
  }
  #undef STGA
  #undef STGB
  #undef RDA
  #undef DOMFMA

  __syncthreads();
  if (role < 2){
    if (wc >= 2){
      #pragma unroll
      for (int mi=0;mi<8;mi++){
        #pragma unroll
        for (int ni=0;ni<4;ni++){
          int col = (wc-2)*64 + ni*16 + lc;
          #pragma unroll
          for (int r=0;r<4;r++)
            ((float*)smem)[(wr*128+mi*16+lr*4+r)*128 + col] = acc[mi][ni][r];
        }
      }
    }
    __syncthreads();
    if (wc < 2){
      float scl = (role==0) ? QSCALE : 1.0f;
      #pragma unroll
      for (int mi=0;mi<8;mi++){
        #pragma unroll
        for (int ni=0;ni<4;ni++){
          int col = wc*64 + ni*16 + lc;
          #pragma unroll
          for (int r=0;r<4;r++){
            int row = wr*128+mi*16+lr*4+r;
            float v = acc[mi][ni][r] * ((float*)smem)[row*128 + col] * scl;
            outB[(size_t)(tm*256+row)*1024 + tn*128 + col] = f2bf(v);
          }
        }
      }
    }
  } else {
    #pragma unroll
    for (int mi=0;mi<8;mi++){
      #pragma unroll
      for (int ni=0;ni<4;ni++){
        int col = tn*256 + wc*64 + ni*16 + lc;
        #pragma unroll
        for (int r=0;r<4;r++){
          int row = tm*256 + wr*128 + mi*16 + lr*4 + r;
          outB[(size_t)row*1024 + col] = f2bf(acc[mi][ni][r]);
        }
      }
    }
  }
}

// ======== 128x256 8-wave single GEMM — final out proj ========
__global__ __launch_bounds__(512) void k_gemmO(const u16* __restrict__ A, const u16* __restrict__ W,
  float* __restrict__ outF)
{
  int tnN = gridDim.x;
  int bid = blockIdx.y*tnN + blockIdx.x;
  int chunk = gridDim.y >> 3;
  int xcd = bid & 7, j = bid >> 3;
  int jd = j / tnN;
  int tm = xcd*chunk + jd;
  int tn = j - jd*tnN;

  __shared__ __align__(16) u16 smem[73728];

  int tid=threadIdx.x, lane=tid&63;
  int w=tid>>6, wr=w>>2, wc=w&3, lc=lane&15, lr=lane>>4;
  int swz = lc&7;
  const f32x4 Z4 = {0.f,0.f,0.f,0.f};
  f32x4 acc[4][4];
  #pragma unroll
  for(int i=0;i<4;i++){
    #pragma unroll
    for(int j2=0;j2<4;j2++) acc[i][j2]=Z4;
  }
  size_t lanoff = (size_t)(tid>>3)*1024 + (size_t)(((tid&7)^((tid>>3)&7))*8);
  const u16* Ag = A + (size_t)tm*131072 + lanoff;
  const u16* Bg = W + (size_t)tn*262144 + lanoff;
  int lo = tid*8;

  #define STAGEO(ao, bo, kt) { \
    const u16* ga = Ag + (kt)*64; const u16* gb = Bg + (kt)*64; \
    gl_lds(ga,                 &smem[(ao) + lo]); \
    gl_lds(ga + (size_t)65536, &smem[(ao) + 4096 + lo]); \
    gl_lds(gb,                  &smem[(bo) + lo]); \
    gl_lds(gb + (size_t)65536,  &smem[(bo) + 4096 + lo]); \
    gl_lds(gb + (size_t)131072, &smem[(bo) + 8192 + lo]); \
    gl_lds(gb + (size_t)196608, &smem[(bo) + 12288 + lo]); }

  STAGEO(0, 24576, 0);
  STAGEO(8192, 40960, 1);
  int cur = 0;
  for (int kt=0; kt<16; ++kt){
    if (kt<15) asm volatile("s_waitcnt vmcnt(6)" ::: "memory");
    else       asm volatile("s_waitcnt vmcnt(0)" ::: "memory");
    __builtin_amdgcn_s_barrier();
    if (kt<14){
      int nid = kt+2; nid -= (nid/3)*3;
      STAGEO(nid*8192, 24576+nid*16384, kt+2);
    }
    int ao = cur*8192, bo = 24576 + cur*16384;
    __builtin_amdgcn_s_setprio(1);
    #pragma unroll
    for (int kk=0; kk<2; ++kk){
      bf16x8 a[4], b[4];
      #pragma unroll
      for (int mi=0;mi<4;mi++){
        int row = wr*64+mi*16+lc;
        a[mi] = *(const bf16x8*)&smem[ao + row*64 + (((kk*4+lr)^swz)<<3)];
      }
      #pragma unroll
      for (int ni=0;ni<4;ni++){
        int row = wc*64+ni*16+lc;
        b[ni] = *(const bf16x8*)&smem[bo + row*64 + (((kk*4+lr)^swz)<<3)];
      }
      #pragma unroll
      for (int mi=0;mi<4;mi++){
        #pragma unroll
        for (int ni=0;ni<4;ni++)
          acc[mi][ni] = MFMA16(a[mi], b[ni], acc[mi][ni]);
      }
    }
    __builtin_amdgcn_s_setprio(0);
    cur = (cur==2)?0:cur+1;
  }
  #pragma unroll
  for (int mi=0;mi<4;mi++){
    #pragma unroll
    for (int ni=0;ni<4;ni++){
      int col = tn*256 + wc*64 + ni*16 + lc;
      #pragma unroll
      for (int r=0;r<4;r++){
        int row = tm*128 + wr*64 + mi*16 + lr*4 + r;
        outF[(size_t)row*1024 + col] = acc[mi][ni][r];
      }
    }
  }
  #undef STAGEO
}

// ---------- chunked causal linear attention ----------
__global__ __launch_bounds__(256,1) void k_attn(const u16* __restrict__ qv, const u16* __restrict__ kv,
  const u16* __restrict__ vv, u16* __restrict__ o, const int* __restrict__ meta,
  const int* __restrict__ tokmap2)
{
  int g = blockIdx.x>>3, h = blockIdx.x&7;
  int nch = meta[129+g];
  if (nch==0) return;
  int base = meta[96+g], nact = meta[32+g];
  __shared__ __align__(16) u16 Qs[64*136];
  __shared__ __align__(16) u16 Ks[64*136];
  __shared__ __align__(16) u16 KTs[128*72];
  __shared__ __align__(16) u16 VTs[128*72];
  __shared__ __align__(16) u16 Ts[2*128*136];
  __shared__ __align__(16) u16 Ps[64*72];
  int tid=threadIdx.x, w=tid>>6, lane=tid&63;
  int wr=w>>1, wc=w&1;
  int lr=lane>>4, lc=lane&15;
  {
    u32x4 z={0,0,0,0};
    for (int i=tid; i<128*136/8; i+=256) *(u32x4*)&Ts[i*8]=z;
  }
  const f32x4 Z4 = {0.f,0.f,0.f,0.f};
  f32x4 accT[4][4];
  #pragma unroll
  for (int i=0;i<4;i++){
    #pragma unroll
    for (int j=0;j<4;j++) accT[i][j]=Z4;
  }
  __syncthreads();
  const u16* kb = kv + (size_t)base*1024 + h*128;
  const u16* vb = vv + (size_t)base*1024 + h*128;
  u16* ob = o + (size_t)base*1024 + h*128;
  int tso = 0;

  for (int c=0; c<nch; ++c){
    #pragma unroll
    for (int it=0; it<4; ++it){
      int id = tid + it*256;
      int row = id>>4, kc = id&15;
      int jj = c*64 + row;
      int tok = tokmap2[g*2048 + (jj<nact ? jj : 0)];
      u32x4 qx = *(const u32x4*)(qv + (size_t)tok*1024 + h*128 + kc*8);
      u32x4 kx = *(const u32x4*)(kb + (size_t)jj*1024 + kc*8);
      u32x4 vx = *(const u32x4*)(vb + (size_t)jj*1024 + kc*8);
      *(u32x4*)&Qs[row*136 + kc*8] = qx;
      *(u32x4*)&Ks[row*136 + kc*8] = kx;
      int col = (((row>>3) ^ (kc&7))<<3) + (row&7);
      #pragma unroll
      for (int t=0;t<4;t++){
        KTs[(kc*8+t*2  )*72 + col] = (u16)(kx[t]&0xffff);
        KTs[(kc*8+t*2+1)*72 + col] = (u16)(kx[t]>>16);
        VTs[(kc*8+t*2  )*72 + col] = (u16)(vx[t]&0xffff);
        VTs[(kc*8+t*2+1)*72 + col] = (u16)(vx[t]>>16);
      }
    }
    __syncthreads();
    bf16x8 qf[2][4];
    #pragma unroll
    for (int ti=0; ti<2; ++ti){
      #pragma unroll
      for (int ks=0; ks<4; ++ks)
        qf[ti][ks] = *(const bf16x8*)&Qs[(wr*32+ti*16+lc)*136 + ks*32 + lr*8];
    }
    f32x4 accO[2][4];
    #pragma unroll
    for (int i=0;i<2;i++){
      #pragma unroll
      for (int j=0;j<4;j++) accO[i][j]=Z4;
    }
    #pragma unroll
    for (int ks=0; ks<4; ++ks){
      bf16x8 bt[4];
      #pragma unroll
      for (int te=0; te<4; ++te)
        bt[te] = *(const bf16x8*)&Ts[tso + (wc*64+te*16+lc)*136 + ks*32 + lr*8];
      #pragma unroll
      for (int ti=0; ti<2; ++ti){
        #pragma unroll
        for (int te=0; te<4; ++te)
          accO[ti][te] = MFMA16(qf[ti][ks], bt[te], accO[ti][te]);
      }
    }
    f32x4 accP[2][2];
    #pragma unroll
    for (int i=0;i<2;i++){
      #pragma unroll
      for (int j=0;j<2;j++) accP[i][j]=Z4;
    }
    #pragma unroll
    for (int ks=0; ks<4; ++ks){
      bf16x8 bk[2];
      #pragma unroll
      for (int tj=0; tj<2; ++tj)
        bk[tj] = *(const bf16x8*)&Ks[(wc*32+tj*16+lc)*136 + ks*32 + lr*8];
      #pragma unroll
      for (int ti=0; ti<2; ++ti){
        #pragma unroll
        for (int tj=0; tj<2; ++tj)
          accP[ti][tj] = MFMA16(qf[ti][ks], bk[tj], accP[ti][tj]);
      }
    }
    #pragma unroll
    for (int ti=0; ti<2; ++ti){
      #pragma unroll
      for (int tj=0; tj<2; ++tj){
        #pragma unroll
        for (int r=0;r<4;r++){
          int i = wr*32+ti*16+lr*4+r;
          int j = wc*32+tj*16+lc;
          Ps[i*72 + j] = f2bf( (j<=i) ? accP[ti][tj][r] : 0.f );
        }
      }
    }
    __syncthreads();
    #pragma unroll
    for (int ks=0; ks<2; ++ks){
      bf16x8 ap[2], bv[4];
      #pragma unroll
      for (int ti=0; ti<2; ++ti)
        ap[ti] = *(const bf16x8*)&Ps[(wr*32+ti*16+lc)*72 + ks*32 + lr*8];
      #pragma unroll
      for (int te=0; te<4; ++te)
        bv[te] = *(const bf16x8*)&VTs[TSW(wc*64+te*16+lc, ks*4+lr)];
      #pragma unroll
      for (int ti=0; ti<2; ++ti){
        #pragma unroll
        for (int te=0; te<4; ++te)
          accO[ti][te] = MFMA16(ap[ti], bv[te], accO[ti][te]);
      }
    }
    #pragma unroll
    for (int ks=0; ks<2; ++ks){
      bf16x8 av[4], bk2[4];
      #pragma unroll
      for (int te=0; te<4; ++te)
        av[te] = *(const bf16x8*)&VTs[TSW(wr*64+te*16+lc, ks*4+lr)];
      #pragma unroll
      for (int td=0; td<4; ++td)
        bk2[td] = *(const bf16x8*)&KTs[TSW(wc*64+td*16+lc, ks*4+lr)];
      #pragma unroll
      for (int te=0; te<4; ++te){
        #pragma unroll
        for (int td=0; td<4; ++td)
          accT[te][td] = MFMA16(av[te], bk2[td], accT[te][td]);
      }
    }
    int tsn = tso ^ (128*136);
    #pragma unroll
    for (int te=0; te<4; ++te){
      #pragma unroll
      for (int td=0; td<4; ++td){
        int dk = wc*64+td*16+lc;
        #pragma unroll
        for (int r=0;r<4;r++){
          int erow = wr*64+te*16+lr*4+r;
          Ts[tsn + erow*136 + dk] = f2bf(accT[te][td][r]);
        }
      }
    }
    #pragma unroll
    for (int ti=0; ti<2; ++ti){
      #pragma unroll
      for (int te=0; te<4; ++te){
        int ecol = wc*64+te*16+lc;
        #pragma unroll
        for (int r=0;r<4;r++){
          int i = wr*32+ti*16+lr*4+r;
          ob[(size_t)(c*64+i)*1024 + ecol] = f2bf(accO[ti][te][r]);
        }
      }
    }
    __syncthreads();
    tso = tsn;
  }
}

// ---------- combine + per-head RMSNorm ----------
__global__ __launch_bounds__(256) void k_comb(const u16* __restrict__ o, const int* __restrict__ sel,
  const float* __restrict__ rw, const int* __restrict__ slot_of, const int* __restrict__ meta,
  const float* __restrict__ nw, u16* __restrict__ fin)
{
  int w=threadIdx.x>>6, lane=threadIdx.x&63;
  int tok = blockIdx.x*4 + w;
  int b = tok>>11;
  int sv = sel[tok];
  float acc[16];
  #pragma unroll
  for (int i=0;i<16;i++) acc[i]=0.f;
  #pragma unroll
  for (int kk=0; kk<2; ++kk){
    int e = kk ? ((sv>>8)&255) : (sv&255);
    int j = slot_of[tok*2 + kk];
    if (j < 0) continue;
    float wgt = rw[tok*2+kk];
    int row = meta[96 + b*8 + e] + j;
    const u16* orow = o + (size_t)row*1024 + lane*16;
    #pragma unroll
    for (int q=0;q<2;q++){
      u32x4 v = *(const u32x4*)(orow + q*8);
      #pragma unroll
      for (int t=0;t<4;t++){
        acc[q*8+t*2]   += wgt * bf2f((u16)(v[t]&0xffff));
        acc[q*8+t*2+1] += wgt * bf2f((u16)(v[t]>>16));
      }
    }
  }
  float ssq=0.f;
  #pragma unroll
  for (int i=0;i<16;i++) ssq += acc[i]*acc[i];
  ssq += __shfl_xor(ssq,1,64);
  ssq += __shfl_xor(ssq,2,64);
  ssq += __shfl_xor(ssq,4,64);
  float sc = rsqrtf(ssq*(1.f/128.f) + 1e-5f);
  int cbase = (lane&7)*16;
  u32x4 o0, o1;
  #pragma unroll
  for (int t=0;t<4;t++)
    o0[t] = pack2(acc[2*t]*sc*nw[cbase+2*t], acc[2*t+1]*sc*nw[cbase+2*t+1]);
  #pragma unroll
  for (int t=0;t<4;t++)
    o1[t] = pack2(acc[8+2*t]*sc*nw[cbase+8+2*t], acc[8+2*t+1]*sc*nw[cbase+8+2*t+1]);
  u16* fp = fin + (size_t)tok*1024 + lane*16;
  *(u32x4*)fp     = o0;
  *(u32x4*)(fp+8) = o1;
}

// ---------- host launcher ----------
extern "C" void kernel_launch(void* const* d_in, const int* in_sizes, int n_in,
                              void* d_out, int out_size, void* d_ws, size_t ws_size,
                              hipStream_t stream)
{
  (void)in_sizes; (void)n_in;
  const float* x     = (const float*)d_in[0];
  const float* gate  = (const float*)d_in[1];
  const float* q_w   = (const float*)d_in[2];
  const float* k_w   = (const float*)d_in[3];
  const float* v_w   = (const float*)d_in[4];
  const float* fmq1  = (const float*)d_in[5];
  const float* fmq2  = (const float*)d_in[6];
  const float* fmk1  = (const float*)d_in[7];
  const float* fmk2  = (const float*)d_in[8];
  const float* norm_w= (const float*)d_in[9];
  const float* o_w   = (const float*)d_in[10];
  float* out = (float*)d_out;

  uint8_t* ws = (uint8_t*)d_ws;
  size_t off = 0;
  auto alloc = [&](size_t bytes)->void*{ void* p = ws + off; off += (bytes + 255) & ~(size_t)255; return p; };
  int*   meta = (int*)alloc(4096);
  int*   sel  = (int*)alloc(8192*4);
  float* rwb  = (float*)alloc(8192*2*4);
  int*   slot = (int*)alloc(16384*4);
  int*   tokm2= (int*)alloc((size_t)65536*4);
  int*   done = (int*)alloc(256);
  u16* wA  = (u16*)alloc((size_t)2097152*2);           // q cat weights (2048x1024)
  u16* wVb = (u16*)alloc((size_t)8388608*2);           // v weights bf16 per expert
  u16* wOb = (u16*)alloc((size_t)1048576*2);           // o_w bf16
  u16* xb  = (u16*)alloc((size_t)8193*1024*2);         // bf16(x) + zero row 8192
  u16* ob  = (u16*)alloc((size_t)RMAX*1024*2);         // attn output
  u16* qh  = (u16*)alloc((size_t)8192*1024*2);         // q-hat, token space
  u16* kh  = (u16*)alloc((size_t)RMAX*1024*2);
  u16* vv  = (u16*)alloc((size_t)RMAX*1024*2);
  if (off > ws_size){
    hipMemsetAsync(d_out, 0x7F, (size_t)out_size*4, stream);
    return;
  }
  u16* wB  = (u16*)d_out;   // 33.5 MB k cat weights in output buffer (dead before k_gemmO)
  u16* fin = qh;            // reuse after attn consumed qh

  k_pre<<<2913,256,0,stream>>>(x, gate, sel, rwb, q_w, k_w, fmq1, fmq2, fmk1, fmk2, wA, wB, xb, v_w, wVb, o_w, wOb, done);
  k_count<<<32,256,0,stream>>>(sel, slot, tokm2, meta, done);
  k_gemmQKV<<<1408,512,0,stream>>>(xb, wA, wB, wVb, qh, kh, vv, meta, tokm2);
  k_attn<<<256,256,0,stream>>>(qh, kh, vv, ob, meta, tokm2);
  k_comb<<<2048,256,0,stream>>>(ob, sel, rwb, slot, meta, norm_w, fin);
  k_gemmO<<<dim3(4,64),512,0,stream>>>(fin, wOb, out);
}